// Round 2
// baseline (3263.449 us; speedup 1.0000x reference)
//
#include <hip/hip_runtime.h>
#include <hip/hip_bf16.h>
#include <math.h>

// B=2048 windows, N=64 tokens, C=192 channels, 6 heads * 32 dim, 3C=576
#define SCALE_Q 0.17677669529663687f

__device__ const float c8tab[8] = {
    1.f, 0.70710678118654752f, 0.f, -0.70710678118654752f,
   -1.f, -0.70710678118654752f, 0.f, 0.70710678118654752f};

// ---------------------------------------------------------------------------
// Forward 2D real-DFT (real part): y1[b][uv][c] = sum_hw cos(2pi(u h + v w)/8) x[b][hw][c]
// One block per window. x[b] and y1[b] are both 12288-float flat blocks.
// ---------------------------------------------------------------------------
__global__ __launch_bounds__(256) void k_dft_fwd(const float* __restrict__ x,
                                                 float* __restrict__ y1)
{
    __shared__ float xs[12288];
    __shared__ float lut[4096];
    const int b = blockIdx.x, tid = threadIdx.x;
    const long base = (long)b * 12288;
    for (int idx = tid; idx < 12288; idx += 256) xs[idx] = x[base + idx];
    for (int idx = tid; idx < 4096; idx += 256) {
        int uv = idx >> 6, hw = idx & 63;
        int k = ((uv >> 3) * (hw >> 3) + (uv & 7) * (hw & 7)) & 7;
        lut[idx] = c8tab[k];
    }
    __syncthreads();
    for (int idx = tid; idx < 12288; idx += 256) {
        int uv = idx / 192, c = idx - uv * 192;
        float acc = 0.f;
        #pragma unroll 8
        for (int hw = 0; hw < 64; ++hw)
            acc += lut[uv * 64 + hw] * xs[hw * 192 + c];
        y1[base + idx] = acc;
    }
}

// ---------------------------------------------------------------------------
// Inverse 2D real-DFT (in-place safe: full window staged in LDS before write).
// y3t layout [b][o][uv]; output flat [b][o*64+hw] == x_ifft[b,h,n,d] layout.
// ---------------------------------------------------------------------------
__global__ __launch_bounds__(256) void k_dft_inv(const float* __restrict__ y3t,
                                                 float* __restrict__ xifft)
{
    __shared__ float ys[12288];
    __shared__ float lut[4096];
    const int b = blockIdx.x, tid = threadIdx.x;
    const long base = (long)b * 12288;
    for (int idx = tid; idx < 12288; idx += 256) ys[idx] = y3t[base + idx];
    for (int idx = tid; idx < 4096; idx += 256) {
        int uv = idx >> 6, hw = idx & 63;
        int k = ((uv >> 3) * (hw >> 3) + (uv & 7) * (hw & 7)) & 7;
        lut[idx] = c8tab[k];
    }
    __syncthreads();
    for (int idx = tid; idx < 12288; idx += 256) {
        int o = idx >> 6, hw = idx & 63;
        float acc = 0.f;
        #pragma unroll 8
        for (int uv = 0; uv < 64; ++uv)
            acc += lut[uv * 64 + hw] * ys[o * 64 + uv];
        xifft[base + idx] = acc * (1.f / 64.f);
    }
}

// ---------------------------------------------------------------------------
// Generic K=192 GEMM:  acc[row][o] = sum_c A[row*192+c] * W[o*192+c]
// COLOUT=false: out[row*192 + o]  (+bias, optional exact GELU)   [in-place OK]
// COLOUT=true : out[o*o_stride + blockIdx.x*win_stride + rl]     [in-place OK
//               when the write region is the block's own 64-row window]
// Output type OT (float or bf16). 64x64 tiles, full K in LDS, pad stride 204.
// ---------------------------------------------------------------------------
template<bool COLOUT, bool GELU_E, bool BIAS_E, typename OT>
__global__ __launch_bounds__(256) void gemm_k192(
    const float* __restrict__ A, const float* __restrict__ W,
    const float* __restrict__ bias, OT* __restrict__ out,
    int Ntot, long o_stride, long win_stride)
{
    __shared__ float As[64 * 204];
    __shared__ float Ws[64 * 204];
    const int tid = threadIdx.x;
    const long row0 = (long)blockIdx.x * 64;

    for (int idx = tid; idx < 12288; idx += 256) {
        int r = idx / 192, c = idx - r * 192;
        As[r * 204 + c] = A[(row0 + r) * 192 + c];
    }
    const int ty = tid >> 4, tx = tid & 15;
    const int nt = Ntot >> 6;
    for (int ot = 0; ot < nt; ++ot) {
        __syncthreads();   // As load done / previous-iter Ws readers done
        for (int idx = tid; idx < 12288; idx += 256) {
            int r = idx / 192, c = idx - r * 192;
            Ws[r * 204 + c] = W[(long)(ot * 64 + r) * 192 + c];
        }
        __syncthreads();
        float acc[4][4];
        #pragma unroll
        for (int i = 0; i < 4; ++i)
            #pragma unroll
            for (int j = 0; j < 4; ++j) acc[i][j] = 0.f;
        const float* P = COLOUT ? Ws : As;   // ty-indexed operand
        const float* Q = COLOUT ? As : Ws;   // tx-indexed operand
        for (int k = 0; k < 192; k += 4) {
            float4 p[4], q[4];
            #pragma unroll
            for (int i = 0; i < 4; ++i)
                p[i] = *(const float4*)(P + (ty + 16 * i) * 204 + k);
            #pragma unroll
            for (int j = 0; j < 4; ++j)
                q[j] = *(const float4*)(Q + (tx + 16 * j) * 204 + k);
            #pragma unroll
            for (int i = 0; i < 4; ++i)
                #pragma unroll
                for (int j = 0; j < 4; ++j)
                    acc[i][j] += p[i].x * q[j].x + p[i].y * q[j].y +
                                 p[i].z * q[j].z + p[i].w * q[j].w;
        }
        #pragma unroll
        for (int i = 0; i < 4; ++i) {
            #pragma unroll
            for (int j = 0; j < 4; ++j) {
                float v = acc[i][j];
                if (COLOUT) {
                    int o  = ot * 64 + ty + 16 * i;
                    int rl = tx + 16 * j;
                    if (BIAS_E) v += bias[o];
                    long dst = (long)o * o_stride + (long)blockIdx.x * win_stride + rl;
                    if constexpr (sizeof(OT) == 2) out[dst] = __float2bfloat16(v);
                    else                           out[dst] = v;
                } else {
                    int o    = ot * 64 + tx + 16 * j;
                    long row = row0 + ty + 16 * i;
                    if (BIAS_E) v += bias[o];
                    if (GELU_E) v = 0.5f * v * (1.0f + erff(v * 0.70710678118654752f));
                    long dst = row * 192 + o;
                    if constexpr (sizeof(OT) == 2) out[dst] = __float2bfloat16(v);
                    else                           out[dst] = v;
                }
            }
        }
    }
}

// ---------------------------------------------------------------------------
// Fused depthwise-3x3 conv (over the (window b, token n) grid, zero-padded)
// + xifft residual + q-scale + windowed attention, one block per (b, h).
// Stages the 96 needed t-channels (s=0,1,2 x 32 dims) with +/-1 window halo.
// Writes out_bnc[b][n][h*32+d] into d_out (later projected in-place).
// ---------------------------------------------------------------------------
__global__ __launch_bounds__(256) void k_attn_fused(
    const __hip_bfloat16* __restrict__ t,
    const float* __restrict__ xifft,
    const float* __restrict__ dww, const float* __restrict__ dwb,
    const float* __restrict__ rpb, const int* __restrict__ relidx,
    float* __restrict__ obnc)
{
    __shared__ __hip_bfloat16 tb[96 * 3 * 66];   // [c3][r][n+pad]
    __shared__ float wd[96 * 9];
    __shared__ float bd[96];
    __shared__ float qs[64 * 36], ks[64 * 36], vs[64 * 36];
    const int b = blockIdx.x, h = blockIdx.y, tid = threadIdx.x;

    for (int i = tid; i < 96 * 3; i += 256) {
        tb[i * 66]      = __float2bfloat16(0.f);
        tb[i * 66 + 65] = __float2bfloat16(0.f);
    }
    for (int idx = tid; idx < 96 * 3 * 64; idx += 256) {
        int c3 = idx / 192;              // s*32 + d
        int r  = (idx >> 6) % 3;
        int n  = idx & 63;
        int s = c3 >> 5, d = c3 & 31;
        int bb = b + r - 1;
        __hip_bfloat16 v = __float2bfloat16(0.f);
        if (bb >= 0 && bb < 2048)
            v = t[(long)(s * 192 + h * 32 + d) * 131072 + (long)bb * 64 + n];
        tb[(c3 * 3 + r) * 66 + n + 1] = v;
    }
    for (int i = tid; i < 864; i += 256) {
        int c3 = i / 9, w9 = i - c3 * 9;
        int s = c3 >> 5, d = c3 & 31;
        wd[i] = dww[(s * 192 + h * 32 + d) * 9 + w9];
    }
    if (tid < 96) {
        int s = tid >> 5, d = tid & 31;
        bd[tid] = dwb[s * 192 + h * 32 + d];
    }
    __syncthreads();

    const long xf_base = (long)b * 12288 + (long)h * 2048;
    for (int idx = tid; idx < 2048; idx += 256) {
        int n = idx >> 5, d = idx & 31;
        float xf = xifft[xf_base + idx];
        float a[3];
        #pragma unroll
        for (int s = 0; s < 3; ++s) {
            int c3 = s * 32 + d;
            float acc = bd[c3];
            #pragma unroll
            for (int r = 0; r < 3; ++r)
                #pragma unroll
                for (int j = 0; j < 3; ++j)
                    acc += wd[c3 * 9 + r * 3 + j] *
                           __bfloat162float(tb[(c3 * 3 + r) * 66 + n + j]);
            a[s] = acc + xf;
        }
        qs[n * 36 + d] = a[0] * SCALE_Q;
        ks[n * 36 + d] = a[1];
        vs[n * 36 + d] = a[2];
    }
    __syncthreads();

    const int row = tid >> 2, cg = tid & 3;
    float p[16];
    float mx = -1e30f;
    #pragma unroll
    for (int mm = 0; mm < 16; ++mm) {
        int m = cg * 16 + mm;
        float dot = 0.f;
        #pragma unroll
        for (int k4 = 0; k4 < 8; ++k4) {
            float4 aq = *(const float4*)&qs[row * 36 + k4 * 4];
            float4 ck = *(const float4*)&ks[m * 36 + k4 * 4];
            dot += aq.x * ck.x + aq.y * ck.y + aq.z * ck.z + aq.w * ck.w;
        }
        p[mm] = dot + rpb[relidx[row * 64 + m] * 6 + h];
        mx = fmaxf(mx, p[mm]);
    }
    mx = fmaxf(mx, __shfl_xor(mx, 1));
    mx = fmaxf(mx, __shfl_xor(mx, 2));
    float sum = 0.f;
    #pragma unroll
    for (int mm = 0; mm < 16; ++mm) { p[mm] = expf(p[mm] - mx); sum += p[mm]; }
    sum += __shfl_xor(sum, 1);
    sum += __shfl_xor(sum, 2);
    const float inv = 1.0f / sum;

    float o[32];
    #pragma unroll
    for (int d = 0; d < 32; ++d) o[d] = 0.f;
    #pragma unroll
    for (int mm = 0; mm < 16; ++mm) {
        float pv = p[mm] * inv;
        int m = cg * 16 + mm;
        #pragma unroll
        for (int d4 = 0; d4 < 8; ++d4) {
            float4 vv = *(const float4*)&vs[m * 36 + d4 * 4];
            o[d4 * 4 + 0] += pv * vv.x;
            o[d4 * 4 + 1] += pv * vv.y;
            o[d4 * 4 + 2] += pv * vv.z;
            o[d4 * 4 + 3] += pv * vv.w;
        }
    }
    #pragma unroll
    for (int d = 0; d < 32; ++d) {
        o[d] += __shfl_xor(o[d], 1);
        o[d] += __shfl_xor(o[d], 2);
    }
    float* dst = obnc + ((long)b * 64 + row) * 192 + h * 32 + cg * 8;
    #pragma unroll
    for (int j = 0; j < 8; ++j) {
        float val;
        switch (cg) {
            case 0: val = o[j];      break;
            case 1: val = o[8 + j];  break;
            case 2: val = o[16 + j]; break;
            default: val = o[24 + j]; break;
        }
        dst[j] = val;
    }
}

// ---------------------------------------------------------------------------
// Launcher. Workspace (251.7 MB total):
//   Ra [f32, 25,165,824]  : y1 -> y2 -> y3t -> xifft   (FFT chain, in-place)
//   Tb [bf16, 75,497,472] : t (qkv 1x1-conv output, o-major)
// d_out doubles as out_bnc, then proj runs in-place on it.
// ---------------------------------------------------------------------------
extern "C" void kernel_launch(void* const* d_in, const int* in_sizes, int n_in,
                              void* d_out, int out_size, void* d_ws, size_t ws_size,
                              hipStream_t stream)
{
    const float* x      = (const float*)d_in[0];
    const float* qkvw   = (const float*)d_in[1];
    const float* qkvb   = (const float*)d_in[2];
    const float* dww    = (const float*)d_in[3];
    const float* dwb    = (const float*)d_in[4];
    const float* q1w    = (const float*)d_in[5];
    const float* q2w    = (const float*)d_in[6];
    const float* rpb    = (const float*)d_in[7];
    const float* projw  = (const float*)d_in[8];
    const float* projb  = (const float*)d_in[9];
    const int*   relidx = (const int*)d_in[10];
    float* out = (float*)d_out;

    float* Ra = (float*)d_ws;
    __hip_bfloat16* Tb = (__hip_bfloat16*)(Ra + 25165824L);

    // FFT branch (in-place chain in Ra)
    k_dft_fwd<<<2048, 256, 0, stream>>>(x, Ra);
    gemm_k192<false, true,  false, float><<<2048, 256, 0, stream>>>(Ra, q1w, nullptr, Ra, 192, 0, 0);
    gemm_k192<true,  false, false, float><<<2048, 256, 0, stream>>>(Ra, q2w, nullptr, Ra, 192, 64, 12288);
    k_dft_inv<<<2048, 256, 0, stream>>>(Ra, Ra);

    // t[o][b*64+n] = x @ qkv_w^T + qkv_b  (bf16, o-major for the depthwise conv)
    gemm_k192<true,  false, true, __hip_bfloat16><<<2048, 256, 0, stream>>>(x, qkvw, qkvb, Tb, 576, 131072, 64);

    // fused depthwise conv + residual + attention -> out_bnc in d_out
    k_attn_fused<<<dim3(2048, 6), 256, 0, stream>>>(Tb, Ra, dww, dwb, rpb, relidx, out);

    // final projection, in-place on d_out
    gemm_k192<false, false, true, float><<<2048, 256, 0, stream>>>(out, projw, projb, out, 192, 0, 0);
}

// Round 3
// 1386.977 us; speedup vs baseline: 2.3529x; 2.3529x over previous
//
#include <hip/hip_runtime.h>
#include <math.h>

// B=2048 windows, N=64 tokens, C=192 channels, 6 heads x 32 dim, 3C=576
#define SCALE_Q 0.17677669529663687f

typedef _Float16 f16;
typedef _Float16 f16x4 __attribute__((ext_vector_type(4)));
typedef _Float16 f16x8 __attribute__((ext_vector_type(8)));
typedef float float4v __attribute__((ext_vector_type(4)));

__device__ const float c8tab[8] = {
    1.f, 0.70710678118654752f, 0.f, -0.70710678118654752f,
   -1.f, -0.70710678118654752f, 0.f, 0.70710678118654752f};

// ---------------------------------------------------------------------------
// Forward 2D real-DFT: y1[b][uv][c] = sum_hw cos(2pi(uh+vw)/8) x[b][hw][c]
// float4-vectorized over c. Output f16.
// ---------------------------------------------------------------------------
__global__ __launch_bounds__(256) void k_dft_fwd(const float* __restrict__ x,
                                                 f16* __restrict__ y1)
{
    __shared__ float xs[64 * 196];
    __shared__ float lutf[4096];
    const int b = blockIdx.x, tid = threadIdx.x;
    const long gbase = (long)b * 12288;
    for (int idx = tid; idx < 3072; idx += 256) {
        int r = idx / 48, c4 = idx % 48;
        *(float4v*)&xs[r * 196 + c4 * 4] =
            *(const float4v*)&x[gbase + r * 192 + c4 * 4];
    }
    for (int idx = tid; idx < 4096; idx += 256) {
        int uv = idx >> 6, hw = idx & 63;
        int k = ((uv >> 3) * (hw >> 3) + (uv & 7) * (hw & 7)) & 7;
        lutf[idx] = c8tab[k];
    }
    __syncthreads();
    for (int oi = 0; oi < 12; ++oi) {
        int idx = oi * 256 + tid;
        int uv = idx / 48, c4 = idx % 48;
        float4v acc = {0.f, 0.f, 0.f, 0.f};
        #pragma unroll 8
        for (int hw = 0; hw < 64; ++hw) {
            float s = lutf[uv * 64 + hw];
            float4v xv = *(const float4v*)&xs[hw * 196 + c4 * 4];
            acc += s * xv;
        }
        f16x4 o4 = {(f16)acc.x, (f16)acc.y, (f16)acc.z, (f16)acc.w};
        *(f16x4*)&y1[gbase + uv * 192 + c4 * 4] = o4;
    }
}

// ---------------------------------------------------------------------------
// Inverse 2D real-DFT (in-place safe): xifft[b][o*64+hw] = (1/64) sum_uv L[uv][hw] y3[b][uv][o]
// ---------------------------------------------------------------------------
__global__ __launch_bounds__(256) void k_dft_inv(const f16* __restrict__ y3,
                                                 f16* __restrict__ xifft)
{
    __shared__ float ys[64 * 196];
    __shared__ float Lf[64 * 68];
    const int b = blockIdx.x, tid = threadIdx.x;
    const long gbase = (long)b * 12288;
    for (int idx = tid; idx < 12288; idx += 256) {
        int uv = idx / 192, o = idx - uv * 192;
        ys[uv * 196 + o] = (float)y3[gbase + idx];
    }
    for (int idx = tid; idx < 4096; idx += 256) {
        int uv = idx >> 6, hw = idx & 63;
        int k = ((uv >> 3) * (hw >> 3) + (uv & 7) * (hw & 7)) & 7;
        Lf[uv * 68 + hw] = c8tab[k] * (1.f / 64.f);
    }
    __syncthreads();
    for (int oi = 0; oi < 12; ++oi) {
        int idx = oi * 256 + tid;
        int o = idx >> 4, hw4 = idx & 15;
        float4v acc = {0.f, 0.f, 0.f, 0.f};
        #pragma unroll 8
        for (int uv = 0; uv < 64; ++uv) {
            float s = ys[uv * 196 + o];
            float4v lv = *(const float4v*)&Lf[uv * 68 + hw4 * 4];
            acc += s * lv;
        }
        f16x4 o4 = {(f16)acc.x, (f16)acc.y, (f16)acc.z, (f16)acc.w};
        *(f16x4*)&xifft[gbase + o * 64 + hw4 * 4] = o4;
    }
}

// ---------------------------------------------------------------------------
// fp16 MFMA GEMM, K=192: D[row][o] = sum_c A[row][c] * W[o][c] (+bias,+gelu)
// A: row-major [M][192], f32 or f16. W: f32 [N][192] (converted in staging).
// out: row-major [M][N], f32 or f16. M = 131072 (2048 blocks x 64 rows).
// LDS pad 192->200 (row 400B: 16B-aligned, bank-step 4 -> 2-way = free).
// In-place over A is safe: As fully staged before first write; each block
// reads/writes only its own 64 rows.
// ---------------------------------------------------------------------------
template<int NT, bool GELU_E, bool BIAS_E, bool A_F32, bool OUT_F32>
__global__ __launch_bounds__(256) void gemm_mfma(
    const void* __restrict__ Ain, const float* __restrict__ W,
    const float* __restrict__ bias, void* __restrict__ out)
{
    __shared__ f16 As[64 * 200];
    __shared__ f16 Ws[64 * 200];
    const int tid = threadIdx.x;
    const long row0 = (long)blockIdx.x * 64;
    constexpr int N = NT * 64;

    if (A_F32) {
        const float* A = (const float*)Ain;
        for (int idx = tid; idx < 3072; idx += 256) {
            int r = idx / 48, c4 = idx % 48;
            float4v v = *(const float4v*)&A[(row0 + r) * 192 + c4 * 4];
            f16x4 hv = {(f16)v.x, (f16)v.y, (f16)v.z, (f16)v.w};
            *(f16x4*)&As[r * 200 + c4 * 4] = hv;
        }
    } else {
        const f16* A = (const f16*)Ain;
        for (int idx = tid; idx < 3072; idx += 256) {
            int r = idx / 48, c4 = idx % 48;
            *(f16x4*)&As[r * 200 + c4 * 4] =
                *(const f16x4*)&A[(row0 + r) * 192 + c4 * 4];
        }
    }
    const int wave = tid >> 6, l = tid & 63, lo = l & 15, hi = l >> 4;
    for (int ot = 0; ot < NT; ++ot) {
        __syncthreads();   // As staged / previous Ws readers done
        for (int idx = tid; idx < 3072; idx += 256) {
            int r = idx / 48, c4 = idx % 48;
            float4v v = *(const float4v*)&W[(long)(ot * 64 + r) * 192 + c4 * 4];
            f16x4 hv = {(f16)v.x, (f16)v.y, (f16)v.z, (f16)v.w};
            *(f16x4*)&Ws[r * 200 + c4 * 4] = hv;
        }
        __syncthreads();
        float4v acc[4];
        #pragma unroll
        for (int nt = 0; nt < 4; ++nt) acc[nt] = (float4v){0.f, 0.f, 0.f, 0.f};
        #pragma unroll
        for (int kc = 0; kc < 6; ++kc) {
            f16x8 a = *(const f16x8*)&As[(wave * 16 + lo) * 200 + kc * 32 + hi * 8];
            #pragma unroll
            for (int nt = 0; nt < 4; ++nt) {
                f16x8 bfr = *(const f16x8*)&Ws[(nt * 16 + lo) * 200 + kc * 32 + hi * 8];
                acc[nt] = __builtin_amdgcn_mfma_f32_16x16x32_f16(a, bfr, acc[nt], 0, 0, 0);
            }
        }
        #pragma unroll
        for (int nt = 0; nt < 4; ++nt) {
            #pragma unroll
            for (int r = 0; r < 4; ++r) {
                float v = acc[nt][r];
                int o = ot * 64 + nt * 16 + lo;
                long row = row0 + wave * 16 + hi * 4 + r;
                if (BIAS_E) v += bias[o];
                if (GELU_E) v = 0.5f * v * (1.0f + erff(v * 0.70710678118654752f));
                if (OUT_F32) ((float*)out)[row * N + o] = v;
                else         ((f16*)out)[row * N + o] = (f16)v;
            }
        }
    }
}

// ---------------------------------------------------------------------------
// Fused depthwise-3x3 conv + xifft residual + windowed attention, per (b,h).
// s-loop reuses one 12.7KB tb buffer (32 ch x 3 rows). Conflict fixes:
// m = mm*4+cg ordering (K/V reads -> 4 distinct addrs, broadcast), Q row in
// registers, bias stride 68. LDS 51.6KB -> 3 blocks/CU.
// ---------------------------------------------------------------------------
__global__ __launch_bounds__(256) void k_attn(
    const f16* __restrict__ t, const f16* __restrict__ xifft,
    const float* __restrict__ dww, const float* __restrict__ dwb,
    const float* __restrict__ rpb, const int* __restrict__ relidx,
    f16* __restrict__ obnc)
{
    __shared__ f16 tb[32 * 3 * 66];
    __shared__ float wd[96 * 9];
    __shared__ float bd[96];
    __shared__ float qs[64 * 36], ks[64 * 36], vs[64 * 36];
    __shared__ f16 bs[64 * 68];
    const int b = blockIdx.x, h = blockIdx.y, tid = threadIdx.x;

    for (int idx = tid; idx < 864; idx += 256) {
        int c3 = idx / 9, w9 = idx - c3 * 9;
        int s = c3 >> 5, d = c3 & 31;
        wd[idx] = dww[(s * 192 + h * 32 + d) * 9 + w9];
    }
    for (int idx = tid; idx < 96; idx += 256) {
        int s = idx >> 5, d = idx & 31;
        bd[idx] = dwb[s * 192 + h * 32 + d];
    }
    for (int idx = tid; idx < 4096; idx += 256)
        bs[(idx >> 6) * 68 + (idx & 63)] = (f16)rpb[relidx[idx] * 6 + h];

    for (int s = 0; s < 3; ++s) {
        __syncthreads();
        for (int i = tid; i < 96; i += 256) {
            tb[i * 66] = (f16)0.f; tb[i * 66 + 65] = (f16)0.f;
        }
        for (int idx = tid; idx < 6144; idx += 256) {
            int d = idx / 192;
            int r = (idx >> 6) % 3;
            int n = idx & 63;
            int bb = b + r - 1;
            f16 v = (f16)0.f;
            if (bb >= 0 && bb < 2048)
                v = t[(long)(bb * 64 + n) * 576 + s * 192 + h * 32 + d];
            tb[(d * 3 + r) * 66 + n + 1] = v;
        }
        __syncthreads();
        for (int idx = tid; idx < 2048; idx += 256) {
            int n = idx >> 5, d = idx & 31;
            float acc = bd[s * 32 + d];
            #pragma unroll
            for (int r = 0; r < 3; ++r)
                #pragma unroll
                for (int j = 0; j < 3; ++j)
                    acc += wd[(s * 32 + d) * 9 + r * 3 + j] *
                           (float)tb[(d * 3 + r) * 66 + n + j];
            acc += (float)xifft[(long)b * 12288 + h * 2048 + idx];
            if (s == 0)      qs[n * 36 + d] = acc * SCALE_Q;
            else if (s == 1) ks[n * 36 + d] = acc;
            else             vs[n * 36 + d] = acc;
        }
    }
    __syncthreads();

    const int row = tid >> 2, cg = tid & 3;
    float qr[32];
    #pragma unroll
    for (int k4 = 0; k4 < 8; ++k4) {
        float4v qv = *(const float4v*)&qs[row * 36 + k4 * 4];
        qr[k4*4+0] = qv.x; qr[k4*4+1] = qv.y; qr[k4*4+2] = qv.z; qr[k4*4+3] = qv.w;
    }
    float p[16], mx = -1e30f;
    #pragma unroll
    for (int mm = 0; mm < 16; ++mm) {
        int m = mm * 4 + cg;
        float dot = 0.f;
        #pragma unroll
        for (int k4 = 0; k4 < 8; ++k4) {
            float4v kv = *(const float4v*)&ks[m * 36 + k4 * 4];
            dot += qr[k4*4]*kv.x + qr[k4*4+1]*kv.y + qr[k4*4+2]*kv.z + qr[k4*4+3]*kv.w;
        }
        p[mm] = dot + (float)bs[row * 68 + m];
        mx = fmaxf(mx, p[mm]);
    }
    mx = fmaxf(mx, __shfl_xor(mx, 1));
    mx = fmaxf(mx, __shfl_xor(mx, 2));
    float sum = 0.f;
    #pragma unroll
    for (int mm = 0; mm < 16; ++mm) { p[mm] = __expf(p[mm] - mx); sum += p[mm]; }
    sum += __shfl_xor(sum, 1);
    sum += __shfl_xor(sum, 2);
    const float inv = 1.0f / sum;

    float o[32];
    #pragma unroll
    for (int d = 0; d < 32; ++d) o[d] = 0.f;
    #pragma unroll
    for (int mm = 0; mm < 16; ++mm) {
        float pv = p[mm] * inv;
        int m = mm * 4 + cg;
        #pragma unroll
        for (int d4 = 0; d4 < 8; ++d4) {
            float4v vv = *(const float4v*)&vs[m * 36 + d4 * 4];
            o[d4*4+0] += pv * vv.x; o[d4*4+1] += pv * vv.y;
            o[d4*4+2] += pv * vv.z; o[d4*4+3] += pv * vv.w;
        }
    }
    #pragma unroll
    for (int d = 0; d < 32; ++d) {
        o[d] += __shfl_xor(o[d], 1);
        o[d] += __shfl_xor(o[d], 2);
    }
    f16x8 pk;
    if (cg == 0) {
        #pragma unroll
        for (int j = 0; j < 8; ++j) pk[j] = (f16)o[j];
    } else if (cg == 1) {
        #pragma unroll
        for (int j = 0; j < 8; ++j) pk[j] = (f16)o[8 + j];
    } else if (cg == 2) {
        #pragma unroll
        for (int j = 0; j < 8; ++j) pk[j] = (f16)o[16 + j];
    } else {
        #pragma unroll
        for (int j = 0; j < 8; ++j) pk[j] = (f16)o[24 + j];
    }
    *(f16x8*)&obnc[(long)(b * 64 + row) * 192 + h * 32 + cg * 8] = pk;
}

// ---------------------------------------------------------------------------
// Launcher. Workspace (f16), 251,658,240 bytes total (== round-2 footprint):
//   A [0, 25165824)          : y1 -> y2 -> y3 -> xifft (in-place chain)
//   T [25165824, 100663296)  : t  (qkv 1x1 output, row-major [bn][576])
//   O [100663296, 125829120) : obnc [bn][192]
// ---------------------------------------------------------------------------
extern "C" void kernel_launch(void* const* d_in, const int* in_sizes, int n_in,
                              void* d_out, int out_size, void* d_ws, size_t ws_size,
                              hipStream_t stream)
{
    const float* x      = (const float*)d_in[0];
    const float* qkvw   = (const float*)d_in[1];
    const float* qkvb   = (const float*)d_in[2];
    const float* dww    = (const float*)d_in[3];
    const float* dwb    = (const float*)d_in[4];
    const float* q1w    = (const float*)d_in[5];
    const float* q2w    = (const float*)d_in[6];
    const float* rpb    = (const float*)d_in[7];
    const float* projw  = (const float*)d_in[8];
    const float* projb  = (const float*)d_in[9];
    const int*   relidx = (const int*)d_in[10];

    f16* A = (f16*)d_ws;
    f16* T = A + 25165824L;
    f16* O = T + 75497472L;

    // FFT branch: y1 = ReDFT(x); y2 = gelu(y1 Q1^T); y3 = y2 Q2^T; xifft = ReIDFT(y3)
    k_dft_fwd<<<2048, 256, 0, stream>>>(x, A);
    gemm_mfma<3, true,  false, false, false><<<2048, 256, 0, stream>>>(A, q1w, nullptr, A);
    gemm_mfma<3, false, false, false, false><<<2048, 256, 0, stream>>>(A, q2w, nullptr, A);
    k_dft_inv<<<2048, 256, 0, stream>>>(A, A);

    // t = x @ qkv_w^T + qkv_b  (row-major [bn][576], f16)
    gemm_mfma<9, false, true, true, false><<<2048, 256, 0, stream>>>(x, qkvw, qkvb, T);

    // fused depthwise conv + residual + attention -> obnc f16
    k_attn<<<dim3(2048, 6), 256, 0, stream>>>(T, A, dww, dwb, rpb, relidx, O);

    // final projection -> d_out f32
    gemm_mfma<3, false, true, false, true><<<2048, 256, 0, stream>>>(O, projw, projb, (float*)d_out);
}

// Round 4
// 1308.410 us; speedup vs baseline: 2.4942x; 1.0600x over previous
//
#include <hip/hip_runtime.h>
#include <math.h>

// B=2048 windows, N=64 tokens, C=192 channels, 6 heads x 32 dim, 3C=576
#define SCALE_Q 0.17677669529663687f

typedef _Float16 f16;
typedef _Float16 f16x4 __attribute__((ext_vector_type(4)));
typedef _Float16 f16x8 __attribute__((ext_vector_type(8)));
typedef float float4v __attribute__((ext_vector_type(4)));

__device__ const float c8tab[8] = {
    1.f, 0.70710678118654752f, 0.f, -0.70710678118654752f,
   -1.f, -0.70710678118654752f, 0.f, 0.70710678118654752f};

// Precomputed relative-position bias tile [6][64][64] (f16)
__device__ f16 g_biasg[6 * 64 * 64];

__global__ __launch_bounds__(256) void k_bias(const float* __restrict__ rpb,
                                              const int* __restrict__ relidx)
{
    int idx = blockIdx.x * 256 + threadIdx.x;   // 0..24575
    if (idx < 24576) {
        int h = idx >> 12, nm = idx & 4095;
        g_biasg[h * 4096 + nm] = (f16)rpb[relidx[nm] * 6 + h];
    }
}

// ---------------------------------------------------------------------------
// Forward 2D real-DFT: y1[b][uv][c] = sum_hw cos(2pi(uh+vw)/8) x[b][hw][c]
// ---------------------------------------------------------------------------
__global__ __launch_bounds__(256) void k_dft_fwd(const float* __restrict__ x,
                                                 f16* __restrict__ y1)
{
    __shared__ float xs[64 * 196];
    __shared__ float lutf[4096];
    const int b = blockIdx.x, tid = threadIdx.x;
    const long gbase = (long)b * 12288;
    for (int idx = tid; idx < 3072; idx += 256) {
        int r = idx / 48, c4 = idx % 48;
        *(float4v*)&xs[r * 196 + c4 * 4] =
            *(const float4v*)&x[gbase + r * 192 + c4 * 4];
    }
    for (int idx = tid; idx < 4096; idx += 256) {
        int uv = idx >> 6, hw = idx & 63;
        int k = ((uv >> 3) * (hw >> 3) + (uv & 7) * (hw & 7)) & 7;
        lutf[idx] = c8tab[k];
    }
    __syncthreads();
    for (int oi = 0; oi < 12; ++oi) {
        int idx = oi * 256 + tid;
        int uv = idx / 48, c4 = idx % 48;
        float4v acc = {0.f, 0.f, 0.f, 0.f};
        #pragma unroll 8
        for (int hw = 0; hw < 64; ++hw) {
            float s = lutf[uv * 64 + hw];
            float4v xv = *(const float4v*)&xs[hw * 196 + c4 * 4];
            acc += s * xv;
        }
        f16x4 o4 = {(f16)acc.x, (f16)acc.y, (f16)acc.z, (f16)acc.w};
        *(f16x4*)&y1[gbase + uv * 192 + c4 * 4] = o4;
    }
}

// ---------------------------------------------------------------------------
// Inverse 2D real-DFT (in-place safe)
// ---------------------------------------------------------------------------
__global__ __launch_bounds__(256) void k_dft_inv(const f16* __restrict__ y3,
                                                 f16* __restrict__ xifft)
{
    __shared__ float ys[64 * 196];
    __shared__ float Lf[64 * 68];
    const int b = blockIdx.x, tid = threadIdx.x;
    const long gbase = (long)b * 12288;
    for (int idx = tid; idx < 12288; idx += 256) {
        int uv = idx / 192, o = idx - uv * 192;
        ys[uv * 196 + o] = (float)y3[gbase + idx];
    }
    for (int idx = tid; idx < 4096; idx += 256) {
        int uv = idx >> 6, hw = idx & 63;
        int k = ((uv >> 3) * (hw >> 3) + (uv & 7) * (hw & 7)) & 7;
        Lf[uv * 68 + hw] = c8tab[k] * (1.f / 64.f);
    }
    __syncthreads();
    for (int oi = 0; oi < 12; ++oi) {
        int idx = oi * 256 + tid;
        int o = idx >> 4, hw4 = idx & 15;
        float4v acc = {0.f, 0.f, 0.f, 0.f};
        #pragma unroll 8
        for (int uv = 0; uv < 64; ++uv) {
            float s = ys[uv * 196 + o];
            float4v lv = *(const float4v*)&Lf[uv * 68 + hw4 * 4];
            acc += s * lv;
        }
        f16x4 o4 = {(f16)acc.x, (f16)acc.y, (f16)acc.z, (f16)acc.w};
        *(f16x4*)&xifft[gbase + o * 64 + hw4 * 4] = o4;
    }
}

// ---------------------------------------------------------------------------
// fp16 MFMA GEMM, K=192. GROUPED=true writes out[(o/32)][row][o%32] (f16) for
// the attention's coalesced channel-group reads; else row-major [M][NT*64].
// ---------------------------------------------------------------------------
template<int NT, bool GELU_E, bool BIAS_E, bool A_F32, bool OUT_F32, bool GROUPED>
__global__ __launch_bounds__(256) void gemm_mfma(
    const void* __restrict__ Ain, const float* __restrict__ W,
    const float* __restrict__ bias, void* __restrict__ out)
{
    __shared__ f16 As[64 * 200];
    __shared__ f16 Ws[64 * 200];
    const int tid = threadIdx.x;
    const long row0 = (long)blockIdx.x * 64;
    constexpr int N = NT * 64;

    if (A_F32) {
        const float* A = (const float*)Ain;
        for (int idx = tid; idx < 3072; idx += 256) {
            int r = idx / 48, c4 = idx % 48;
            float4v v = *(const float4v*)&A[(row0 + r) * 192 + c4 * 4];
            f16x4 hv = {(f16)v.x, (f16)v.y, (f16)v.z, (f16)v.w};
            *(f16x4*)&As[r * 200 + c4 * 4] = hv;
        }
    } else {
        const f16* A = (const f16*)Ain;
        for (int idx = tid; idx < 3072; idx += 256) {
            int r = idx / 48, c4 = idx % 48;
            *(f16x4*)&As[r * 200 + c4 * 4] =
                *(const f16x4*)&A[(row0 + r) * 192 + c4 * 4];
        }
    }
    const int wave = tid >> 6, l = tid & 63, lo = l & 15, hi = l >> 4;
    for (int ot = 0; ot < NT; ++ot) {
        __syncthreads();
        for (int idx = tid; idx < 3072; idx += 256) {
            int r = idx / 48, c4 = idx % 48;
            float4v v = *(const float4v*)&W[(long)(ot * 64 + r) * 192 + c4 * 4];
            f16x4 hv = {(f16)v.x, (f16)v.y, (f16)v.z, (f16)v.w};
            *(f16x4*)&Ws[r * 200 + c4 * 4] = hv;
        }
        __syncthreads();
        float4v acc[4];
        #pragma unroll
        for (int nt = 0; nt < 4; ++nt) acc[nt] = (float4v){0.f, 0.f, 0.f, 0.f};
        #pragma unroll
        for (int kc = 0; kc < 6; ++kc) {
            f16x8 a = *(const f16x8*)&As[(wave * 16 + lo) * 200 + kc * 32 + hi * 8];
            #pragma unroll
            for (int nt = 0; nt < 4; ++nt) {
                f16x8 bfr = *(const f16x8*)&Ws[(nt * 16 + lo) * 200 + kc * 32 + hi * 8];
                acc[nt] = __builtin_amdgcn_mfma_f32_16x16x32_f16(a, bfr, acc[nt], 0, 0, 0);
            }
        }
        #pragma unroll
        for (int nt = 0; nt < 4; ++nt) {
            #pragma unroll
            for (int r = 0; r < 4; ++r) {
                float v = acc[nt][r];
                int o = ot * 64 + nt * 16 + lo;
                long row = row0 + wave * 16 + hi * 4 + r;
                if (BIAS_E) v += bias[o];
                if (GELU_E) v = 0.5f * v * (1.0f + erff(v * 0.70710678118654752f));
                if (GROUPED) {
                    int g = o >> 5, dc = o & 31;
                    ((f16*)out)[((long)g * 131072 + row) * 32 + dc] = (f16)v;
                } else if (OUT_F32) {
                    ((float*)out)[row * N + o] = v;
                } else {
                    ((f16*)out)[row * N + o] = (f16)v;
                }
            }
        }
    }
}

// ---------------------------------------------------------------------------
// Fused depthwise-3x3 conv + xifft residual + windowed attention, per (b,h).
// T grouped [18][131072][32]: staging is f16x8-coalesced. Q rows live in
// registers (4-lane shfl). LDS 43.6KB -> 3 blocks/CU.
// ---------------------------------------------------------------------------
__global__ __launch_bounds__(256) void k_attn(
    const f16* __restrict__ T, const f16* __restrict__ xifft,
    const float* __restrict__ dww, const float* __restrict__ dwb,
    f16* __restrict__ obnc)
{
    __shared__ f16 tb[32 * 3 * 66];       // [d][r][n+pad]
    __shared__ float wd[96 * 9];
    __shared__ float bd[96];
    __shared__ float ks[64 * 36], vs[64 * 36];
    __shared__ f16 bs[64 * 68];
    const int b = blockIdx.x, h = blockIdx.y, tid = threadIdx.x;
    const int n = tid >> 2, cth = tid & 3;     // thread owns (n, d=cth*8..+7)

    for (int idx = tid; idx < 864; idx += 256) {
        int c3 = idx / 9, w9 = idx - c3 * 9;
        int s = c3 >> 5, d = c3 & 31;
        wd[idx] = dww[(s * 192 + h * 32 + d) * 9 + w9];
    }
    if (tid < 96) {
        int s = tid >> 5, d = tid & 31;
        bd[tid] = dwb[s * 192 + h * 32 + d];
    }
    for (int idx = tid; idx < 1024; idx += 256) {
        f16x4 v = *(const f16x4*)&g_biasg[h * 4096 + idx * 4];
        int r = idx >> 4, c = (idx & 15) * 4;
        *(f16x4*)&bs[r * 68 + c] = v;
    }

    // xifft chunk for this thread (reused for q,k,v)
    float xf[8];
    {
        f16x8 v = *(const f16x8*)&xifft[(long)b * 12288 + h * 2048 + n * 32 + cth * 8];
        #pragma unroll
        for (int j = 0; j < 8; ++j) xf[j] = (float)v[j];
    }

    float q8[8];
    for (int s = 0; s < 3; ++s) {
        __syncthreads();
        if (tid < 96) {   // zero halo pads: tid = d*3+r
            tb[tid * 66] = (f16)0.f;
            tb[tid * 66 + 65] = (f16)0.f;
        }
        for (int idx = tid; idx < 768; idx += 256) {
            int r = idx >> 8, rem = idx & 255;
            int nn = rem >> 2, cc = rem & 3;
            int bb = b + r - 1;
            f16x8 v = {};
            if (bb >= 0 && bb < 2048)
                v = *(const f16x8*)&T[((long)(s * 6 + h) * 131072
                                      + (long)bb * 64 + nn) * 32 + cc * 8];
            #pragma unroll
            for (int dd = 0; dd < 8; ++dd)
                tb[((cc * 8 + dd) * 3 + r) * 66 + nn + 1] = v[dd];
        }
        __syncthreads();
        #pragma unroll
        for (int dd = 0; dd < 8; ++dd) {
            int d = cth * 8 + dd;
            float acc = bd[s * 32 + d];
            #pragma unroll
            for (int r = 0; r < 3; ++r)
                #pragma unroll
                for (int j = 0; j < 3; ++j)
                    acc += wd[(s * 32 + d) * 9 + r * 3 + j] *
                           (float)tb[(d * 3 + r) * 66 + n + j];
            acc += xf[dd];
            if (s == 0)      q8[dd] = acc * SCALE_Q;
            else if (s == 1) ks[n * 36 + d] = acc;
            else             vs[n * 36 + d] = acc;
        }
    }
    __syncthreads();

    // assemble full q row via 4-lane shuffles
    float qr[32];
    #pragma unroll
    for (int c = 0; c < 4; ++c)
        #pragma unroll
        for (int dd = 0; dd < 8; ++dd)
            qr[c * 8 + dd] = __shfl(q8[dd], c, 4);

    const int row = n, cg = cth;
    float p[16], mx = -1e30f;
    #pragma unroll
    for (int mm = 0; mm < 16; ++mm) {
        int m = mm * 4 + cg;
        float dot = 0.f;
        #pragma unroll
        for (int k4 = 0; k4 < 8; ++k4) {
            float4v kv = *(const float4v*)&ks[m * 36 + k4 * 4];
            dot += qr[k4*4]*kv.x + qr[k4*4+1]*kv.y + qr[k4*4+2]*kv.z + qr[k4*4+3]*kv.w;
        }
        p[mm] = dot + (float)bs[row * 68 + m];
        mx = fmaxf(mx, p[mm]);
    }
    mx = fmaxf(mx, __shfl_xor(mx, 1));
    mx = fmaxf(mx, __shfl_xor(mx, 2));
    float sum = 0.f;
    #pragma unroll
    for (int mm = 0; mm < 16; ++mm) { p[mm] = __expf(p[mm] - mx); sum += p[mm]; }
    sum += __shfl_xor(sum, 1);
    sum += __shfl_xor(sum, 2);
    const float inv = 1.0f / sum;

    float o[32];
    #pragma unroll
    for (int d = 0; d < 32; ++d) o[d] = 0.f;
    #pragma unroll
    for (int mm = 0; mm < 16; ++mm) {
        float pv = p[mm] * inv;
        int m = mm * 4 + cg;
        #pragma unroll
        for (int d4 = 0; d4 < 8; ++d4) {
            float4v vv = *(const float4v*)&vs[m * 36 + d4 * 4];
            o[d4*4+0] += pv * vv.x; o[d4*4+1] += pv * vv.y;
            o[d4*4+2] += pv * vv.z; o[d4*4+3] += pv * vv.w;
        }
    }
    #pragma unroll
    for (int d = 0; d < 32; ++d) {
        o[d] += __shfl_xor(o[d], 1);
        o[d] += __shfl_xor(o[d], 2);
    }
    f16x8 pk;
    #pragma unroll
    for (int j = 0; j < 8; ++j) pk[j] = (f16)o[cg * 8 + j];
    *(f16x8*)&obnc[(long)(b * 64 + row) * 192 + h * 32 + cg * 8] = pk;
}

// ---------------------------------------------------------------------------
// Launcher. Workspace (f16), 251,658,240 bytes:
//   A [0, 25165824)          : y1 -> y2 -> y3 -> xifft (in-place chain)
//   T [25165824, 100663296)  : qkv conv output, grouped [18][131072][32]
//   O [100663296, 125829120) : obnc [bn][192]
// Bias tile lives in static __device__ memory (g_biasg).
// ---------------------------------------------------------------------------
extern "C" void kernel_launch(void* const* d_in, const int* in_sizes, int n_in,
                              void* d_out, int out_size, void* d_ws, size_t ws_size,
                              hipStream_t stream)
{
    const float* x      = (const float*)d_in[0];
    const float* qkvw   = (const float*)d_in[1];
    const float* qkvb   = (const float*)d_in[2];
    const float* dww    = (const float*)d_in[3];
    const float* dwb    = (const float*)d_in[4];
    const float* q1w    = (const float*)d_in[5];
    const float* q2w    = (const float*)d_in[6];
    const float* rpb    = (const float*)d_in[7];
    const float* projw  = (const float*)d_in[8];
    const float* projb  = (const float*)d_in[9];
    const int*   relidx = (const int*)d_in[10];

    f16* A = (f16*)d_ws;
    f16* T = A + 25165824L;
    f16* O = T + 75497472L;

    k_bias<<<96, 256, 0, stream>>>(rpb, relidx);

    // FFT branch: y1 = ReDFT(x); y2 = gelu(y1 Q1^T); y3 = y2 Q2^T; xifft = ReIDFT(y3)
    k_dft_fwd<<<2048, 256, 0, stream>>>(x, A);
    gemm_mfma<3, true,  false, false, false, false><<<2048, 256, 0, stream>>>(A, q1w, nullptr, A);
    gemm_mfma<3, false, false, false, false, false><<<2048, 256, 0, stream>>>(A, q2w, nullptr, A);
    k_dft_inv<<<2048, 256, 0, stream>>>(A, A);

    // t = x @ qkv_w^T + qkv_b  (grouped layout [18][bn][32], f16)
    gemm_mfma<9, false, true, true, false, true><<<2048, 256, 0, stream>>>(x, qkvw, qkvb, T);

    // fused depthwise conv + residual + attention -> obnc f16
    k_attn<<<dim3(2048, 6), 256, 0, stream>>>(T, A, dww, dwb, O);

    // final projection -> d_out f32
    gemm_mfma<3, false, true, false, true, false><<<2048, 256, 0, stream>>>(O, projw, projb, (float*)d_out);
}

// Round 5
// 702.417 us; speedup vs baseline: 4.6460x; 1.8627x over previous
//
#include <hip/hip_runtime.h>
#include <math.h>

// B=2048 windows, N=64 tokens, C=192 channels, 6 heads x 32 dim, 3C=576
#define SCALE_Q 0.17677669529663687f

typedef _Float16 f16;
typedef _Float16 f16x4 __attribute__((ext_vector_type(4)));
typedef _Float16 f16x8 __attribute__((ext_vector_type(8)));
typedef float float4v __attribute__((ext_vector_type(4)));

__device__ const float c8tab[8] = {
    1.f, 0.70710678118654752f, 0.f, -0.70710678118654752f,
   -1.f, -0.70710678118654752f, 0.f, 0.70710678118654752f};

// Precomputed relative-position bias tile [6][64][64] (f16)
__device__ f16 g_biasg[6 * 64 * 64];

__global__ __launch_bounds__(256) void k_bias(const float* __restrict__ rpb,
                                              const int* __restrict__ relidx)
{
    int idx = blockIdx.x * 256 + threadIdx.x;   // 0..24575
    if (idx < 24576) {
        int h = idx >> 12, nm = idx & 4095;
        g_biasg[h * 4096 + nm] = (f16)rpb[relidx[nm] * 6 + h];
    }
}

// ---------------------------------------------------------------------------
// Forward 2D real-DFT: y1[b][uv][c] = sum_hw cos(2pi(uh+vw)/8) x[b][hw][c]
// ---------------------------------------------------------------------------
__global__ __launch_bounds__(256) void k_dft_fwd(const float* __restrict__ x,
                                                 f16* __restrict__ y1)
{
    __shared__ float xs[64 * 196];
    __shared__ float lutf[4096];
    const int b = blockIdx.x, tid = threadIdx.x;
    const long gbase = (long)b * 12288;
    for (int idx = tid; idx < 3072; idx += 256) {
        int r = idx / 48, c4 = idx % 48;
        *(float4v*)&xs[r * 196 + c4 * 4] =
            *(const float4v*)&x[gbase + r * 192 + c4 * 4];
    }
    for (int idx = tid; idx < 4096; idx += 256) {
        int uv = idx >> 6, hw = idx & 63;
        int k = ((uv >> 3) * (hw >> 3) + (uv & 7) * (hw & 7)) & 7;
        lutf[idx] = c8tab[k];
    }
    __syncthreads();
    for (int oi = 0; oi < 12; ++oi) {
        int idx = oi * 256 + tid;
        int uv = idx / 48, c4 = idx % 48;
        float4v acc = {0.f, 0.f, 0.f, 0.f};
        #pragma unroll 8
        for (int hw = 0; hw < 64; ++hw) {
            float s = lutf[uv * 64 + hw];
            float4v xv = *(const float4v*)&xs[hw * 196 + c4 * 4];
            acc += s * xv;
        }
        f16x4 o4 = {(f16)acc.x, (f16)acc.y, (f16)acc.z, (f16)acc.w};
        *(f16x4*)&y1[gbase + uv * 192 + c4 * 4] = o4;
    }
}

// ---------------------------------------------------------------------------
// Inverse 2D real-DFT (in-place safe)
// ---------------------------------------------------------------------------
__global__ __launch_bounds__(256) void k_dft_inv(const f16* __restrict__ y3,
                                                 f16* __restrict__ xifft)
{
    __shared__ float ys[64 * 196];
    __shared__ float Lf[64 * 68];
    const int b = blockIdx.x, tid = threadIdx.x;
    const long gbase = (long)b * 12288;
    for (int idx = tid; idx < 1536; idx += 256) {
        int uv = idx / 24, o8 = idx % 24;
        f16x8 v = *(const f16x8*)&y3[gbase + uv * 192 + o8 * 8];
        #pragma unroll
        for (int j = 0; j < 8; ++j) ys[uv * 196 + o8 * 8 + j] = (float)v[j];
    }
    for (int idx = tid; idx < 4096; idx += 256) {
        int uv = idx >> 6, hw = idx & 63;
        int k = ((uv >> 3) * (hw >> 3) + (uv & 7) * (hw & 7)) & 7;
        Lf[uv * 68 + hw] = c8tab[k] * (1.f / 64.f);
    }
    __syncthreads();
    for (int oi = 0; oi < 12; ++oi) {
        int idx = oi * 256 + tid;
        int o = idx >> 4, hw4 = idx & 15;
        float4v acc = {0.f, 0.f, 0.f, 0.f};
        #pragma unroll 8
        for (int uv = 0; uv < 64; ++uv) {
            float s = ys[uv * 196 + o];
            float4v lv = *(const float4v*)&Lf[uv * 68 + hw4 * 4];
            acc += s * lv;
        }
        f16x4 o4 = {(f16)acc.x, (f16)acc.y, (f16)acc.z, (f16)acc.w};
        *(f16x4*)&xifft[gbase + o * 64 + hw4 * 4] = o4;
    }
}

// ---------------------------------------------------------------------------
// fp16 MFMA GEMM, K=192. GROUPED=true writes out[(o/32)][row][o%32] (f16);
// else row-major [M][NT*64].
// ---------------------------------------------------------------------------
template<int NT, bool GELU_E, bool BIAS_E, bool A_F32, bool OUT_F32, bool GROUPED>
__global__ __launch_bounds__(256) void gemm_mfma(
    const void* __restrict__ Ain, const float* __restrict__ W,
    const float* __restrict__ bias, void* __restrict__ out)
{
    __shared__ f16 As[64 * 200];
    __shared__ f16 Ws[64 * 200];
    const int tid = threadIdx.x;
    const long row0 = (long)blockIdx.x * 64;
    constexpr int N = NT * 64;

    if (A_F32) {
        const float* A = (const float*)Ain;
        for (int idx = tid; idx < 3072; idx += 256) {
            int r = idx / 48, c4 = idx % 48;
            float4v v = *(const float4v*)&A[(row0 + r) * 192 + c4 * 4];
            f16x4 hv = {(f16)v.x, (f16)v.y, (f16)v.z, (f16)v.w};
            *(f16x4*)&As[r * 200 + c4 * 4] = hv;
        }
    } else {
        const f16* A = (const f16*)Ain;
        for (int idx = tid; idx < 3072; idx += 256) {
            int r = idx / 48, c4 = idx % 48;
            *(f16x4*)&As[r * 200 + c4 * 4] =
                *(const f16x4*)&A[(row0 + r) * 192 + c4 * 4];
        }
    }
    const int wave = tid >> 6, l = tid & 63, lo = l & 15, hi = l >> 4;
    for (int ot = 0; ot < NT; ++ot) {
        __syncthreads();
        for (int idx = tid; idx < 3072; idx += 256) {
            int r = idx / 48, c4 = idx % 48;
            float4v v = *(const float4v*)&W[(long)(ot * 64 + r) * 192 + c4 * 4];
            f16x4 hv = {(f16)v.x, (f16)v.y, (f16)v.z, (f16)v.w};
            *(f16x4*)&Ws[r * 200 + c4 * 4] = hv;
        }
        __syncthreads();
        float4v acc[4];
        #pragma unroll
        for (int nt = 0; nt < 4; ++nt) acc[nt] = (float4v){0.f, 0.f, 0.f, 0.f};
        #pragma unroll
        for (int kc = 0; kc < 6; ++kc) {
            f16x8 a = *(const f16x8*)&As[(wave * 16 + lo) * 200 + kc * 32 + hi * 8];
            #pragma unroll
            for (int nt = 0; nt < 4; ++nt) {
                f16x8 bfr = *(const f16x8*)&Ws[(nt * 16 + lo) * 200 + kc * 32 + hi * 8];
                acc[nt] = __builtin_amdgcn_mfma_f32_16x16x32_f16(a, bfr, acc[nt], 0, 0, 0);
            }
        }
        #pragma unroll
        for (int nt = 0; nt < 4; ++nt) {
            #pragma unroll
            for (int r = 0; r < 4; ++r) {
                float v = acc[nt][r];
                int o = ot * 64 + nt * 16 + lo;
                long row = row0 + wave * 16 + hi * 4 + r;
                if (BIAS_E) v += bias[o];
                if (GELU_E) v = 0.5f * v * (1.0f + erff(v * 0.70710678118654752f));
                if (GROUPED) {
                    int g = o >> 5, dc = o & 31;
                    ((f16*)out)[((long)g * 131072 + row) * 32 + dc] = (f16)v;
                } else if (OUT_F32) {
                    ((float*)out)[row * N + o] = v;
                } else {
                    ((f16*)out)[row * N + o] = (f16)v;
                }
            }
        }
    }
}

// ---------------------------------------------------------------------------
// Fused depthwise-3x3 conv + xifft residual + MFMA windowed attention.
// One block per (b,h). Thread (n = tid>>2, cth = tid&3) computes conv for
// 8 channels via 9 direct f16x8 global loads (L1 absorbs halo overlap).
// q,k staged [64][40] f16; v transposed [32][72]; P wave-private [64][72].
// QK^T: 4 MFMA/wave; PV: 4 MFMA/wave. Softmax in C-layout registers.
// ---------------------------------------------------------------------------
__global__ __launch_bounds__(256, 4) void k_attn(
    const f16* __restrict__ T, const f16* __restrict__ xifft,
    const float* __restrict__ dww, const float* __restrict__ dwb,
    f16* __restrict__ obnc)
{
    __shared__ f16 qls[64 * 40];
    __shared__ f16 kls[64 * 40];
    __shared__ f16 vtl[32 * 72];
    __shared__ f16 pls[64 * 72];
    __shared__ f16 bs[64 * 68];
    __shared__ float wd[864];
    __shared__ float bd[96];
    const int b = blockIdx.x, h = blockIdx.y, tid = threadIdx.x;
    const int n = tid >> 2, cth = tid & 3;

    for (int idx = tid; idx < 864; idx += 256) {
        int c3 = idx / 9, w9 = idx - c3 * 9;
        int s = c3 >> 5, d = c3 & 31;
        wd[idx] = dww[(s * 192 + h * 32 + d) * 9 + w9];
    }
    if (tid < 96) {
        int s = tid >> 5, d = tid & 31;
        bd[tid] = dwb[s * 192 + h * 32 + d];
    }
    for (int idx = tid; idx < 1024; idx += 256) {
        f16x4 v = *(const f16x4*)&g_biasg[h * 4096 + idx * 4];
        *(f16x4*)&bs[(idx >> 4) * 68 + (idx & 15) * 4] = v;
    }

    // xifft chunk for this thread (reused for q,k,v)
    float xf[8];
    {
        f16x8 v = *(const f16x8*)&xifft[(long)b * 12288 + h * 2048 + n * 32 + cth * 8];
        #pragma unroll
        for (int j = 0; j < 8; ++j) xf[j] = (float)v[j];
    }
    __syncthreads();

    // ---- depthwise conv, 3 s-phases ----
    #pragma unroll
    for (int s = 0; s < 3; ++s) {
        const f16* Tg = T + ((long)(s * 6 + h) * 131072) * 32;
        f16x8 tv[3][3];
        #pragma unroll
        for (int r = 0; r < 3; ++r) {
            int bb = b + r - 1;
            bool vb = (bb >= 0 && bb < 2048);
            #pragma unroll
            for (int j = 0; j < 3; ++j) {
                int nn = n + j - 1;
                f16x8 v = {};
                if (vb && nn >= 0 && nn < 64)
                    v = *(const f16x8*)&Tg[((long)bb * 64 + nn) * 32 + cth * 8];
                tv[r][j] = v;
            }
        }
        float a8[8];
        #pragma unroll
        for (int dd = 0; dd < 8; ++dd) {
            int d = cth * 8 + dd;
            float acc = bd[s * 32 + d];
            #pragma unroll
            for (int r = 0; r < 3; ++r)
                #pragma unroll
                for (int j = 0; j < 3; ++j)
                    acc += wd[(s * 32 + d) * 9 + r * 3 + j] * (float)tv[r][j][dd];
            a8[dd] = acc + xf[dd];
        }
        if (s == 0) {
            f16x8 o;
            #pragma unroll
            for (int dd = 0; dd < 8; ++dd) o[dd] = (f16)(a8[dd] * SCALE_Q);
            *(f16x8*)&qls[n * 40 + cth * 8] = o;
        } else if (s == 1) {
            f16x8 o;
            #pragma unroll
            for (int dd = 0; dd < 8; ++dd) o[dd] = (f16)a8[dd];
            *(f16x8*)&kls[n * 40 + cth * 8] = o;
        } else {
            #pragma unroll
            for (int dd = 0; dd < 8; ++dd)
                vtl[(cth * 8 + dd) * 72 + n] = (f16)a8[dd];
        }
    }
    __syncthreads();

    // ---- QK^T via MFMA ----
    const int w = tid >> 6, l = tid & 63, lo = l & 15, hi = l >> 4;
    f16x8 qfrag = *(const f16x8*)&qls[(w * 16 + lo) * 40 + hi * 8];
    float4v accq[4];
    #pragma unroll
    for (int mt = 0; mt < 4; ++mt) {
        f16x8 kfrag = *(const f16x8*)&kls[(mt * 16 + lo) * 40 + hi * 8];
        accq[mt] = __builtin_amdgcn_mfma_f32_16x16x32_f16(
            qfrag, kfrag, (float4v){0.f, 0.f, 0.f, 0.f}, 0, 0, 0);
    }

    // ---- bias + softmax in C-layout registers ----
    float pv[4][4];   // [mt][r]: row = w*16+hi*4+r, col = mt*16+lo
    #pragma unroll
    for (int mt = 0; mt < 4; ++mt)
        #pragma unroll
        for (int r = 0; r < 4; ++r)
            pv[mt][r] = accq[mt][r] +
                        (float)bs[(w * 16 + hi * 4 + r) * 68 + mt * 16 + lo];
    float inv[4];
    #pragma unroll
    for (int r = 0; r < 4; ++r) {
        float mx = fmaxf(fmaxf(pv[0][r], pv[1][r]), fmaxf(pv[2][r], pv[3][r]));
        mx = fmaxf(mx, __shfl_xor(mx, 1));
        mx = fmaxf(mx, __shfl_xor(mx, 2));
        mx = fmaxf(mx, __shfl_xor(mx, 4));
        mx = fmaxf(mx, __shfl_xor(mx, 8));
        float sum = 0.f;
        #pragma unroll
        for (int mt = 0; mt < 4; ++mt) {
            pv[mt][r] = __expf(pv[mt][r] - mx);
            sum += pv[mt][r];
        }
        sum += __shfl_xor(sum, 1);
        sum += __shfl_xor(sum, 2);
        sum += __shfl_xor(sum, 4);
        sum += __shfl_xor(sum, 8);
        inv[r] = 1.0f / sum;
    }
    #pragma unroll
    for (int mt = 0; mt < 4; ++mt)
        #pragma unroll
        for (int r = 0; r < 4; ++r)
            pls[(w * 16 + hi * 4 + r) * 72 + mt * 16 + lo] =
                (f16)(pv[mt][r] * inv[r]);
    // wave-private rows: no barrier needed (compiler inserts lgkmcnt wait)

    // ---- PV via MFMA ----
    float4v acco[2] = {(float4v){0.f,0.f,0.f,0.f}, (float4v){0.f,0.f,0.f,0.f}};
    #pragma unroll
    for (int kc = 0; kc < 2; ++kc) {
        f16x8 pfrag = *(const f16x8*)&pls[(w * 16 + lo) * 72 + kc * 32 + hi * 8];
        #pragma unroll
        for (int dt = 0; dt < 2; ++dt) {
            f16x8 vfrag = *(const f16x8*)&vtl[(dt * 16 + lo) * 72 + kc * 32 + hi * 8];
            acco[dt] = __builtin_amdgcn_mfma_f32_16x16x32_f16(pfrag, vfrag, acco[dt], 0, 0, 0);
        }
    }
    #pragma unroll
    for (int dt = 0; dt < 2; ++dt)
        #pragma unroll
        for (int r = 0; r < 4; ++r)
            obnc[(long)(b * 64 + w * 16 + hi * 4 + r) * 192 + h * 32 + dt * 16 + lo] =
                (f16)acco[dt][r];
}

// ---------------------------------------------------------------------------
// Launcher. Workspace (f16), 251,658,240 bytes:
//   A [0, 25165824)          : y1 -> y2 -> y3 -> xifft (in-place chain)
//   T [25165824, 100663296)  : qkv conv output, grouped [18][131072][32]
//   O [100663296, 125829120) : obnc [bn][192]
// ---------------------------------------------------------------------------
extern "C" void kernel_launch(void* const* d_in, const int* in_sizes, int n_in,
                              void* d_out, int out_size, void* d_ws, size_t ws_size,
                              hipStream_t stream)
{
    const float* x      = (const float*)d_in[0];
    const float* qkvw   = (const float*)d_in[1];
    const float* qkvb   = (const float*)d_in[2];
    const float* dww    = (const float*)d_in[3];
    const float* dwb    = (const float*)d_in[4];
    const float* q1w    = (const float*)d_in[5];
    const float* q2w    = (const float*)d_in[6];
    const float* rpb    = (const float*)d_in[7];
    const float* projw  = (const float*)d_in[8];
    const float* projb  = (const float*)d_in[9];
    const int*   relidx = (const int*)d_in[10];

    f16* A = (f16*)d_ws;
    f16* T = A + 25165824L;
    f16* O = T + 75497472L;

    k_bias<<<96, 256, 0, stream>>>(rpb, relidx);

    // FFT branch: y1 = ReDFT(x); y2 = gelu(y1 Q1^T); y3 = y2 Q2^T; xifft = ReIDFT(y3)
    k_dft_fwd<<<2048, 256, 0, stream>>>(x, A);
    gemm_mfma<3, true,  false, false, false, false><<<2048, 256, 0, stream>>>(A, q1w, nullptr, A);
    gemm_mfma<3, false, false, false, false, false><<<2048, 256, 0, stream>>>(A, q2w, nullptr, A);
    k_dft_inv<<<2048, 256, 0, stream>>>(A, A);

    // t = x @ qkv_w^T + qkv_b  (grouped layout [18][bn][32], f16)
    gemm_mfma<9, false, true, true, false, true><<<2048, 256, 0, stream>>>(x, qkvw, qkvb, T);

    // fused depthwise conv + residual + MFMA attention -> obnc f16
    k_attn<<<dim3(2048, 6), 256, 0, stream>>>(T, A, dww, dwb, O);

    // final projection -> d_out f32
    gemm_mfma<3, false, true, false, true, false><<<2048, 256, 0, stream>>>(O, projw, projb, (float*)d_out);
}

// Round 6
// 491.805 us; speedup vs baseline: 6.6357x; 1.4282x over previous
//
#include <hip/hip_runtime.h>
#include <math.h>

// B=2048 windows, N=64 tokens, C=192 channels, 6 heads x 32 dim, 3C=576
#define SCALE_Q 0.17677669529663687f

typedef _Float16 f16;
typedef _Float16 f16x4 __attribute__((ext_vector_type(4)));
typedef _Float16 f16x8 __attribute__((ext_vector_type(8)));
typedef float float4v __attribute__((ext_vector_type(4)));

__device__ const float c8tab[8] = {
    1.f, 0.70710678118654752f, 0.f, -0.70710678118654752f,
   -1.f, -0.70710678118654752f, 0.f, 0.70710678118654752f};

// Precomputed relative-position bias tile [6][64][64] (f16), L2-hot at use.
__device__ f16 g_biasg[6 * 64 * 64];

// ---------------------------------------------------------------------------
// Prep: convert all weights to f16 (wbuf) + build bias tile. One-time, tiny.
// wbuf: [0,110592) qkvw | [110592,147456) q1 | [147456,184320) q2 | [184320,221184) proj
// ---------------------------------------------------------------------------
__global__ __launch_bounds__(256) void k_prep(
    const float* __restrict__ qkvw, const float* __restrict__ q1w,
    const float* __restrict__ q2w, const float* __restrict__ projw,
    const float* __restrict__ rpb, const int* __restrict__ relidx,
    f16* __restrict__ wbuf)
{
    int idx = blockIdx.x * 256 + threadIdx.x;
    if (idx < 110592)      wbuf[idx] = (f16)qkvw[idx];
    else if (idx < 147456) wbuf[idx] = (f16)q1w[idx - 110592];
    else if (idx < 184320) wbuf[idx] = (f16)q2w[idx - 147456];
    else if (idx < 221184) wbuf[idx] = (f16)projw[idx - 184320];
    else if (idx < 245760) {
        int i = idx - 221184;
        int h = i >> 12, nm = i & 4095;
        g_biasg[h * 4096 + nm] = (f16)rpb[relidx[nm] * 6 + h];
    }
}

// ---------------------------------------------------------------------------
// Fully fused FFT branch, one block per window:
//   xifft = ReIDFT( (gelu(ReDFT(x) @ q1^T)) @ q2^T )
// 4 MFMA phases over LDS; weights' B-fragments read from L2 (f16, row-major).
// LDS: xT[192][72] (also y3T), y1[64][200] (also y2 in-place), L[64][72].
// Barriers: stage | ph1 (protect xT->y3T) | ph3 (y3T visible). 62.5 KB -> 2 blk/CU.
// ---------------------------------------------------------------------------
__global__ __launch_bounds__(256) void k_fft(
    const float* __restrict__ x, const f16* __restrict__ q1h,
    const f16* __restrict__ q2h, f16* __restrict__ xifft)
{
    __shared__ f16 xT[192 * 72];   // x^T, later y3^T
    __shared__ f16 y1[64 * 200];   // y1, later y2 (in-place)
    __shared__ f16 L[64 * 72];     // DFT cos matrix (symmetric)
    const int b = blockIdx.x, tid = threadIdx.x;
    const long gbase = (long)b * 12288;
    const int w = tid >> 6, l = tid & 63, lo = l & 15, hi = l >> 4;

    // stage x transposed: per iter all lanes share c4, vary hw -> LDS conflict-free
    #pragma unroll
    for (int it = 0; it < 12; ++it) {
        int idx = tid + it * 256;
        int hw = idx & 63, c4 = idx >> 6;
        float4v v = *(const float4v*)&x[gbase + hw * 192 + c4 * 4];
        xT[(c4 * 4 + 0) * 72 + hw] = (f16)v.x;
        xT[(c4 * 4 + 1) * 72 + hw] = (f16)v.y;
        xT[(c4 * 4 + 2) * 72 + hw] = (f16)v.z;
        xT[(c4 * 4 + 3) * 72 + hw] = (f16)v.w;
    }
    for (int idx = tid; idx < 4096; idx += 256) {
        int uv = idx >> 6, hw = idx & 63;
        int k = ((uv >> 3) * (hw >> 3) + (uv & 7) * (hw & 7)) & 7;
        L[uv * 72 + hw] = (f16)c8tab[k];
    }
    __syncthreads();

    // phase 1: y1[uv][c] = sum_hw L[uv][hw] * xT[c][hw]
    {
        float4v acc[12];
        #pragma unroll
        for (int nt = 0; nt < 12; ++nt) acc[nt] = (float4v){0.f,0.f,0.f,0.f};
        #pragma unroll
        for (int kc = 0; kc < 2; ++kc) {
            f16x8 a = *(const f16x8*)&L[(w * 16 + lo) * 72 + kc * 32 + hi * 8];
            #pragma unroll
            for (int nt = 0; nt < 12; ++nt) {
                f16x8 bf = *(const f16x8*)&xT[(nt * 16 + lo) * 72 + kc * 32 + hi * 8];
                acc[nt] = __builtin_amdgcn_mfma_f32_16x16x32_f16(a, bf, acc[nt], 0, 0, 0);
            }
        }
        #pragma unroll
        for (int nt = 0; nt < 12; ++nt)
            #pragma unroll
            for (int r = 0; r < 4; ++r)
                y1[(w * 16 + hi * 4 + r) * 200 + nt * 16 + lo] = (f16)acc[nt][r];
    }
    __syncthreads();

    // phase 2: y2 = gelu(y1 @ q1^T), in-place (reads complete before writes;
    // rows are wave-own -> no barrier)
    {
        float4v acc[12];
        #pragma unroll
        for (int nt = 0; nt < 12; ++nt) acc[nt] = (float4v){0.f,0.f,0.f,0.f};
        for (int kc = 0; kc < 6; ++kc) {
            f16x8 a = *(const f16x8*)&y1[(w * 16 + lo) * 200 + kc * 32 + hi * 8];
            #pragma unroll
            for (int nt = 0; nt < 12; ++nt) {
                f16x8 bf = *(const f16x8*)&q1h[(nt * 16 + lo) * 192 + kc * 32 + hi * 8];
                acc[nt] = __builtin_amdgcn_mfma_f32_16x16x32_f16(a, bf, acc[nt], 0, 0, 0);
            }
        }
        #pragma unroll
        for (int nt = 0; nt < 12; ++nt)
            #pragma unroll
            for (int r = 0; r < 4; ++r) {
                float v = acc[nt][r];
                v = 0.5f * v * (1.0f + erff(v * 0.70710678118654752f));
                y1[(w * 16 + hi * 4 + r) * 200 + nt * 16 + lo] = (f16)v;
            }
    }
    // phase 3: y3 = y2 @ q2^T, stored transposed into xT (dead after bar above)
    {
        float4v acc[12];
        #pragma unroll
        for (int nt = 0; nt < 12; ++nt) acc[nt] = (float4v){0.f,0.f,0.f,0.f};
        for (int kc = 0; kc < 6; ++kc) {
            f16x8 a = *(const f16x8*)&y1[(w * 16 + lo) * 200 + kc * 32 + hi * 8];
            #pragma unroll
            for (int nt = 0; nt < 12; ++nt) {
                f16x8 bf = *(const f16x8*)&q2h[(nt * 16 + lo) * 192 + kc * 32 + hi * 8];
                acc[nt] = __builtin_amdgcn_mfma_f32_16x16x32_f16(a, bf, acc[nt], 0, 0, 0);
            }
        }
        #pragma unroll
        for (int nt = 0; nt < 12; ++nt)
            #pragma unroll
            for (int r = 0; r < 4; ++r)
                xT[(nt * 16 + lo) * 72 + (w * 16 + hi * 4 + r)] = (f16)acc[nt][r];
    }
    __syncthreads();

    // phase 4: xifft[o][hw] = (1/64) sum_uv y3T[o][uv] * L[hw][uv]
    #pragma unroll
    for (int mt3 = 0; mt3 < 3; ++mt3) {
        int mt = w * 3 + mt3;
        float4v acc[4];
        #pragma unroll
        for (int nt = 0; nt < 4; ++nt) acc[nt] = (float4v){0.f,0.f,0.f,0.f};
        #pragma unroll
        for (int kc = 0; kc < 2; ++kc) {
            f16x8 a = *(const f16x8*)&xT[(mt * 16 + lo) * 72 + kc * 32 + hi * 8];
            #pragma unroll
            for (int nt = 0; nt < 4; ++nt) {
                f16x8 bf = *(const f16x8*)&L[(nt * 16 + lo) * 72 + kc * 32 + hi * 8];
                acc[nt] = __builtin_amdgcn_mfma_f32_16x16x32_f16(a, bf, acc[nt], 0, 0, 0);
            }
        }
        #pragma unroll
        for (int nt = 0; nt < 4; ++nt)
            #pragma unroll
            for (int r = 0; r < 4; ++r)
                xifft[gbase + (mt * 16 + hi * 4 + r) * 64 + nt * 16 + lo] =
                    (f16)(acc[nt][r] * (1.f / 64.f));
    }
}

// ---------------------------------------------------------------------------
// fp16 MFMA GEMM, K=192, W pre-converted f16 [N][192].
// GROUPED: out[(o/32)][row][o%32] f16, LDS-bounced -> f16x8 coalesced stores.
// OUT_F32: row-major f32, LDS-bounced -> float4 stores.
// ---------------------------------------------------------------------------
template<int NT, bool BIAS_E, bool A_F32, bool OUT_F32, bool GROUPED>
__global__ __launch_bounds__(256) void gemm_mfma(
    const void* __restrict__ Ain, const f16* __restrict__ W,
    const float* __restrict__ bias, void* __restrict__ out)
{
    __shared__ f16 As[64 * 200];
    __shared__ f16 Ws[64 * 200];   // doubles as epilogue bounce buffer
    const int tid = threadIdx.x;
    const long row0 = (long)blockIdx.x * 64;
    const int w = tid >> 6, l = tid & 63, lo = l & 15, hi = l >> 4;

    if (A_F32) {
        const float* A = (const float*)Ain;
        for (int idx = tid; idx < 3072; idx += 256) {
            int r = idx / 48, c4 = idx % 48;
            float4v v = *(const float4v*)&A[(row0 + r) * 192 + c4 * 4];
            f16x4 hv = {(f16)v.x, (f16)v.y, (f16)v.z, (f16)v.w};
            *(f16x4*)&As[r * 200 + c4 * 4] = hv;
        }
    } else {
        const f16* A = (const f16*)Ain;
        for (int idx = tid; idx < 1536; idx += 256) {
            int r = idx / 24, c8 = idx % 24;
            *(f16x8*)&As[r * 200 + c8 * 8] =
                *(const f16x8*)&A[(row0 + r) * 192 + c8 * 8];
        }
    }
    for (int ot = 0; ot < NT; ++ot) {
        __syncthreads();   // As staged / previous bounce reads done
        for (int idx = tid; idx < 1536; idx += 256) {
            int r = idx / 24, c8 = idx % 24;
            *(f16x8*)&Ws[r * 200 + c8 * 8] =
                *(const f16x8*)&W[(long)(ot * 64 + r) * 192 + c8 * 8];
        }
        __syncthreads();
        float4v acc[4];
        #pragma unroll
        for (int nt = 0; nt < 4; ++nt) acc[nt] = (float4v){0.f,0.f,0.f,0.f};
        #pragma unroll
        for (int kc = 0; kc < 6; ++kc) {
            f16x8 a = *(const f16x8*)&As[(w * 16 + lo) * 200 + kc * 32 + hi * 8];
            #pragma unroll
            for (int nt = 0; nt < 4; ++nt) {
                f16x8 bf = *(const f16x8*)&Ws[(nt * 16 + lo) * 200 + kc * 32 + hi * 8];
                acc[nt] = __builtin_amdgcn_mfma_f32_16x16x32_f16(a, bf, acc[nt], 0, 0, 0);
            }
        }
        __syncthreads();   // all waves' Ws reads done before bounce overwrite
        if (GROUPED) {
            f16* bw = Ws;  // [64][72]
            #pragma unroll
            for (int nt = 0; nt < 4; ++nt)
                #pragma unroll
                for (int r = 0; r < 4; ++r) {
                    float v = acc[nt][r];
                    if (BIAS_E) v += bias[ot * 64 + nt * 16 + lo];
                    bw[(w * 16 + hi * 4 + r) * 72 + nt * 16 + lo] = (f16)v;
                }
            int row = w * 16 + (l >> 2);
            #pragma unroll
            for (int j = 0; j < 2; ++j) {
                int col = (l & 3) * 16 + j * 8;
                f16x8 v = *(const f16x8*)&bw[row * 72 + col];
                int o = ot * 64 + col;
                *(f16x8*)&((f16*)out)[((long)(o >> 5) * 131072 + row0 + row) * 32 + (o & 31)] = v;
            }
        } else if (OUT_F32) {
            float* bwf = (float*)Ws;  // [64][68]
            #pragma unroll
            for (int nt = 0; nt < 4; ++nt)
                #pragma unroll
                for (int r = 0; r < 4; ++r) {
                    float v = acc[nt][r];
                    if (BIAS_E) v += bias[ot * 64 + nt * 16 + lo];
                    bwf[(w * 16 + hi * 4 + r) * 68 + nt * 16 + lo] = v;
                }
            int row = w * 16 + (l >> 2);
            #pragma unroll
            for (int j = 0; j < 4; ++j) {
                int c4 = ((l & 3) + j * 4) * 4;
                float4v v = *(const float4v*)&bwf[row * 68 + c4];
                *(float4v*)&((float*)out)[(row0 + row) * (NT * 64) + ot * 64 + c4] = v;
            }
        }
    }
}

// ---------------------------------------------------------------------------
// Fused depthwise-3x3 conv + xifft residual + MFMA windowed attention.
// One block per (b,h). Halo rows staged in tb per s-phase (coalesced f16x8);
// conv weights vectorized [s][rj][32]; bias from g_biasg (L2); output bounced
// through dead qls. LDS 38.6 KB -> 4 blocks/CU.
// ---------------------------------------------------------------------------
__global__ __launch_bounds__(256, 4) void k_attn(
    const f16* __restrict__ T, const f16* __restrict__ xifft,
    const float* __restrict__ dww, const float* __restrict__ dwb,
    f16* __restrict__ obnc)
{
    __shared__ f16 tb[3 * 66 * 32];   // [r][nn+1][ch]
    __shared__ f16 qls[64 * 40];      // q rows; later output bounce
    __shared__ f16 kls[64 * 40];
    __shared__ f16 vtl[32 * 72];      // v transposed
    __shared__ f16 pls[64 * 72];      // softmax(P)
    __shared__ f16 wd[864];           // [s][rj][32]
    __shared__ float bd[96];
    const int b = blockIdx.x, h = blockIdx.y, tid = threadIdx.x;
    const int n = tid >> 2, cth = tid & 3;

    for (int idx = tid; idx < 864; idx += 256) {
        int s = idx / 288, rj = (idx % 288) >> 5, d = idx & 31;
        wd[idx] = (f16)dww[(s * 192 + h * 32 + d) * 9 + rj];
    }
    if (tid < 96) {
        int s = tid >> 5, d = tid & 31;
        bd[tid] = dwb[s * 192 + h * 32 + d];
    }
    float xf[8];
    {
        f16x8 v = *(const f16x8*)&xifft[(long)b * 12288 + h * 2048 + n * 32 + cth * 8];
        #pragma unroll
        for (int j = 0; j < 8; ++j) xf[j] = (float)v[j];
    }

    for (int s = 0; s < 3; ++s) {
        __syncthreads();   // tb consumers done (s=0: wd/bd staged)
        if (tid < 24) {    // zero n-pads
            int r = tid / 8, pe = (tid >> 2) & 1, cc = tid & 3;
            f16x8 z = {};
            *(f16x8*)&tb[((r * 66) + pe * 65) * 32 + cc * 8] = z;
        }
        #pragma unroll
        for (int it = 0; it < 3; ++it) {
            int idx = tid + it * 256;
            int r = idx >> 8, rem = idx & 255;
            int nn = rem >> 2, cc = rem & 3;
            int bb = b + r - 1;
            f16x8 v = {};
            if (bb >= 0 && bb < 2048)
                v = *(const f16x8*)&T[((long)(s * 6 + h) * 131072
                                      + (long)bb * 64 + nn) * 32 + cc * 8];
            *(f16x8*)&tb[(r * 66 + nn + 1) * 32 + cc * 8] = v;
        }
        __syncthreads();
        float a8[8];
        #pragma unroll
        for (int dd = 0; dd < 8; ++dd) a8[dd] = bd[s * 32 + cth * 8 + dd];
        #pragma unroll
        for (int rj = 0; rj < 9; ++rj) {
            f16x8 tv = *(const f16x8*)&tb[((rj / 3) * 66 + n + rj % 3) * 32 + cth * 8];
            f16x8 wv = *(const f16x8*)&wd[(s * 9 + rj) * 32 + cth * 8];
            #pragma unroll
            for (int dd = 0; dd < 8; ++dd)
                a8[dd] += (float)wv[dd] * (float)tv[dd];
        }
        #pragma unroll
        for (int dd = 0; dd < 8; ++dd) a8[dd] += xf[dd];
        if (s == 0) {
            f16x8 o;
            #pragma unroll
            for (int dd = 0; dd < 8; ++dd) o[dd] = (f16)(a8[dd] * SCALE_Q);
            *(f16x8*)&qls[n * 40 + cth * 8] = o;
        } else if (s == 1) {
            f16x8 o;
            #pragma unroll
            for (int dd = 0; dd < 8; ++dd) o[dd] = (f16)a8[dd];
            *(f16x8*)&kls[n * 40 + cth * 8] = o;
        } else {
            #pragma unroll
            for (int dd = 0; dd < 8; ++dd)
                vtl[(cth * 8 + dd) * 72 + n] = (f16)a8[dd];
        }
    }
    __syncthreads();

    // QK^T (K=32, one MFMA per tile-pair)
    const int w = tid >> 6, l = tid & 63, lo = l & 15, hi = l >> 4;
    f16x8 qfrag = *(const f16x8*)&qls[(w * 16 + lo) * 40 + hi * 8];
    float4v accq[4];
    #pragma unroll
    for (int mt = 0; mt < 4; ++mt) {
        f16x8 kfrag = *(const f16x8*)&kls[(mt * 16 + lo) * 40 + hi * 8];
        accq[mt] = __builtin_amdgcn_mfma_f32_16x16x32_f16(
            qfrag, kfrag, (float4v){0.f, 0.f, 0.f, 0.f}, 0, 0, 0);
    }

    // bias + softmax in C-layout registers
    const f16* bg = g_biasg + h * 4096;
    float pv[4][4];
    #pragma unroll
    for (int mt = 0; mt < 4; ++mt)
        #pragma unroll
        for (int r = 0; r < 4; ++r)
            pv[mt][r] = accq[mt][r] + (float)bg[(w * 16 + hi * 4 + r) * 64 + mt * 16 + lo];
    float inv[4];
    #pragma unroll
    for (int r = 0; r < 4; ++r) {
        float mx = fmaxf(fmaxf(pv[0][r], pv[1][r]), fmaxf(pv[2][r], pv[3][r]));
        mx = fmaxf(mx, __shfl_xor(mx, 1));
        mx = fmaxf(mx, __shfl_xor(mx, 2));
        mx = fmaxf(mx, __shfl_xor(mx, 4));
        mx = fmaxf(mx, __shfl_xor(mx, 8));
        float sum = 0.f;
        #pragma unroll
        for (int mt = 0; mt < 4; ++mt) { pv[mt][r] = __expf(pv[mt][r] - mx); sum += pv[mt][r]; }
        sum += __shfl_xor(sum, 1);
        sum += __shfl_xor(sum, 2);
        sum += __shfl_xor(sum, 4);
        sum += __shfl_xor(sum, 8);
        inv[r] = 1.0f / sum;
    }
    #pragma unroll
    for (int mt = 0; mt < 4; ++mt)
        #pragma unroll
        for (int r = 0; r < 4; ++r)
            pls[(w * 16 + hi * 4 + r) * 72 + mt * 16 + lo] = (f16)(pv[mt][r] * inv[r]);
    // wave-private rows: in-order LDS per wave, no barrier

    // PV
    float4v acco[2] = {(float4v){0.f,0.f,0.f,0.f}, (float4v){0.f,0.f,0.f,0.f}};
    #pragma unroll
    for (int kc = 0; kc < 2; ++kc) {
        f16x8 pfrag = *(const f16x8*)&pls[(w * 16 + lo) * 72 + kc * 32 + hi * 8];
        #pragma unroll
        for (int dt = 0; dt < 2; ++dt) {
            f16x8 vfrag = *(const f16x8*)&vtl[(dt * 16 + lo) * 72 + kc * 32 + hi * 8];
            acco[dt] = __builtin_amdgcn_mfma_f32_16x16x32_f16(pfrag, vfrag, acco[dt], 0, 0, 0);
        }
    }
    // bounce output through qls (dead, wave-own rows) -> coalesced f16x8 stores
    #pragma unroll
    for (int dt = 0; dt < 2; ++dt)
        #pragma unroll
        for (int r = 0; r < 4; ++r)
            qls[(w * 16 + hi * 4 + r) * 40 + dt * 16 + lo] = (f16)acco[dt][r];
    {
        int row = w * 16 + (l >> 2);
        f16x8 ov = *(const f16x8*)&qls[row * 40 + (l & 3) * 8];
        *(f16x8*)&obnc[((long)b * 64 + row) * 192 + h * 32 + (l & 3) * 8] = ov;
    }
}

// ---------------------------------------------------------------------------
// Launcher. Workspace (f16), 252,100,608 bytes:
//   XI [0, 25165824)           : xifft
//   T  [25165824, 100663296)   : qkv conv output, grouped [18][131072][32]
//   O  [100663296, 125829120)  : obnc [bn][192]
//   WB [125829120, +221184)    : f16 weights (qkvw | q1 | q2 | proj)
// ---------------------------------------------------------------------------
extern "C" void kernel_launch(void* const* d_in, const int* in_sizes, int n_in,
                              void* d_out, int out_size, void* d_ws, size_t ws_size,
                              hipStream_t stream)
{
    const float* x      = (const float*)d_in[0];
    const float* qkvw   = (const float*)d_in[1];
    const float* qkvb   = (const float*)d_in[2];
    const float* dww    = (const float*)d_in[3];
    const float* dwb    = (const float*)d_in[4];
    const float* q1w    = (const float*)d_in[5];
    const float* q2w    = (const float*)d_in[6];
    const float* rpb    = (const float*)d_in[7];
    const float* projw  = (const float*)d_in[8];
    const float* projb  = (const float*)d_in[9];
    const int*   relidx = (const int*)d_in[10];

    f16* XI = (f16*)d_ws;
    f16* T  = XI + 25165824L;
    f16* O  = T + 75497472L;
    f16* WB = O + 25165824L;
    f16* qkvh  = WB;
    f16* q1h   = WB + 110592;
    f16* q2h   = WB + 147456;
    f16* projh = WB + 184320;

    k_prep<<<960, 256, 0, stream>>>(qkvw, q1w, q2w, projw, rpb, relidx, WB);

    // fused FFT branch -> xifft
    k_fft<<<2048, 256, 0, stream>>>(x, q1h, q2h, XI);

    // t = x @ qkv_w^T + qkv_b  (grouped [18][bn][32], f16)
    gemm_mfma<9, true, true, false, true><<<2048, 256, 0, stream>>>(x, qkvh, qkvb, T);

    // fused depthwise conv + residual + MFMA attention -> obnc f16
    k_attn<<<dim3(2048, 6), 256, 0, stream>>>(T, XI, dww, dwb, O);

    // final projection -> d_out f32
    gemm_mfma<3, true, false, true, false><<<2048, 256, 0, stream>>>(O, projh, projb, (float*)d_out);
}

// Round 7
// 482.995 us; speedup vs baseline: 6.7567x; 1.0182x over previous
//
#include <hip/hip_runtime.h>
#include <math.h>

// B=2048 windows, N=64 tokens, C=192 channels, 6 heads x 32 dim, 3C=576
#define SCALE_Q 0.17677669529663687f

typedef _Float16 f16;
typedef _Float16 f16x4 __attribute__((ext_vector_type(4)));
typedef _Float16 f16x8 __attribute__((ext_vector_type(8)));
typedef float float4v __attribute__((ext_vector_type(4)));

// Precomputed relative-position bias tile [6][64][64] (f16), L2-hot at use.
__device__ f16 g_biasg[6 * 64 * 64];

// Fast exact-enough GELU: A&S 7.1.26 erf approx, |err| <= 1.5e-7.
__device__ __forceinline__ float gelu_f(float v) {
    float az = fabsf(v) * 0.70710678118654752f;
    float t = 1.0f / fmaf(az, 0.3275911f, 1.0f);
    float p = t * fmaf(t, fmaf(t, fmaf(t, fmaf(t, 1.061405429f, -1.453152027f),
                                       1.421413741f), -0.284496736f), 0.254829592f);
    float erfv = 1.0f - p * __expf(-az * az);
    erfv = copysignf(erfv, v);
    return 0.5f * v * (1.0f + erfv);
}

// ---------------------------------------------------------------------------
// Prep: convert all weights to f16 (wbuf) + build bias tile. One-time, tiny.
// wbuf: [0,110592) qkvw | [110592,147456) q1 | [147456,184320) q2 | [184320,221184) proj
// ---------------------------------------------------------------------------
__global__ __launch_bounds__(256) void k_prep(
    const float* __restrict__ qkvw, const float* __restrict__ q1w,
    const float* __restrict__ q2w, const float* __restrict__ projw,
    const float* __restrict__ rpb, const int* __restrict__ relidx,
    f16* __restrict__ wbuf)
{
    int idx = blockIdx.x * 256 + threadIdx.x;
    if (idx < 110592)      wbuf[idx] = (f16)qkvw[idx];
    else if (idx < 147456) wbuf[idx] = (f16)q1w[idx - 110592];
    else if (idx < 184320) wbuf[idx] = (f16)q2w[idx - 147456];
    else if (idx < 221184) wbuf[idx] = (f16)projw[idx - 184320];
    else if (idx < 245760) {
        int i = idx - 221184;
        int h = i >> 12, nm = i & 4095;
        g_biasg[h * 4096 + nm] = (f16)rpb[relidx[nm] * 6 + h];
    }
}

// ---------------------------------------------------------------------------
// Global transpose: x f32 [131072][192] -> XTg f16 [192][131072].
// 64x64 tiles via padded LDS; coalesced reads and writes.
// ---------------------------------------------------------------------------
__global__ __launch_bounds__(256) void k_xt(const float* __restrict__ x,
                                            f16* __restrict__ XTg)
{
    __shared__ float xs[64 * 65];
    const int bb = blockIdx.x, cg = blockIdx.y, tid = threadIdx.x;
    #pragma unroll
    for (int it = 0; it < 4; ++it) {
        int idx = tid + it * 256;          // 1024 float4 loads
        int r = idx >> 4, c4 = idx & 15;
        float4v v = *(const float4v*)&x[((long)bb * 64 + r) * 192 + cg * 64 + c4 * 4];
        xs[r * 65 + c4 * 4 + 0] = v.x;
        xs[r * 65 + c4 * 4 + 1] = v.y;
        xs[r * 65 + c4 * 4 + 2] = v.z;
        xs[r * 65 + c4 * 4 + 3] = v.w;
    }
    __syncthreads();
    #pragma unroll
    for (int it = 0; it < 2; ++it) {
        int idx = tid + it * 256;          // 512 f16x8 stores
        int oc = idx >> 3, r8 = idx & 7;
        f16x8 o;
        #pragma unroll
        for (int j = 0; j < 8; ++j) o[j] = (f16)xs[(r8 * 8 + j) * 65 + oc];
        *(f16x8*)&XTg[((long)(cg * 64 + oc)) * 131072 + (long)bb * 64 + r8 * 8] = o;
    }
}

// ---------------------------------------------------------------------------
// Fully fused FFT branch, one block (512 thr, 8 waves) per window:
//   xifft = ReIDFT( (gelu(ReDFT(x) @ q1^T)) @ q2^T )
// Wave split: rw = w&3 (row tile), ch = w>>2 (col half).
// DFT matrix L computed per-lane (cos LUT arithmetic), not stored.
// LDS: XT[192][72] (x^T, later y2 [64][216]) + Y[64][200] (y1, later y3T
// [192][64] XOR-swizzled) = 53,248 B.
// ---------------------------------------------------------------------------
__global__ __launch_bounds__(512, 4) void k_fft(
    const f16* __restrict__ XTg, const f16* __restrict__ q1h,
    const f16* __restrict__ q2h, f16* __restrict__ xifft)
{
    __shared__ f16 XT[192 * 72];
    __shared__ f16 Y[64 * 200];
    const int b = blockIdx.x, tid = threadIdx.x;
    const long gbase = (long)b * 12288;
    const int w = tid >> 6, l = tid & 63, lo = l & 15, hi = l >> 4;
    const int rw = w & 3, ch = w >> 2;

    // stage x^T coalesced
    #pragma unroll
    for (int it = 0; it < 3; ++it) {
        int idx = tid + it * 512;
        int c = idx >> 3, g8 = idx & 7;
        *(f16x8*)&XT[c * 72 + g8 * 8] =
            *(const f16x8*)&XTg[(long)c * 131072 + b * 64 + g8 * 8];
    }
    __syncthreads();

    // ph1: y1[uv][c] = sum_hw L[uv][hw] x^T[c][hw]
    {
        f16x8 afr[2];
        int u = (rw * 16 + lo) >> 3, v = (rw * 16 + lo) & 7;
        #pragma unroll
        for (int kc = 0; kc < 2; ++kc) {
            int cg = kc * 4 + hi;
            #pragma unroll
            for (int e = 0; e < 8; ++e) {
                int k = (u * cg + v * e) & 7;
                afr[kc][e] = (f16)__cosf((float)k * 0.78539816339744831f);
            }
        }
        float4v acc[6];
        #pragma unroll
        for (int nt = 0; nt < 6; ++nt) acc[nt] = (float4v){0.f,0.f,0.f,0.f};
        #pragma unroll
        for (int kc = 0; kc < 2; ++kc)
            #pragma unroll
            for (int nt = 0; nt < 6; ++nt) {
                f16x8 bf = *(const f16x8*)&XT[(ch * 96 + nt * 16 + lo) * 72 + kc * 32 + hi * 8];
                acc[nt] = __builtin_amdgcn_mfma_f32_16x16x32_f16(afr[kc], bf, acc[nt], 0, 0, 0);
            }
        #pragma unroll
        for (int nt = 0; nt < 6; ++nt)
            #pragma unroll
            for (int r = 0; r < 4; ++r)
                Y[(rw * 16 + hi * 4 + r) * 200 + ch * 96 + nt * 16 + lo] = (f16)acc[nt][r];
    }
    __syncthreads();

    // ph2: y2 = gelu(y1 @ q1^T) -> XT region, stride 216
    {
        float4v acc[6];
        #pragma unroll
        for (int nt = 0; nt < 6; ++nt) acc[nt] = (float4v){0.f,0.f,0.f,0.f};
        for (int kc = 0; kc < 6; ++kc) {
            f16x8 a = *(const f16x8*)&Y[(rw * 16 + lo) * 200 + kc * 32 + hi * 8];
            #pragma unroll
            for (int nt = 0; nt < 6; ++nt) {
                f16x8 bf = *(const f16x8*)&q1h[(long)(ch * 96 + nt * 16 + lo) * 192 + kc * 32 + hi * 8];
                acc[nt] = __builtin_amdgcn_mfma_f32_16x16x32_f16(a, bf, acc[nt], 0, 0, 0);
            }
        }
        __syncthreads();   // all ph2 y1-reads done before overwriting... (XT region)
        f16* y2 = XT;
        #pragma unroll
        for (int nt = 0; nt < 6; ++nt)
            #pragma unroll
            for (int r = 0; r < 4; ++r)
                y2[(rw * 16 + hi * 4 + r) * 216 + ch * 96 + nt * 16 + lo] =
                    (f16)gelu_f(acc[nt][r]);
    }
    __syncthreads();

    // ph3: y3T[o][uv] = sum_c q2[o][c] y2[uv][c]  -> Y region, swizzled cols
    {
        const f16* y2 = XT;
        float4v acc[6];
        #pragma unroll
        for (int jt = 0; jt < 6; ++jt) acc[jt] = (float4v){0.f,0.f,0.f,0.f};
        for (int kc = 0; kc < 6; ++kc) {
            f16x8 bf[2];
            #pragma unroll
            for (int t = 0; t < 2; ++t)
                bf[t] = *(const f16x8*)&y2[((ch * 2 + t) * 16 + lo) * 216 + kc * 32 + hi * 8];
            #pragma unroll
            for (int j = 0; j < 3; ++j) {
                f16x8 a = *(const f16x8*)&q2h[(long)((rw * 3 + j) * 16 + lo) * 192 + kc * 32 + hi * 8];
                #pragma unroll
                for (int t = 0; t < 2; ++t)
                    acc[j * 2 + t] = __builtin_amdgcn_mfma_f32_16x16x32_f16(a, bf[t], acc[j * 2 + t], 0, 0, 0);
            }
        }
        __syncthreads();   // ph3 y2-reads + (ph2's Y-reads) done before writing Y
        #pragma unroll
        for (int j = 0; j < 3; ++j)
            #pragma unroll
            for (int t = 0; t < 2; ++t)
                #pragma unroll
                for (int r = 0; r < 4; ++r) {
                    int row = (rw * 3 + j) * 16 + hi * 4 + r;
                    int col = (ch * 2 + t) * 16 + lo;
                    Y[row * 64 + (col ^ ((row & 7) << 3))] = (f16)acc[j * 2 + t][r];
                }
    }
    __syncthreads();

    // ph4: xifft[o][hw] = (1/64) sum_uv y3T[o][uv] L[hw][uv]
    {
        f16x8 bfr[2][2];
        #pragma unroll
        for (int t = 0; t < 2; ++t) {
            int hw = (ch * 2 + t) * 16 + lo;
            int hu = hw >> 3, hv = hw & 7;
            #pragma unroll
            for (int kc = 0; kc < 2; ++kc) {
                int cg = kc * 4 + hi;
                #pragma unroll
                for (int e = 0; e < 8; ++e) {
                    int k = (hu * cg + hv * e) & 7;
                    bfr[t][kc][e] = (f16)__cosf((float)k * 0.78539816339744831f);
                }
            }
        }
        float4v acc[6];
        #pragma unroll
        for (int jt = 0; jt < 6; ++jt) acc[jt] = (float4v){0.f,0.f,0.f,0.f};
        #pragma unroll
        for (int kc = 0; kc < 2; ++kc)
            #pragma unroll
            for (int j = 0; j < 3; ++j) {
                int row = (rw * 3 + j) * 16 + lo;
                f16x8 a = *(const f16x8*)&Y[row * 64 + ((kc * 32 + hi * 8) ^ ((row & 7) << 3))];
                #pragma unroll
                for (int t = 0; t < 2; ++t)
                    acc[j * 2 + t] = __builtin_amdgcn_mfma_f32_16x16x32_f16(a, bfr[t][kc], acc[j * 2 + t], 0, 0, 0);
            }
        #pragma unroll
        for (int j = 0; j < 3; ++j)
            #pragma unroll
            for (int t = 0; t < 2; ++t)
                #pragma unroll
                for (int r = 0; r < 4; ++r)
                    xifft[gbase + ((rw * 3 + j) * 16 + hi * 4 + r) * 64 + (ch * 2 + t) * 16 + lo] =
                        (f16)(acc[j * 2 + t][r] * 0.015625f);
    }
}

// ---------------------------------------------------------------------------
// fp16 MFMA GEMM, K=192, W pre-converted f16 [Ntot][192]. Col-split via
// blockIdx.y (ob = y*NT*64). GROUPED: out[(o/32)][row][o%32] f16, LDS-bounced.
// OUT_F32: row-major [M][192] f32, LDS-bounced.
// ---------------------------------------------------------------------------
template<int NT, bool BIAS_E, bool A_F32, bool OUT_F32, bool GROUPED>
__global__ __launch_bounds__(256) void gemm_mfma(
    const void* __restrict__ Ain, const f16* __restrict__ W,
    const float* __restrict__ bias, void* __restrict__ out)
{
    __shared__ f16 As[64 * 200];
    __shared__ f16 Ws[64 * 200];   // doubles as epilogue bounce buffer
    const int tid = threadIdx.x;
    const long row0 = (long)blockIdx.x * 64;
    const int ob = blockIdx.y * (NT * 64);
    const int w = tid >> 6, l = tid & 63, lo = l & 15, hi = l >> 4;

    if (A_F32) {
        const float* A = (const float*)Ain;
        for (int idx = tid; idx < 3072; idx += 256) {
            int r = idx / 48, c4 = idx % 48;
            float4v v = *(const float4v*)&A[(row0 + r) * 192 + c4 * 4];
            f16x4 hv = {(f16)v.x, (f16)v.y, (f16)v.z, (f16)v.w};
            *(f16x4*)&As[r * 200 + c4 * 4] = hv;
        }
    } else {
        const f16* A = (const f16*)Ain;
        for (int idx = tid; idx < 1536; idx += 256) {
            int r = idx / 24, c8 = idx % 24;
            *(f16x8*)&As[r * 200 + c8 * 8] =
                *(const f16x8*)&A[(row0 + r) * 192 + c8 * 8];
        }
    }
    for (int ot = 0; ot < NT; ++ot) {
        __syncthreads();
        for (int idx = tid; idx < 1536; idx += 256) {
            int r = idx / 24, c8 = idx % 24;
            *(f16x8*)&Ws[r * 200 + c8 * 8] =
                *(const f16x8*)&W[(long)(ob + ot * 64 + r) * 192 + c8 * 8];
        }
        __syncthreads();
        float4v acc[4];
        #pragma unroll
        for (int nt = 0; nt < 4; ++nt) acc[nt] = (float4v){0.f,0.f,0.f,0.f};
        #pragma unroll
        for (int kc = 0; kc < 6; ++kc) {
            f16x8 a = *(const f16x8*)&As[(w * 16 + lo) * 200 + kc * 32 + hi * 8];
            #pragma unroll
            for (int nt = 0; nt < 4; ++nt) {
                f16x8 bf = *(const f16x8*)&Ws[(nt * 16 + lo) * 200 + kc * 32 + hi * 8];
                acc[nt] = __builtin_amdgcn_mfma_f32_16x16x32_f16(a, bf, acc[nt], 0, 0, 0);
            }
        }
        __syncthreads();   // all waves' Ws reads done before bounce overwrite
        if (GROUPED) {
            f16* bw = Ws;  // [64][72]
            #pragma unroll
            for (int nt = 0; nt < 4; ++nt)
                #pragma unroll
                for (int r = 0; r < 4; ++r) {
                    float v = acc[nt][r];
                    if (BIAS_E) v += bias[ob + ot * 64 + nt * 16 + lo];
                    bw[(w * 16 + hi * 4 + r) * 72 + nt * 16 + lo] = (f16)v;
                }
            int row = w * 16 + (l >> 2);
            #pragma unroll
            for (int j = 0; j < 2; ++j) {
                int col = (l & 3) * 16 + j * 8;
                f16x8 v = *(const f16x8*)&bw[row * 72 + col];
                int o = ob + ot * 64 + col;
                *(f16x8*)&((f16*)out)[((long)(o >> 5) * 131072 + row0 + row) * 32 + (o & 31)] = v;
            }
        } else if (OUT_F32) {
            float* bwf = (float*)Ws;  // [64][68]
            #pragma unroll
            for (int nt = 0; nt < 4; ++nt)
                #pragma unroll
                for (int r = 0; r < 4; ++r) {
                    float v = acc[nt][r];
                    if (BIAS_E) v += bias[ob + ot * 64 + nt * 16 + lo];
                    bwf[(w * 16 + hi * 4 + r) * 68 + nt * 16 + lo] = v;
                }
            int row = w * 16 + (l >> 2);
            #pragma unroll
            for (int j = 0; j < 4; ++j) {
                int c4 = ((l & 3) + j * 4) * 4;
                float4v v = *(const float4v*)&bwf[row * 68 + c4];
                *(float4v*)&((float*)out)[(row0 + row) * 192 + ob + ot * 64 + c4] = v;
            }
        }
    }
}

// ---------------------------------------------------------------------------
// Fused depthwise-3x3 conv + xifft residual + MFMA windowed attention.
// One block per (b,h). Halo rows staged in tb per s-phase (coalesced f16x8);
// conv weights vectorized [s][rj][32]; bias from g_biasg (L2); output bounced
// through dead qls. LDS 38.6 KB -> 4 blocks/CU.
// ---------------------------------------------------------------------------
__global__ __launch_bounds__(256, 4) void k_attn(
    const f16* __restrict__ T, const f16* __restrict__ xifft,
    const float* __restrict__ dww, const float* __restrict__ dwb,
    f16* __restrict__ obnc)
{
    __shared__ f16 tb[3 * 66 * 32];   // [r][nn+1][ch]
    __shared__ f16 qls[64 * 40];      // q rows; later output bounce
    __shared__ f16 kls[64 * 40];
    __shared__ f16 vtl[32 * 72];      // v transposed
    __shared__ f16 pls[64 * 72];      // softmax(P)
    __shared__ f16 wd[864];           // [s][rj][32]
    __shared__ float bd[96];
    const int b = blockIdx.x, h = blockIdx.y, tid = threadIdx.x;
    const int n = tid >> 2, cth = tid & 3;

    for (int idx = tid; idx < 864; idx += 256) {
        int s = idx / 288, rj = (idx % 288) >> 5, d = idx & 31;
        wd[idx] = (f16)dww[(s * 192 + h * 32 + d) * 9 + rj];
    }
    if (tid < 96) {
        int s = tid >> 5, d = tid & 31;
        bd[tid] = dwb[s * 192 + h * 32 + d];
    }
    float xf[8];
    {
        f16x8 v = *(const f16x8*)&xifft[(long)b * 12288 + h * 2048 + n * 32 + cth * 8];
        #pragma unroll
        for (int j = 0; j < 8; ++j) xf[j] = (float)v[j];
    }

    for (int s = 0; s < 3; ++s) {
        __syncthreads();
        if (tid < 24) {    // zero n-pads
            int r = tid / 8, pe = (tid >> 2) & 1, cc = tid & 3;
            f16x8 z = {};
            *(f16x8*)&tb[((r * 66) + pe * 65) * 32 + cc * 8] = z;
        }
        #pragma unroll
        for (int it = 0; it < 3; ++it) {
            int idx = tid + it * 256;
            int r = idx >> 8, rem = idx & 255;
            int nn = rem >> 2, cc = rem & 3;
            int bb = b + r - 1;
            f16x8 v = {};
            if (bb >= 0 && bb < 2048)
                v = *(const f16x8*)&T[((long)(s * 6 + h) * 131072
                                      + (long)bb * 64 + nn) * 32 + cc * 8];
            *(f16x8*)&tb[(r * 66 + nn + 1) * 32 + cc * 8] = v;
        }
        __syncthreads();
        float a8[8];
        #pragma unroll
        for (int dd = 0; dd < 8; ++dd) a8[dd] = bd[s * 32 + cth * 8 + dd];
        #pragma unroll
        for (int rj = 0; rj < 9; ++rj) {
            f16x8 tv = *(const f16x8*)&tb[((rj / 3) * 66 + n + rj % 3) * 32 + cth * 8];
            f16x8 wv = *(const f16x8*)&wd[(s * 9 + rj) * 32 + cth * 8];
            #pragma unroll
            for (int dd = 0; dd < 8; ++dd)
                a8[dd] += (float)wv[dd] * (float)tv[dd];
        }
        #pragma unroll
        for (int dd = 0; dd < 8; ++dd) a8[dd] += xf[dd];
        if (s == 0) {
            f16x8 o;
            #pragma unroll
            for (int dd = 0; dd < 8; ++dd) o[dd] = (f16)(a8[dd] * SCALE_Q);
            *(f16x8*)&qls[n * 40 + cth * 8] = o;
        } else if (s == 1) {
            f16x8 o;
            #pragma unroll
            for (int dd = 0; dd < 8; ++dd) o[dd] = (f16)a8[dd];
            *(f16x8*)&kls[n * 40 + cth * 8] = o;
        } else {
            #pragma unroll
            for (int dd = 0; dd < 8; ++dd)
                vtl[(cth * 8 + dd) * 72 + n] = (f16)a8[dd];
        }
    }
    __syncthreads();

    // QK^T
    const int w = tid >> 6, l = tid & 63, lo = l & 15, hi = l >> 4;
    f16x8 qfrag = *(const f16x8*)&qls[(w * 16 + lo) * 40 + hi * 8];
    float4v accq[4];
    #pragma unroll
    for (int mt = 0; mt < 4; ++mt) {
        f16x8 kfrag = *(const f16x8*)&kls[(mt * 16 + lo) * 40 + hi * 8];
        accq[mt] = __builtin_amdgcn_mfma_f32_16x16x32_f16(
            qfrag, kfrag, (float4v){0.f, 0.f, 0.f, 0.f}, 0, 0, 0);
    }

    // bias + softmax in C-layout registers
    const f16* bg = g_biasg + h * 4096;
    float pv[4][4];
    #pragma unroll
    for (int mt = 0; mt < 4; ++mt)
        #pragma unroll
        for (int r = 0; r < 4; ++r)
            pv[mt][r] = accq[mt][r] + (float)bg[(w * 16 + hi * 4 + r) * 64 + mt * 16 + lo];
    float inv[4];
    #pragma unroll
    for (int r = 0; r < 4; ++r) {
        float mx = fmaxf(fmaxf(pv[0][r], pv[1][r]), fmaxf(pv[2][r], pv[3][r]));
        mx = fmaxf(mx, __shfl_xor(mx, 1));
        mx = fmaxf(mx, __shfl_xor(mx, 2));
        mx = fmaxf(mx, __shfl_xor(mx, 4));
        mx = fmaxf(mx, __shfl_xor(mx, 8));
        float sum = 0.f;
        #pragma unroll
        for (int mt = 0; mt < 4; ++mt) { pv[mt][r] = __expf(pv[mt][r] - mx); sum += pv[mt][r]; }
        sum += __shfl_xor(sum, 1);
        sum += __shfl_xor(sum, 2);
        sum += __shfl_xor(sum, 4);
        sum += __shfl_xor(sum, 8);
        inv[r] = 1.0f / sum;
    }
    #pragma unroll
    for (int mt = 0; mt < 4; ++mt)
        #pragma unroll
        for (int r = 0; r < 4; ++r)
            pls[(w * 16 + hi * 4 + r) * 72 + mt * 16 + lo] = (f16)(pv[mt][r] * inv[r]);
    // wave-private rows: in-order LDS per wave, no barrier

    // PV
    float4v acco[2] = {(float4v){0.f,0.f,0.f,0.f}, (float4v){0.f,0.f,0.f,0.f}};
    #pragma unroll
    for (int kc = 0; kc < 2; ++kc) {
        f16x8 pfrag = *(const f16x8*)&pls[(w * 16 + lo) * 72 + kc * 32 + hi * 8];
        #pragma unroll
        for (int dt = 0; dt < 2; ++dt) {
            f16x8 vfrag = *(const f16x8*)&vtl[(dt * 16 + lo) * 72 + kc * 32 + hi * 8];
            acco[dt] = __builtin_amdgcn_mfma_f32_16x16x32_f16(pfrag, vfrag, acco[dt], 0, 0, 0);
        }
    }
    // bounce output through qls (dead, wave-own rows) -> coalesced f16x8 stores
    #pragma unroll
    for (int dt = 0; dt < 2; ++dt)
        #pragma unroll
        for (int r = 0; r < 4; ++r)
            qls[(w * 16 + hi * 4 + r) * 40 + dt * 16 + lo] = (f16)acco[dt][r];
    {
        int row = w * 16 + (l >> 2);
        f16x8 ov = *(const f16x8*)&qls[row * 40 + (l & 3) * 8];
        *(f16x8*)&obnc[((long)b * 64 + row) * 192 + h * 32 + (l & 3) * 8] = ov;
    }
}

// ---------------------------------------------------------------------------
// Launcher. Workspace (f16 elems), 252,100,608 bytes total:
//   T   [0, 75497472)            : qkv conv output, grouped [18][131072][32]
//   XTg [0, 25165824)            : x^T f16 (ALIASES T head; dead before qkv writes T)
//   XI  [75497472, 100663296)    : xifft
//   O   [100663296, 125829120)   : obnc [bn][192]
//   WB  [125829120, +221184)     : f16 weights (qkvw | q1 | q2 | proj)
// ---------------------------------------------------------------------------
extern "C" void kernel_launch(void* const* d_in, const int* in_sizes, int n_in,
                              void* d_out, int out_size, void* d_ws, size_t ws_size,
                              hipStream_t stream)
{
    const float* x      = (const float*)d_in[0];
    const float* qkvw   = (const float*)d_in[1];
    const float* qkvb   = (const float*)d_in[2];
    const float* dww    = (const float*)d_in[3];
    const float* dwb    = (const float*)d_in[4];
    const float* q1w    = (const float*)d_in[5];
    const float* q2w    = (const float*)d_in[6];
    const float* rpb    = (const float*)d_in[7];
    const float* projw  = (const float*)d_in[8];
    const float* projb  = (const float*)d_in[9];
    const int*   relidx = (const int*)d_in[10];

    f16* T   = (f16*)d_ws;
    f16* XTg = T;                         // alias: dead before qkv-gemm writes T
    f16* XI  = T + 75497472L;
    f16* O   = XI + 25165824L;
    f16* WB  = O + 25165824L;
    f16* qkvh  = WB;
    f16* q1h   = WB + 110592;
    f16* q2h   = WB + 147456;
    f16* projh = WB + 184320;

    k_prep<<<960, 256, 0, stream>>>(qkvw, q1w, q2w, projw, rpb, relidx, WB);

    // x -> x^T (f16, channel-major)
    k_xt<<<dim3(2048, 3), 256, 0, stream>>>(x, XTg);

    // fused FFT branch -> xifft
    k_fft<<<2048, 512, 0, stream>>>(XTg, q1h, q2h, XI);

    // t = x @ qkv_w^T + qkv_b  (grouped [18][bn][32], f16), col-split x3
    gemm_mfma<3, true, true, false, true><<<dim3(2048, 3), 256, 0, stream>>>(x, qkvh, qkvb, T);

    // fused depthwise conv + residual + MFMA attention -> obnc f16
    k_attn<<<dim3(2048, 6), 256, 0, stream>>>(T, XI, dww, dwb, O);

    // final projection -> d_out f32
    gemm_mfma<3, true, false, true, false><<<dim3(2048, 1), 256, 0, stream>>>(O, projh, projb, (float*)d_out);
}

// Round 8
// 429.252 us; speedup vs baseline: 7.6026x; 1.1252x over previous
//
#include <hip/hip_runtime.h>
#include <math.h>

// B=2048 windows, N=64 tokens, C=192 channels, 6 heads x 32 dim, 3C=576
#define SCALE_Q 0.17677669529663687f

typedef _Float16 f16;
typedef _Float16 f16x4 __attribute__((ext_vector_type(4)));
typedef _Float16 f16x8 __attribute__((ext_vector_type(8)));
typedef float float4v __attribute__((ext_vector_type(4)));

// Precomputed relative-position bias tile [6][64][64] (f16), L2-hot at use.
__device__ f16 g_biasg[6 * 64 * 64];

// Fast GELU: A&S 7.1.26 erf approx, |err| <= 1.5e-7.
__device__ __forceinline__ float gelu_f(float v) {
    float az = fabsf(v) * 0.70710678118654752f;
    float t = 1.0f / fmaf(az, 0.3275911f, 1.0f);
    float p = t * fmaf(t, fmaf(t, fmaf(t, fmaf(t, 1.061405429f, -1.453152027f),
                                       1.421413741f), -0.284496736f), 0.254829592f);
    float erfv = 1.0f - p * __expf(-az * az);
    erfv = copysignf(erfv, v);
    return 0.5f * v * (1.0f + erfv);
}

// ---------------------------------------------------------------------------
// Prep: convert all weights to f16 (wbuf) + build bias tile.
// wbuf: [0,110592) qkvw | [110592,147456) q1 | [147456,184320) q2 | [184320,221184) proj
// ---------------------------------------------------------------------------
__global__ __launch_bounds__(256) void k_prep(
    const float* __restrict__ qkvw, const float* __restrict__ q1w,
    const float* __restrict__ q2w, const float* __restrict__ projw,
    const float* __restrict__ rpb, const int* __restrict__ relidx,
    f16* __restrict__ wbuf)
{
    int idx = blockIdx.x * 256 + threadIdx.x;
    if (idx < 110592)      wbuf[idx] = (f16)qkvw[idx];
    else if (idx < 147456) wbuf[idx] = (f16)q1w[idx - 110592];
    else if (idx < 184320) wbuf[idx] = (f16)q2w[idx - 147456];
    else if (idx < 221184) wbuf[idx] = (f16)projw[idx - 184320];
    else if (idx < 245760) {
        int i = idx - 221184;
        int h = i >> 12, nm = i & 4095;
        g_biasg[h * 4096 + nm] = (f16)rpb[relidx[nm] * 6 + h];
    }
}

// ---------------------------------------------------------------------------
// x f32 [131072][192] -> XTg f16 [192][131072] (transposed) AND
//                        XR  f16 [131072][192] (row-major).
// 64x64 tiles via padded LDS; all global accesses coalesced.
// ---------------------------------------------------------------------------
__global__ __launch_bounds__(256) void k_xt(const float* __restrict__ x,
                                            f16* __restrict__ XTg,
                                            f16* __restrict__ XR)
{
    __shared__ float xs[64 * 65];
    const int bb = blockIdx.x, cg = blockIdx.y, tid = threadIdx.x;
    #pragma unroll
    for (int it = 0; it < 4; ++it) {
        int idx = tid + it * 256;          // 1024 float4 loads
        int r = idx >> 4, c4 = idx & 15;
        float4v v = *(const float4v*)&x[((long)bb * 64 + r) * 192 + cg * 64 + c4 * 4];
        xs[r * 65 + c4 * 4 + 0] = v.x;
        xs[r * 65 + c4 * 4 + 1] = v.y;
        xs[r * 65 + c4 * 4 + 2] = v.z;
        xs[r * 65 + c4 * 4 + 3] = v.w;
    }
    __syncthreads();
    // row-major f16 copy
    #pragma unroll
    for (int it = 0; it < 2; ++it) {
        int idx = tid + it * 256;          // 512 f16x8 stores
        int r = idx >> 3, c8 = idx & 7;
        f16x8 o;
        #pragma unroll
        for (int j = 0; j < 8; ++j) o[j] = (f16)xs[r * 65 + c8 * 8 + j];
        *(f16x8*)&XR[((long)bb * 64 + r) * 192 + cg * 64 + c8 * 8] = o;
    }
    // transposed f16 copy
    #pragma unroll
    for (int it = 0; it < 2; ++it) {
        int idx = tid + it * 256;          // 512 f16x8 stores
        int oc = idx >> 3, r8 = idx & 7;
        f16x8 o;
        #pragma unroll
        for (int j = 0; j < 8; ++j) o[j] = (f16)xs[(r8 * 8 + j) * 65 + oc];
        *(f16x8*)&XTg[((long)(cg * 64 + oc)) * 131072 + (long)bb * 64 + r8 * 8] = o;
    }
}

// ---------------------------------------------------------------------------
// Fully fused FFT branch, one block (512 thr, 8 waves) per window:
//   xifft = ReIDFT( (gelu(ReDFT(x) @ q1^T)) @ q2^T )
// Wave split: rw = w&3 (row tile), ch = w>>2 (col half). DFT matrix per-lane.
// LDS: XT[192][72] (x^T, later y2 [64][216]) + Y[64][200] (y1, later y3T
// swizzled) = 53,248 B.
// ---------------------------------------------------------------------------
__global__ __launch_bounds__(512, 4) void k_fft(
    const f16* __restrict__ XTg, const f16* __restrict__ q1h,
    const f16* __restrict__ q2h, f16* __restrict__ xifft)
{
    __shared__ f16 XT[192 * 72];
    __shared__ f16 Y[64 * 200];
    const int b = blockIdx.x, tid = threadIdx.x;
    const long gbase = (long)b * 12288;
    const int w = tid >> 6, l = tid & 63, lo = l & 15, hi = l >> 4;
    const int rw = w & 3, ch = w >> 2;

    #pragma unroll
    for (int it = 0; it < 3; ++it) {
        int idx = tid + it * 512;
        int c = idx >> 3, g8 = idx & 7;
        *(f16x8*)&XT[c * 72 + g8 * 8] =
            *(const f16x8*)&XTg[(long)c * 131072 + b * 64 + g8 * 8];
    }
    __syncthreads();

    // ph1: y1[uv][c] = sum_hw L[uv][hw] x^T[c][hw]
    {
        f16x8 afr[2];
        int u = (rw * 16 + lo) >> 3, v = (rw * 16 + lo) & 7;
        #pragma unroll
        for (int kc = 0; kc < 2; ++kc) {
            int cg = kc * 4 + hi;
            #pragma unroll
            for (int e = 0; e < 8; ++e) {
                int k = (u * cg + v * e) & 7;
                afr[kc][e] = (f16)__cosf((float)k * 0.78539816339744831f);
            }
        }
        float4v acc[6];
        #pragma unroll
        for (int nt = 0; nt < 6; ++nt) acc[nt] = (float4v){0.f,0.f,0.f,0.f};
        #pragma unroll
        for (int kc = 0; kc < 2; ++kc)
            #pragma unroll
            for (int nt = 0; nt < 6; ++nt) {
                f16x8 bf = *(const f16x8*)&XT[(ch * 96 + nt * 16 + lo) * 72 + kc * 32 + hi * 8];
                acc[nt] = __builtin_amdgcn_mfma_f32_16x16x32_f16(afr[kc], bf, acc[nt], 0, 0, 0);
            }
        #pragma unroll
        for (int nt = 0; nt < 6; ++nt)
            #pragma unroll
            for (int r = 0; r < 4; ++r)
                Y[(rw * 16 + hi * 4 + r) * 200 + ch * 96 + nt * 16 + lo] = (f16)acc[nt][r];
    }
    __syncthreads();

    // ph2: y2 = gelu(y1 @ q1^T) -> XT region, stride 216
    {
        float4v acc[6];
        #pragma unroll
        for (int nt = 0; nt < 6; ++nt) acc[nt] = (float4v){0.f,0.f,0.f,0.f};
        for (int kc = 0; kc < 6; ++kc) {
            f16x8 a = *(const f16x8*)&Y[(rw * 16 + lo) * 200 + kc * 32 + hi * 8];
            #pragma unroll
            for (int nt = 0; nt < 6; ++nt) {
                f16x8 bf = *(const f16x8*)&q1h[(long)(ch * 96 + nt * 16 + lo) * 192 + kc * 32 + hi * 8];
                acc[nt] = __builtin_amdgcn_mfma_f32_16x16x32_f16(a, bf, acc[nt], 0, 0, 0);
            }
        }
        __syncthreads();
        f16* y2 = XT;
        #pragma unroll
        for (int nt = 0; nt < 6; ++nt)
            #pragma unroll
            for (int r = 0; r < 4; ++r)
                y2[(rw * 16 + hi * 4 + r) * 216 + ch * 96 + nt * 16 + lo] =
                    (f16)gelu_f(acc[nt][r]);
    }
    __syncthreads();

    // ph3: y3T[o][uv] = sum_c q2[o][c] y2[uv][c] -> Y region, swizzled cols
    {
        const f16* y2 = XT;
        float4v acc[6];
        #pragma unroll
        for (int jt = 0; jt < 6; ++jt) acc[jt] = (float4v){0.f,0.f,0.f,0.f};
        for (int kc = 0; kc < 6; ++kc) {
            f16x8 bf[2];
            #pragma unroll
            for (int t = 0; t < 2; ++t)
                bf[t] = *(const f16x8*)&y2[((ch * 2 + t) * 16 + lo) * 216 + kc * 32 + hi * 8];
            #pragma unroll
            for (int j = 0; j < 3; ++j) {
                f16x8 a = *(const f16x8*)&q2h[(long)((rw * 3 + j) * 16 + lo) * 192 + kc * 32 + hi * 8];
                #pragma unroll
                for (int t = 0; t < 2; ++t)
                    acc[j * 2 + t] = __builtin_amdgcn_mfma_f32_16x16x32_f16(a, bf[t], acc[j * 2 + t], 0, 0, 0);
            }
        }
        __syncthreads();
        #pragma unroll
        for (int j = 0; j < 3; ++j)
            #pragma unroll
            for (int t = 0; t < 2; ++t)
                #pragma unroll
                for (int r = 0; r < 4; ++r) {
                    int row = (rw * 3 + j) * 16 + hi * 4 + r;
                    int col = (ch * 2 + t) * 16 + lo;
                    Y[row * 64 + (col ^ ((row & 7) << 3))] = (f16)acc[j * 2 + t][r];
                }
    }
    __syncthreads();

    // ph4: xifft[o][hw] = (1/64) sum_uv y3T[o][uv] L[hw][uv]
    {
        f16x8 bfr[2][2];
        #pragma unroll
        for (int t = 0; t < 2; ++t) {
            int hw = (ch * 2 + t) * 16 + lo;
            int hu = hw >> 3, hv = hw & 7;
            #pragma unroll
            for (int kc = 0; kc < 2; ++kc) {
                int cg = kc * 4 + hi;
                #pragma unroll
                for (int e = 0; e < 8; ++e) {
                    int k = (hu * cg + hv * e) & 7;
                    bfr[t][kc][e] = (f16)__cosf((float)k * 0.78539816339744831f);
                }
            }
        }
        float4v acc[6];
        #pragma unroll
        for (int jt = 0; jt < 6; ++jt) acc[jt] = (float4v){0.f,0.f,0.f,0.f};
        #pragma unroll
        for (int kc = 0; kc < 2; ++kc)
            #pragma unroll
            for (int j = 0; j < 3; ++j) {
                int row = (rw * 3 + j) * 16 + lo;
                f16x8 a = *(const f16x8*)&Y[row * 64 + ((kc * 32 + hi * 8) ^ ((row & 7) << 3))];
                #pragma unroll
                for (int t = 0; t < 2; ++t)
                    acc[j * 2 + t] = __builtin_amdgcn_mfma_f32_16x16x32_f16(a, bfr[t][kc], acc[j * 2 + t], 0, 0, 0);
            }
        #pragma unroll
        for (int j = 0; j < 3; ++j)
            #pragma unroll
            for (int t = 0; t < 2; ++t)
                #pragma unroll
                for (int r = 0; r < 4; ++r)
                    xifft[gbase + ((rw * 3 + j) * 16 + hi * 4 + r) * 64 + (ch * 2 + t) * 16 + lo] =
                        (f16)(acc[j * 2 + t][r] * 0.015625f);
    }
}

// ---------------------------------------------------------------------------
// fp16 MFMA GEMM, K=192, A f16 [M][192], W f16 [Ntot][192].
// GROUPED: out[(o/32)][row][o%32] f16, LDS-bounced. OUT_F32: [M][192] f32.
// ---------------------------------------------------------------------------
template<int NT, bool BIAS_E, bool OUT_F32, bool GROUPED>
__global__ __launch_bounds__(256) void gemm_mfma(
    const f16* __restrict__ A, const f16* __restrict__ W,
    const float* __restrict__ bias, void* __restrict__ out)
{
    __shared__ f16 As[64 * 200];
    __shared__ f16 Ws[64 * 200];   // doubles as epilogue bounce buffer
    const int tid = threadIdx.x;
    const long row0 = (long)blockIdx.x * 64;
    const int ob = blockIdx.y * (NT * 64);
    const int w = tid >> 6, l = tid & 63, lo = l & 15, hi = l >> 4;

    for (int idx = tid; idx < 1536; idx += 256) {
        int r = idx / 24, c8 = idx % 24;
        *(f16x8*)&As[r * 200 + c8 * 8] =
            *(const f16x8*)&A[(row0 + r) * 192 + c8 * 8];
    }
    for (int ot = 0; ot < NT; ++ot) {
        __syncthreads();
        for (int idx = tid; idx < 1536; idx += 256) {
            int r = idx / 24, c8 = idx % 24;
            *(f16x8*)&Ws[r * 200 + c8 * 8] =
                *(const f16x8*)&W[(long)(ob + ot * 64 + r) * 192 + c8 * 8];
        }
        __syncthreads();
        float4v acc[4];
        #pragma unroll
        for (int nt = 0; nt < 4; ++nt) acc[nt] = (float4v){0.f,0.f,0.f,0.f};
        #pragma unroll
        for (int kc = 0; kc < 6; ++kc) {
            f16x8 a = *(const f16x8*)&As[(w * 16 + lo) * 200 + kc * 32 + hi * 8];
            #pragma unroll
            for (int nt = 0; nt < 4; ++nt) {
                f16x8 bf = *(const f16x8*)&Ws[(nt * 16 + lo) * 200 + kc * 32 + hi * 8];
                acc[nt] = __builtin_amdgcn_mfma_f32_16x16x32_f16(a, bf, acc[nt], 0, 0, 0);
            }
        }
        __syncthreads();   // all waves' Ws reads done before bounce overwrite
        if (GROUPED) {
            f16* bw = Ws;  // [64][72]
            #pragma unroll
            for (int nt = 0; nt < 4; ++nt)
                #pragma unroll
                for (int r = 0; r < 4; ++r) {
                    float v = acc[nt][r];
                    if (BIAS_E) v += bias[ob + ot * 64 + nt * 16 + lo];
                    bw[(w * 16 + hi * 4 + r) * 72 + nt * 16 + lo] = (f16)v;
                }
            int row = w * 16 + (l >> 2);
            #pragma unroll
            for (int j = 0; j < 2; ++j) {
                int col = (l & 3) * 16 + j * 8;
                f16x8 v = *(const f16x8*)&bw[row * 72 + col];
                int o = ob + ot * 64 + col;
                *(f16x8*)&((f16*)out)[((long)(o >> 5) * 131072 + row0 + row) * 32 + (o & 31)] = v;
            }
        } else if (OUT_F32) {
            float* bwf = (float*)Ws;  // [64][68]
            #pragma unroll
            for (int nt = 0; nt < 4; ++nt)
                #pragma unroll
                for (int r = 0; r < 4; ++r) {
                    float v = acc[nt][r];
                    if (BIAS_E) v += bias[ob + ot * 64 + nt * 16 + lo];
                    bwf[(w * 16 + hi * 4 + r) * 68 + nt * 16 + lo] = v;
                }
            int row = w * 16 + (l >> 2);
            #pragma unroll
            for (int j = 0; j < 4; ++j) {
                int c4 = ((l & 3) + j * 4) * 4;
                float4v v = *(const float4v*)&bwf[row * 68 + c4];
                *(float4v*)&((float*)out)[(row0 + row) * 192 + ob + ot * 64 + c4] = v;
            }
        }
    }
}

// ---------------------------------------------------------------------------
// Fused depthwise-3x3 conv (packed-f16 math) + xifft residual + MFMA attention.
// One block per (b,h). LDS 38.6 KB -> 4 blocks/CU.
// ---------------------------------------------------------------------------
__global__ __launch_bounds__(256, 4) void k_attn(
    const f16* __restrict__ T, const f16* __restrict__ xifft,
    const float* __restrict__ dww, const float* __restrict__ dwb,
    f16* __restrict__ obnc)
{
    __shared__ f16 tb[3 * 66 * 32];   // [r][nn+1][ch]
    __shared__ f16 qls[64 * 40];      // q rows; later output bounce
    __shared__ f16 kls[64 * 40];
    __shared__ f16 vtl[32 * 72];      // v transposed
    __shared__ f16 pls[64 * 72];      // softmax(P)
    __shared__ f16 wd[864];           // [s][rj][32]
    __shared__ f16 bd[96];
    const int b = blockIdx.x, h = blockIdx.y, tid = threadIdx.x;
    const int n = tid >> 2, cth = tid & 3;

    for (int idx = tid; idx < 864; idx += 256) {
        int s = idx / 288, rj = (idx % 288) >> 5, d = idx & 31;
        wd[idx] = (f16)dww[(s * 192 + h * 32 + d) * 9 + rj];
    }
    if (tid < 96) {
        int s = tid >> 5, d = tid & 31;
        bd[tid] = (f16)dwb[s * 192 + h * 32 + d];
    }
    f16x8 xf8 = *(const f16x8*)&xifft[(long)b * 12288 + h * 2048 + n * 32 + cth * 8];

    for (int s = 0; s < 3; ++s) {
        __syncthreads();
        if (tid < 24) {    // zero n-pads
            int r = tid / 8, pe = (tid >> 2) & 1, cc = tid & 3;
            f16x8 z = {};
            *(f16x8*)&tb[((r * 66) + pe * 65) * 32 + cc * 8] = z;
        }
        #pragma unroll
        for (int it = 0; it < 3; ++it) {
            int idx = tid + it * 256;
            int r = idx >> 8, rem = idx & 255;
            int nn = rem >> 2, cc = rem & 3;
            int bb = b + r - 1;
            f16x8 v = {};
            if (bb >= 0 && bb < 2048)
                v = *(const f16x8*)&T[((long)(s * 6 + h) * 131072
                                      + (long)bb * 64 + nn) * 32 + cc * 8];
            *(f16x8*)&tb[(r * 66 + nn + 1) * 32 + cc * 8] = v;
        }
        __syncthreads();
        // packed-f16 conv: acc = bias; 9 taps of v_pk_fma; + residual
        f16x8 acc = *(const f16x8*)&bd[s * 32 + cth * 8];
        #pragma unroll
        for (int rj = 0; rj < 9; ++rj) {
            f16x8 tv = *(const f16x8*)&tb[((rj / 3) * 66 + n + rj % 3) * 32 + cth * 8];
            f16x8 wv = *(const f16x8*)&wd[(s * 9 + rj) * 32 + cth * 8];
            acc += wv * tv;
        }
        acc += xf8;
        if (s == 0) {
            acc *= (f16)SCALE_Q;
            *(f16x8*)&qls[n * 40 + cth * 8] = acc;
        } else if (s == 1) {
            *(f16x8*)&kls[n * 40 + cth * 8] = acc;
        } else {
            #pragma unroll
            for (int dd = 0; dd < 8; ++dd)
                vtl[(cth * 8 + dd) * 72 + n] = acc[dd];
        }
    }
    __syncthreads();

    // QK^T
    const int w = tid >> 6, l = tid & 63, lo = l & 15, hi = l >> 4;
    f16x8 qfrag = *(const f16x8*)&qls[(w * 16 + lo) * 40 + hi * 8];
    float4v accq[4];
    #pragma unroll
    for (int mt = 0; mt < 4; ++mt) {
        f16x8 kfrag = *(const f16x8*)&kls[(mt * 16 + lo) * 40 + hi * 8];
        accq[mt] = __builtin_amdgcn_mfma_f32_16x16x32_f16(
            qfrag, kfrag, (float4v){0.f, 0.f, 0.f, 0.f}, 0, 0, 0);
    }

    // bias + softmax in C-layout registers
    const f16* bg = g_biasg + h * 4096;
    float pv[4][4];
    #pragma unroll
    for (int mt = 0; mt < 4; ++mt)
        #pragma unroll
        for (int r = 0; r < 4; ++r)
            pv[mt][r] = accq[mt][r] + (float)bg[(w * 16 + hi * 4 + r) * 64 + mt * 16 + lo];
    float inv[4];
    #pragma unroll
    for (int r = 0; r < 4; ++r) {
        float mx = fmaxf(fmaxf(pv[0][r], pv[1][r]), fmaxf(pv[2][r], pv[3][r]));
        mx = fmaxf(mx, __shfl_xor(mx, 1));
        mx = fmaxf(mx, __shfl_xor(mx, 2));
        mx = fmaxf(mx, __shfl_xor(mx, 4));
        mx = fmaxf(mx, __shfl_xor(mx, 8));
        float sum = 0.f;
        #pragma unroll
        for (int mt = 0; mt < 4; ++mt) { pv[mt][r] = __expf(pv[mt][r] - mx); sum += pv[mt][r]; }
        sum += __shfl_xor(sum, 1);
        sum += __shfl_xor(sum, 2);
        sum += __shfl_xor(sum, 4);
        sum += __shfl_xor(sum, 8);
        inv[r] = 1.0f / sum;
    }
    #pragma unroll
    for (int mt = 0; mt < 4; ++mt)
        #pragma unroll
        for (int r = 0; r < 4; ++r)
            pls[(w * 16 + hi * 4 + r) * 72 + mt * 16 + lo] = (f16)(pv[mt][r] * inv[r]);
    // wave-private rows: in-order LDS per wave, no barrier

    // PV
    float4v acco[2] = {(float4v){0.f,0.f,0.f,0.f}, (float4v){0.f,0.f,0.f,0.f}};
    #pragma unroll
    for (int kc = 0; kc < 2; ++kc) {
        f16x8 pfrag = *(const f16x8*)&pls[(w * 16 + lo) * 72 + kc * 32 + hi * 8];
        #pragma unroll
        for (int dt = 0; dt < 2; ++dt) {
            f16x8 vfrag = *(const f16x8*)&vtl[(dt * 16 + lo) * 72 + kc * 32 + hi * 8];
            acco[dt] = __builtin_amdgcn_mfma_f32_16x16x32_f16(pfrag, vfrag, acco[dt], 0, 0, 0);
        }
    }
    // bounce output through qls (dead, wave-own rows) -> coalesced f16x8 stores
    #pragma unroll
    for (int dt = 0; dt < 2; ++dt)
        #pragma unroll
        for (int r = 0; r < 4; ++r)
            qls[(w * 16 + hi * 4 + r) * 40 + dt * 16 + lo] = (f16)acco[dt][r];
    {
        int row = w * 16 + (l >> 2);
        f16x8 ov = *(const f16x8*)&qls[row * 40 + (l & 3) * 8];
        *(f16x8*)&obnc[((long)b * 64 + row) * 192 + h * 32 + (l & 3) * 8] = ov;
    }
}

// ---------------------------------------------------------------------------
// Launcher. Workspace (f16 elems), 252,100,608 bytes total:
//   T   [0, 75497472)            : qkv conv output, grouped [18][131072][32]
//   XTg [0, 25165824)            : x^T f16 (ALIASES T head; dead before qkv writes T)
//   XI  [75497472, 100663296)    : xifft
//   O   [100663296, 125829120)   : obnc [bn][192]
//   XR  = O alias                : x row-major f16 (dead before attn writes O)
//   WB  [125829120, +221184)     : f16 weights (qkvw | q1 | q2 | proj)
// ---------------------------------------------------------------------------
extern "C" void kernel_launch(void* const* d_in, const int* in_sizes, int n_in,
                              void* d_out, int out_size, void* d_ws, size_t ws_size,
                              hipStream_t stream)
{
    const float* x      = (const float*)d_in[0];
    const float* qkvw   = (const float*)d_in[1];
    const float* qkvb   = (const float*)d_in[2];
    const float* dww    = (const float*)d_in[3];
    const float* dwb    = (const float*)d_in[4];
    const float* q1w    = (const float*)d_in[5];
    const float* q2w    = (const float*)d_in[6];
    const float* rpb    = (const float*)d_in[7];
    const float* projw  = (const float*)d_in[8];
    const float* projb  = (const float*)d_in[9];
    const int*   relidx = (const int*)d_in[10];

    f16* T   = (f16*)d_ws;
    f16* XTg = T;                         // alias: dead before qkv-gemm writes T
    f16* XI  = T + 75497472L;
    f16* O   = XI + 25165824L;
    f16* XR  = O;                         // alias: dead before attn writes O
    f16* WB  = O + 25165824L;
    f16* qkvh  = WB;
    f16* q1h   = WB + 110592;
    f16* q2h   = WB + 147456;
    f16* projh = WB + 184320;

    k_prep<<<960, 256, 0, stream>>>(qkvw, q1w, q2w, projw, rpb, relidx, WB);

    // x -> x^T f16 + x row-major f16
    k_xt<<<dim3(2048, 3), 256, 0, stream>>>(x, XTg, XR);

    // fused FFT branch -> xifft
    k_fft<<<2048, 512, 0, stream>>>(XTg, q1h, q2h, XI);

    // t = x @ qkv_w^T + qkv_b  (grouped [18][bn][32], f16), single pass NT=9
    gemm_mfma<9, true, false, true><<<dim3(2048, 1), 256, 0, stream>>>(XR, qkvh, qkvb, T);

    // fused depthwise conv + residual + MFMA attention -> obnc f16
    k_attn<<<dim3(2048, 6), 256, 0, stream>>>(T, XI, dww, dwb, O);

    // final projection -> d_out f32
    gemm_mfma<3, true, true, false><<<dim3(2048, 1), 256, 0, stream>>>(O, projh, projb, (float*)d_out);
}

// Round 9
// 372.761 us; speedup vs baseline: 8.7548x; 1.1515x over previous
//
#include <hip/hip_runtime.h>
#include <math.h>

// B=2048 windows, N=64 tokens, C=192 channels, 6 heads x 32 dim, 3C=576
#define SCALE_Q 0.17677669529663687f

typedef _Float16 f16;
typedef _Float16 f16x4 __attribute__((ext_vector_type(4)));
typedef _Float16 f16x8 __attribute__((ext_vector_type(8)));
typedef float float4v __attribute__((ext_vector_type(4)));

// Precomputed relative-position bias tile [6][64][64] (f16), L2-hot at use.
__device__ f16 g_biasg[6 * 64 * 64];

// Fast GELU: A&S 7.1.26 erf approx, |err| <= 1.5e-7.
__device__ __forceinline__ float gelu_f(float v) {
    float az = fabsf(v) * 0.70710678118654752f;
    float t = 1.0f / fmaf(az, 0.3275911f, 1.0f);
    float p = t * fmaf(t, fmaf(t, fmaf(t, fmaf(t, 1.061405429f, -1.453152027f),
                                       1.421413741f), -0.284496736f), 0.254829592f);
    float erfv = 1.0f - p * __expf(-az * az);
    erfv = copysignf(erfv, v);
    return 0.5f * v * (1.0f + erfv);
}

// ---------------------------------------------------------------------------
// Prep: qkvh/projh f16 copies; q1f/q2f in MFMA-fragment order
//   Wf[(nt*6+kc)*1024 + lane*8 + j] = W[nt*16 + (lane&15)][kc*32 + (lane>>4)*8 + j]
// plus the bias tile. One-time.
// ---------------------------------------------------------------------------
__global__ __launch_bounds__(256) void k_prep(
    const float* __restrict__ qkvw, const float* __restrict__ q1w,
    const float* __restrict__ q2w, const float* __restrict__ projw,
    const float* __restrict__ rpb, const int* __restrict__ relidx,
    f16* __restrict__ wb, f16* __restrict__ q1f, f16* __restrict__ q2f)
{
    int idx = blockIdx.x * 256 + threadIdx.x;
    if (idx < 110592) {
        wb[idx] = (f16)qkvw[idx];
    } else if (idx < 147456) {
        wb[idx] = (f16)projw[idx - 110592];
    } else if (idx < 294912) {
        int i = idx - 147456;
        const float* src = q1w;
        f16* dst = q1f;
        if (i >= 73728) { i -= 73728; src = q2w; dst = q2f; }
        int frag = i >> 10, rem = i & 1023;
        int lane = rem >> 3, j = rem & 7;
        int nt = frag / 6, kc = frag - nt * 6;
        int row = nt * 16 + (lane & 15);
        int col = kc * 32 + (lane >> 4) * 8 + j;
        dst[i] = (f16)src[row * 192 + col];
    } else if (idx < 319488) {
        int i = idx - 294912;
        int h = i >> 12, nm = i & 4095;
        g_biasg[h * 4096 + nm] = (f16)rpb[relidx[nm] * 6 + h];
    }
}

// ---------------------------------------------------------------------------
// x f32 [131072][192] -> XTg f16 [192][131072] (transposed) AND
//                        XR  f16 [131072][192] (row-major).
// ---------------------------------------------------------------------------
__global__ __launch_bounds__(256) void k_xt(const float* __restrict__ x,
                                            f16* __restrict__ XTg,
                                            f16* __restrict__ XR)
{
    __shared__ float xs[64 * 65];
    const int bb = blockIdx.x, cg = blockIdx.y, tid = threadIdx.x;
    #pragma unroll
    for (int it = 0; it < 4; ++it) {
        int idx = tid + it * 256;
        int r = idx >> 4, c4 = idx & 15;
        float4v v = *(const float4v*)&x[((long)bb * 64 + r) * 192 + cg * 64 + c4 * 4];
        xs[r * 65 + c4 * 4 + 0] = v.x;
        xs[r * 65 + c4 * 4 + 1] = v.y;
        xs[r * 65 + c4 * 4 + 2] = v.z;
        xs[r * 65 + c4 * 4 + 3] = v.w;
    }
    __syncthreads();
    #pragma unroll
    for (int it = 0; it < 2; ++it) {
        int idx = tid + it * 256;
        int r = idx >> 3, c8 = idx & 7;
        f16x8 o;
        #pragma unroll
        for (int j = 0; j < 8; ++j) o[j] = (f16)xs[r * 65 + c8 * 8 + j];
        *(f16x8*)&XR[((long)bb * 64 + r) * 192 + cg * 64 + c8 * 8] = o;
    }
    #pragma unroll
    for (int it = 0; it < 2; ++it) {
        int idx = tid + it * 256;
        int oc = idx >> 3, r8 = idx & 7;
        f16x8 o;
        #pragma unroll
        for (int j = 0; j < 8; ++j) o[j] = (f16)xs[(r8 * 8 + j) * 65 + oc];
        *(f16x8*)&XTg[((long)(cg * 64 + oc)) * 131072 + (long)bb * 64 + r8 * 8] = o;
    }
}

// ---------------------------------------------------------------------------
// Fully fused FFT branch, one block (512 thr, 8 waves) per window.
// ph1/ph4: rw=w&3 row-tiles, ch=w>>2 col-halves; DFT matrix per-lane cos.
// ph2/ph3: h2=w&1 (2 tiles), q4=w>>1 (3 weight tiles); weights from q1f/q2f
// fragment-order (coalesced 1KB/wave loads, L2-hot).
// LDS: XT[192][72] (x^T, later y2 [64][216]) + Y[64][200] (y1, later y3T
// swizzled [192][64]) = 53,248 B -> 3 blocks/CU.
// ---------------------------------------------------------------------------
__global__ __launch_bounds__(512, 4) void k_fft(
    const f16* __restrict__ XTg, const f16* __restrict__ q1f,
    const f16* __restrict__ q2f, f16* __restrict__ xifft)
{
    __shared__ f16 XT[192 * 72];
    __shared__ f16 Y[64 * 200];
    const int b = blockIdx.x, tid = threadIdx.x;
    const long gbase = (long)b * 12288;
    const int w = tid >> 6, l = tid & 63, lo = l & 15, hi = l >> 4;
    const int rw = w & 3, ch = w >> 2;
    const int h2 = w & 1, q4 = w >> 1;

    #pragma unroll
    for (int it = 0; it < 3; ++it) {
        int idx = tid + it * 512;
        int c = idx >> 3, g8 = idx & 7;
        *(f16x8*)&XT[c * 72 + g8 * 8] =
            *(const f16x8*)&XTg[(long)c * 131072 + b * 64 + g8 * 8];
    }
    __syncthreads();

    // ph1: y1[uv][c] = sum_hw L[uv][hw] x^T[c][hw]
    {
        f16x8 afr[2];
        int u = (rw * 16 + lo) >> 3, v = (rw * 16 + lo) & 7;
        #pragma unroll
        for (int kc = 0; kc < 2; ++kc) {
            int cg = kc * 4 + hi;
            #pragma unroll
            for (int e = 0; e < 8; ++e) {
                int k = (u * cg + v * e) & 7;
                afr[kc][e] = (f16)__cosf((float)k * 0.78539816339744831f);
            }
        }
        float4v acc[6];
        #pragma unroll
        for (int nt = 0; nt < 6; ++nt) acc[nt] = (float4v){0.f,0.f,0.f,0.f};
        #pragma unroll
        for (int kc = 0; kc < 2; ++kc)
            #pragma unroll
            for (int nt = 0; nt < 6; ++nt) {
                f16x8 bf = *(const f16x8*)&XT[(ch * 96 + nt * 16 + lo) * 72 + kc * 32 + hi * 8];
                acc[nt] = __builtin_amdgcn_mfma_f32_16x16x32_f16(afr[kc], bf, acc[nt], 0, 0, 0);
            }
        #pragma unroll
        for (int nt = 0; nt < 6; ++nt)
            #pragma unroll
            for (int r = 0; r < 4; ++r)
                Y[(rw * 16 + hi * 4 + r) * 200 + ch * 96 + nt * 16 + lo] = (f16)acc[nt][r];
    }
    __syncthreads();   // y1 visible; XT(x^T) reads done

    // ph2: y2[uv][o] = gelu(sum_c y1[uv][c] q1[o][c]) -> XT region, stride 216
    {
        float4v acc[2][3];
        #pragma unroll
        for (int mt = 0; mt < 2; ++mt)
            #pragma unroll
            for (int nj = 0; nj < 3; ++nj) acc[mt][nj] = (float4v){0.f,0.f,0.f,0.f};
        for (int kc = 0; kc < 6; ++kc) {
            f16x8 a[2];
            #pragma unroll
            for (int mt = 0; mt < 2; ++mt)
                a[mt] = *(const f16x8*)&Y[(h2 * 32 + mt * 16 + lo) * 200 + kc * 32 + hi * 8];
            #pragma unroll
            for (int nj = 0; nj < 3; ++nj) {
                f16x8 bf = *(const f16x8*)&q1f[((q4 * 3 + nj) * 6 + kc) * 1024 + l * 8];
                #pragma unroll
                for (int mt = 0; mt < 2; ++mt)
                    acc[mt][nj] = __builtin_amdgcn_mfma_f32_16x16x32_f16(a[mt], bf, acc[mt][nj], 0, 0, 0);
            }
        }
        f16* y2 = XT;
        #pragma unroll
        for (int mt = 0; mt < 2; ++mt)
            #pragma unroll
            for (int nj = 0; nj < 3; ++nj)
                #pragma unroll
                for (int r = 0; r < 4; ++r)
                    y2[(h2 * 32 + mt * 16 + hi * 4 + r) * 216 + (q4 * 3 + nj) * 16 + lo] =
                        (f16)gelu_f(acc[mt][nj][r]);
    }
    __syncthreads();   // y2 visible; Y(y1) reads done

    // ph3: y3T[o][uv] = sum_c q2[o][c] y2[uv][c] -> Y region, swizzled cols
    {
        const f16* y2 = XT;
        float4v acc[3][2];
        #pragma unroll
        for (int jo = 0; jo < 3; ++jo)
            #pragma unroll
            for (int ju = 0; ju < 2; ++ju) acc[jo][ju] = (float4v){0.f,0.f,0.f,0.f};
        for (int kc = 0; kc < 6; ++kc) {
            f16x8 bf2[2];
            #pragma unroll
            for (int ju = 0; ju < 2; ++ju)
                bf2[ju] = *(const f16x8*)&y2[((h2 * 2 + ju) * 16 + lo) * 216 + kc * 32 + hi * 8];
            #pragma unroll
            for (int jo = 0; jo < 3; ++jo) {
                f16x8 a = *(const f16x8*)&q2f[((q4 * 3 + jo) * 6 + kc) * 1024 + l * 8];
                #pragma unroll
                for (int ju = 0; ju < 2; ++ju)
                    acc[jo][ju] = __builtin_amdgcn_mfma_f32_16x16x32_f16(a, bf2[ju], acc[jo][ju], 0, 0, 0);
            }
        }
        #pragma unroll
        for (int jo = 0; jo < 3; ++jo)
            #pragma unroll
            for (int ju = 0; ju < 2; ++ju)
                #pragma unroll
                for (int r = 0; r < 4; ++r) {
                    int row = (q4 * 3 + jo) * 16 + hi * 4 + r;
                    int col = (h2 * 2 + ju) * 16 + lo;
                    Y[row * 64 + (col ^ ((row & 7) << 3))] = (f16)acc[jo][ju][r];
                }
    }
    __syncthreads();   // y3T visible; XT(y2) reads done

    // ph4: xifft[o][hw] = (1/64) sum_uv y3T[o][uv] L[hw][uv]
    {
        f16x8 bfr[2][2];
        #pragma unroll
        for (int t = 0; t < 2; ++t) {
            int hw = (ch * 2 + t) * 16 + lo;
            int hu = hw >> 3, hv = hw & 7;
            #pragma unroll
            for (int kc = 0; kc < 2; ++kc) {
                int cg = kc * 4 + hi;
                #pragma unroll
                for (int e = 0; e < 8; ++e) {
                    int k = (hu * cg + hv * e) & 7;
                    bfr[t][kc][e] = (f16)__cosf((float)k * 0.78539816339744831f);
                }
            }
        }
        float4v acc[6];
        #pragma unroll
        for (int jt = 0; jt < 6; ++jt) acc[jt] = (float4v){0.f,0.f,0.f,0.f};
        #pragma unroll
        for (int kc = 0; kc < 2; ++kc)
            #pragma unroll
            for (int j = 0; j < 3; ++j) {
                int row = (rw * 3 + j) * 16 + lo;
                f16x8 a = *(const f16x8*)&Y[row * 64 + ((kc * 32 + hi * 8) ^ ((row & 7) << 3))];
                #pragma unroll
                for (int t = 0; t < 2; ++t)
                    acc[j * 2 + t] = __builtin_amdgcn_mfma_f32_16x16x32_f16(a, bfr[t][kc], acc[j * 2 + t], 0, 0, 0);
            }
        #pragma unroll
        for (int j = 0; j < 3; ++j)
            #pragma unroll
            for (int t = 0; t < 2; ++t)
                #pragma unroll
                for (int r = 0; r < 4; ++r)
                    xifft[gbase + ((rw * 3 + j) * 16 + hi * 4 + r) * 64 + (ch * 2 + t) * 16 + lo] =
                        (f16)(acc[j * 2 + t][r] * 0.015625f);
    }
}

// ---------------------------------------------------------------------------
// fp16 MFMA GEMM, K=192, A f16 [M][192], W f16 [Ntot][192].
// GROUPED: out[(o/32)][row][o%32] f16, LDS-bounced. OUT_F32: [M][192] f32.
// ---------------------------------------------------------------------------
template<int NT, bool BIAS_E, bool OUT_F32, bool GROUPED>
__global__ __launch_bounds__(256) void gemm_mfma(
    const f16* __restrict__ A, const f16* __restrict__ W,
    const float* __restrict__ bias, void* __restrict__ out)
{
    __shared__ f16 As[64 * 200];
    __shared__ f16 Ws[64 * 200];   // doubles as epilogue bounce buffer
    const int tid = threadIdx.x;
    const long row0 = (long)blockIdx.x * 64;
    const int ob = blockIdx.y * (NT * 64);
    const int w = tid >> 6, l = tid & 63, lo = l & 15, hi = l >> 4;

    for (int idx = tid; idx < 1536; idx += 256) {
        int r = idx / 24, c8 = idx % 24;
        *(f16x8*)&As[r * 200 + c8 * 8] =
            *(const f16x8*)&A[(row0 + r) * 192 + c8 * 8];
    }
    for (int ot = 0; ot < NT; ++ot) {
        __syncthreads();
        for (int idx = tid; idx < 1536; idx += 256) {
            int r = idx / 24, c8 = idx % 24;
            *(f16x8*)&Ws[r * 200 + c8 * 8] =
                *(const f16x8*)&W[(long)(ob + ot * 64 + r) * 192 + c8 * 8];
        }
        __syncthreads();
        float4v acc[4];
        #pragma unroll
        for (int nt = 0; nt < 4; ++nt) acc[nt] = (float4v){0.f,0.f,0.f,0.f};
        #pragma unroll
        for (int kc = 0; kc < 6; ++kc) {
            f16x8 a = *(const f16x8*)&As[(w * 16 + lo) * 200 + kc * 32 + hi * 8];
            #pragma unroll
            for (int nt = 0; nt < 4; ++nt) {
                f16x8 bf = *(const f16x8*)&Ws[(nt * 16 + lo) * 200 + kc * 32 + hi * 8];
                acc[nt] = __builtin_amdgcn_mfma_f32_16x16x32_f16(a, bf, acc[nt], 0, 0, 0);
            }
        }
        __syncthreads();   // all waves' Ws reads done before bounce overwrite
        if (GROUPED) {
            f16* bw = Ws;  // [64][72]
            #pragma unroll
            for (int nt = 0; nt < 4; ++nt)
                #pragma unroll
                for (int r = 0; r < 4; ++r) {
                    float v = acc[nt][r];
                    if (BIAS_E) v += bias[ob + ot * 64 + nt * 16 + lo];
                    bw[(w * 16 + hi * 4 + r) * 72 + nt * 16 + lo] = (f16)v;
                }
            int row = w * 16 + (l >> 2);
            #pragma unroll
            for (int j = 0; j < 2; ++j) {
                int col = (l & 3) * 16 + j * 8;
                f16x8 v = *(const f16x8*)&bw[row * 72 + col];
                int o = ob + ot * 64 + col;
                *(f16x8*)&((f16*)out)[((long)(o >> 5) * 131072 + row0 + row) * 32 + (o & 31)] = v;
            }
        } else if (OUT_F32) {
            float* bwf = (float*)Ws;  // [64][68]
            #pragma unroll
            for (int nt = 0; nt < 4; ++nt)
                #pragma unroll
                for (int r = 0; r < 4; ++r) {
                    float v = acc[nt][r];
                    if (BIAS_E) v += bias[ob + ot * 64 + nt * 16 + lo];
                    bwf[(w * 16 + hi * 4 + r) * 68 + nt * 16 + lo] = v;
                }
            int row = w * 16 + (l >> 2);
            #pragma unroll
            for (int j = 0; j < 4; ++j) {
                int c4 = ((l & 3) + j * 4) * 4;
                float4v v = *(const float4v*)&bwf[row * 68 + c4];
                *(float4v*)&((float*)out)[(row0 + row) * 192 + ob + ot * 64 + c4] = v;
            }
        }
    }
}

// ---------------------------------------------------------------------------
// Fused depthwise-3x3 conv (packed-f16 math) + xifft residual + MFMA attention.
// One block per (b,h). LDS 38.6 KB -> 4 blocks/CU.
// ---------------------------------------------------------------------------
__global__ __launch_bounds__(256, 4) void k_attn(
    const f16* __restrict__ T, const f16* __restrict__ xifft,
    const float* __restrict__ dww, const float* __restrict__ dwb,
    f16* __restrict__ obnc)
{
    __shared__ f16 tb[3 * 66 * 32];   // [r][nn+1][ch]
    __shared__ f16 qls[64 * 40];      // q rows; later output bounce
    __shared__ f16 kls[64 * 40];
    __shared__ f16 vtl[32 * 72];      // v transposed
    __shared__ f16 pls[64 * 72];      // softmax(P)
    __shared__ f16 wd[864];           // [s][rj][32]
    __shared__ f16 bd[96];
    const int b = blockIdx.x, h = blockIdx.y, tid = threadIdx.x;
    const int n = tid >> 2, cth = tid & 3;

    for (int idx = tid; idx < 864; idx += 256) {
        int s = idx / 288, rj = (idx % 288) >> 5, d = idx & 31;
        wd[idx] = (f16)dww[(s * 192 + h * 32 + d) * 9 + rj];
    }
    if (tid < 96) {
        int s = tid >> 5, d = tid & 31;
        bd[tid] = (f16)dwb[s * 192 + h * 32 + d];
    }
    f16x8 xf8 = *(const f16x8*)&xifft[(long)b * 12288 + h * 2048 + n * 32 + cth * 8];

    for (int s = 0; s < 3; ++s) {
        __syncthreads();
        if (tid < 24) {    // zero n-pads
            int r = tid / 8, pe = (tid >> 2) & 1, cc = tid & 3;
            f16x8 z = {};
            *(f16x8*)&tb[((r * 66) + pe * 65) * 32 + cc * 8] = z;
        }
        #pragma unroll
        for (int it = 0; it < 3; ++it) {
            int idx = tid + it * 256;
            int r = idx >> 8, rem = idx & 255;
            int nn = rem >> 2, cc = rem & 3;
            int bb = b + r - 1;
            f16x8 v = {};
            if (bb >= 0 && bb < 2048)
                v = *(const f16x8*)&T[((long)(s * 6 + h) * 131072
                                      + (long)bb * 64 + nn) * 32 + cc * 8];
            *(f16x8*)&tb[(r * 66 + nn + 1) * 32 + cc * 8] = v;
        }
        __syncthreads();
        f16x8 acc = *(const f16x8*)&bd[s * 32 + cth * 8];
        #pragma unroll
        for (int rj = 0; rj < 9; ++rj) {
            f16x8 tv = *(const f16x8*)&tb[((rj / 3) * 66 + n + rj % 3) * 32 + cth * 8];
            f16x8 wv = *(const f16x8*)&wd[(s * 9 + rj) * 32 + cth * 8];
            acc += wv * tv;
        }
        acc += xf8;
        if (s == 0) {
            acc *= (f16)SCALE_Q;
            *(f16x8*)&qls[n * 40 + cth * 8] = acc;
        } else if (s == 1) {
            *(f16x8*)&kls[n * 40 + cth * 8] = acc;
        } else {
            #pragma unroll
            for (int dd = 0; dd < 8; ++dd)
                vtl[(cth * 8 + dd) * 72 + n] = acc[dd];
        }
    }
    __syncthreads();

    // QK^T
    const int w = tid >> 6, l = tid & 63, lo = l & 15, hi = l >> 4;
    f16x8 qfrag = *(const f16x8*)&qls[(w * 16 + lo) * 40 + hi * 8];
    float4v accq[4];
    #pragma unroll
    for (int mt = 0; mt < 4; ++mt) {
        f16x8 kfrag = *(const f16x8*)&kls[(mt * 16 + lo) * 40 + hi * 8];
        accq[mt] = __builtin_amdgcn_mfma_f32_16x16x32_f16(
            qfrag, kfrag, (float4v){0.f, 0.f, 0.f, 0.f}, 0, 0, 0);
    }

    // bias + softmax in C-layout registers
    const f16* bg = g_biasg + h * 4096;
    float pv[4][4];
    #pragma unroll
    for (int mt = 0; mt < 4; ++mt)
        #pragma unroll
        for (int r = 0; r < 4; ++r)
            pv[mt][r] = accq[mt][r] + (float)bg[(w * 16 + hi * 4 + r) * 64 + mt * 16 + lo];
    float inv[4];
    #pragma unroll
    for (int r = 0; r < 4; ++r) {
        float mx = fmaxf(fmaxf(pv[0][r], pv[1][r]), fmaxf(pv[2][r], pv[3][r]));
        mx = fmaxf(mx, __shfl_xor(mx, 1));
        mx = fmaxf(mx, __shfl_xor(mx, 2));
        mx = fmaxf(mx, __shfl_xor(mx, 4));
        mx = fmaxf(mx, __shfl_xor(mx, 8));
        float sum = 0.f;
        #pragma unroll
        for (int mt = 0; mt < 4; ++mt) { pv[mt][r] = __expf(pv[mt][r] - mx); sum += pv[mt][r]; }
        sum += __shfl_xor(sum, 1);
        sum += __shfl_xor(sum, 2);
        sum += __shfl_xor(sum, 4);
        sum += __shfl_xor(sum, 8);
        inv[r] = 1.0f / sum;
    }
    #pragma unroll
    for (int mt = 0; mt < 4; ++mt)
        #pragma unroll
        for (int r = 0; r < 4; ++r)
            pls[(w * 16 + hi * 4 + r) * 72 + mt * 16 + lo] = (f16)(pv[mt][r] * inv[r]);
    // wave-private rows: in-order LDS per wave, no barrier

    // PV
    float4v acco[2] = {(float4v){0.f,0.f,0.f,0.f}, (float4v){0.f,0.f,0.f,0.f}};
    #pragma unroll
    for (int kc = 0; kc < 2; ++kc) {
        f16x8 pfrag = *(const f16x8*)&pls[(w * 16 + lo) * 72 + kc * 32 + hi * 8];
        #pragma unroll
        for (int dt = 0; dt < 2; ++dt) {
            f16x8 vfrag = *(const f16x8*)&vtl[(dt * 16 + lo) * 72 + kc * 32 + hi * 8];
            acco[dt] = __builtin_amdgcn_mfma_f32_16x16x32_f16(pfrag, vfrag, acco[dt], 0, 0, 0);
        }
    }
    // bounce output through qls (dead, wave-own rows) -> coalesced f16x8 stores
    #pragma unroll
    for (int dt = 0; dt < 2; ++dt)
        #pragma unroll
        for (int r = 0; r < 4; ++r)
            qls[(w * 16 + hi * 4 + r) * 40 + dt * 16 + lo] = (f16)acco[dt][r];
    {
        int row = w * 16 + (l >> 2);
        f16x8 ov = *(const f16x8*)&qls[row * 40 + (l & 3) * 8];
        *(f16x8*)&obnc[((long)b * 64 + row) * 192 + h * 32 + (l & 3) * 8] = ov;
    }
}

// ---------------------------------------------------------------------------
// Launcher. Workspace (f16 elems), 251,953,152 bytes total:
//   T   [0, 75497472)            : qkv conv output, grouped [18][131072][32]
//   XTg = T[0, 25165824)         : x^T f16 (alias; dead before qkv writes T)
//   q1f = T[25165824, +73728)    : q1 fragment-order (alias; dead before qkv)
//   q2f = T[25239552, +73728)    : q2 fragment-order (alias; dead before qkv)
//   XI  [75497472, 100663296)    : xifft
//   O   [100663296, 125829120)   : obnc [bn][192]
//   XR  = O alias                : x row-major f16 (dead before attn writes O)
//   WB  [125829120, +147456)     : qkvh | projh
// ---------------------------------------------------------------------------
extern "C" void kernel_launch(void* const* d_in, const int* in_sizes, int n_in,
                              void* d_out, int out_size, void* d_ws, size_t ws_size,
                              hipStream_t stream)
{
    const float* x      = (const float*)d_in[0];
    const float* qkvw   = (const float*)d_in[1];
    const float* qkvb   = (const float*)d_in[2];
    const float* dww    = (const float*)d_in[3];
    const float* dwb    = (const float*)d_in[4];
    const float* q1w    = (const float*)d_in[5];
    const float* q2w    = (const float*)d_in[6];
    const float* rpb    = (const float*)d_in[7];
    const float* projw  = (const float*)d_in[8];
    const float* projb  = (const float*)d_in[9];
    const int*   relidx = (const int*)d_in[10];

    f16* T   = (f16*)d_ws;
    f16* XTg = T;                          // alias: dead before qkv-gemm writes T
    f16* q1f = T + 25165824L;              // alias: dead before qkv-gemm writes T
    f16* q2f = T + 25239552L;
    f16* XI  = T + 75497472L;
    f16* O   = XI + 25165824L;
    f16* XR  = O;                          // alias: dead before attn writes O
    f16* WB  = O + 25165824L;
    f16* qkvh  = WB;
    f16* projh = WB + 110592;

    k_prep<<<1248, 256, 0, stream>>>(qkvw, q1w, q2w, projw, rpb, relidx, WB, q1f, q2f);

    // x -> x^T f16 + x row-major f16
    k_xt<<<dim3(2048, 3), 256, 0, stream>>>(x, XTg, XR);

    // fused FFT branch -> xifft
    k_fft<<<2048, 512, 0, stream>>>(XTg, q1f, q2f, XI);

    // t = x @ qkv_w^T + qkv_b  (grouped [18][bn][32], f16)
    gemm_mfma<9, true, false, true><<<dim3(2048, 1), 256, 0, stream>>>(XR, qkvh, qkvb, T);

    // fused depthwise conv + residual + MFMA attention -> obnc f16
    k_attn<<<dim3(2048, 6), 256, 0, stream>>>(T, XI, dww, dwb, O);

    // final projection -> d_out f32
    gemm_mfma<3, true, true, false><<<dim3(2048, 1), 256, 0, stream>>>(O, projh, projb, (float*)d_out);
}

// Round 10
// 350.333 us; speedup vs baseline: 9.3153x; 1.0640x over previous
//
#include <hip/hip_runtime.h>
#include <math.h>

// B=2048 windows, N=64 tokens, C=192 channels, 6 heads x 32 dim, 3C=576
#define SCALE_Q 0.17677669529663687f

typedef _Float16 f16;
typedef _Float16 f16x4 __attribute__((ext_vector_type(4)));
typedef _Float16 f16x8 __attribute__((ext_vector_type(8)));
typedef float float4v __attribute__((ext_vector_type(4)));

// Precomputed relative-position bias tile [6][64][64] (f16), L2-hot at use.
__device__ f16 g_biasg[6 * 64 * 64];

// cos(k*pi/4), k in [0,8) — branchless
__device__ __forceinline__ float cos8(int k) {
    float m = (k & 1) ? 0.70710678118654752f : ((k & 2) ? 0.f : 1.f);
    return (k >= 3 && k <= 5) ? -m : m;
}

// Fast GELU: A&S 7.1.26 erf approx, |err| <= 1.5e-7.
__device__ __forceinline__ float gelu_f(float v) {
    float az = fabsf(v) * 0.70710678118654752f;
    float t = 1.0f / fmaf(az, 0.3275911f, 1.0f);
    float p = t * fmaf(t, fmaf(t, fmaf(t, fmaf(t, 1.061405429f, -1.453152027f),
                                       1.421413741f), -0.284496736f), 0.254829592f);
    float erfv = 1.0f - p * __expf(-az * az);
    erfv = copysignf(erfv, v);
    return 0.5f * v * (1.0f + erfv);
}

// ---------------------------------------------------------------------------
// Prep: all weights to f16 MFMA-fragment order (512 elems/fragment):
//   Wf[(o16*6+kc)*512 + lane*8 + j] = W[o16*16+(lane&15)][kc*32+(lane>>4)*8+j]
// qkvf (576x192) | projf (192x192) | q1f | q2f (192x192) + bias tile.
// ---------------------------------------------------------------------------
__global__ __launch_bounds__(256) void k_prep(
    const float* __restrict__ qkvw, const float* __restrict__ q1w,
    const float* __restrict__ q2w, const float* __restrict__ projw,
    const float* __restrict__ rpb, const int* __restrict__ relidx,
    f16* __restrict__ qkvf, f16* __restrict__ projf,
    f16* __restrict__ q1f, f16* __restrict__ q2f)
{
    int idx = blockIdx.x * 256 + threadIdx.x;
    if (idx < 221184) {
        int i = idx;
        const float* src;
        f16* dst;
        if (i < 110592)      { src = qkvw;  dst = qkvf; }
        else if (i < 147456) { i -= 110592; src = projw; dst = projf; }
        else if (i < 184320) { i -= 147456; src = q1w;   dst = q1f; }
        else                 { i -= 184320; src = q2w;   dst = q2f; }
        int frag = i >> 9, rem = i & 511;
        int lane = rem >> 3, j = rem & 7;
        int o16 = frag / 6, kc = frag - o16 * 6;
        int row = o16 * 16 + (lane & 15);
        int col = kc * 32 + (lane >> 4) * 8 + j;
        dst[i] = (f16)src[row * 192 + col];
    } else if (idx < 245760) {
        int i = idx - 221184;
        int h = i >> 12, nm = i & 4095;
        g_biasg[h * 4096 + nm] = (f16)rpb[relidx[nm] * 6 + h];
    }
}

// ---------------------------------------------------------------------------
// x f32 [131072][192] -> XTg f16 [192][131072] (transposed), coalesced both sides.
// ---------------------------------------------------------------------------
__global__ __launch_bounds__(256) void k_xt(const float* __restrict__ x,
                                            f16* __restrict__ XTg)
{
    __shared__ float xs[64 * 65];
    const int bb = blockIdx.x, cg = blockIdx.y, tid = threadIdx.x;
    #pragma unroll
    for (int it = 0; it < 4; ++it) {
        int idx = tid + it * 256;
        int r = idx >> 4, c4 = idx & 15;
        float4v v = *(const float4v*)&x[((long)bb * 64 + r) * 192 + cg * 64 + c4 * 4];
        xs[r * 65 + c4 * 4 + 0] = v.x;
        xs[r * 65 + c4 * 4 + 1] = v.y;
        xs[r * 65 + c4 * 4 + 2] = v.z;
        xs[r * 65 + c4 * 4 + 3] = v.w;
    }
    __syncthreads();
    #pragma unroll
    for (int it = 0; it < 2; ++it) {
        int idx = tid + it * 256;
        int oc = idx >> 3, r8 = idx & 7;
        f16x8 o;
        #pragma unroll
        for (int j = 0; j < 8; ++j) o[j] = (f16)xs[(r8 * 8 + j) * 65 + oc];
        *(f16x8*)&XTg[((long)(cg * 64 + oc)) * 131072 + (long)bb * 64 + r8 * 8] = o;
    }
}

// ---------------------------------------------------------------------------
// Fully fused FFT branch, one block (512 thr, 8 waves) per window.
// ph1/ph4: rw=w&3 row-tiles, ch=w>>2 col-halves; DFT matrix per-lane (cos8).
// ph2/ph3: h2=w&1, q4=w>>1; weights from q1f/q2f fragment-order (L2-hot 1KB loads).
// LDS: XT[192][72] (x^T, later y2 [64][216]) + Y[64][200] (y1, later y3T swz).
// ---------------------------------------------------------------------------
__global__ __launch_bounds__(512, 4) void k_fft(
    const f16* __restrict__ XTg, const f16* __restrict__ q1f,
    const f16* __restrict__ q2f, f16* __restrict__ xifft)
{
    __shared__ f16 XT[192 * 72];
    __shared__ f16 Y[64 * 200];
    const int b = blockIdx.x, tid = threadIdx.x;
    const long gbase = (long)b * 12288;
    const int w = tid >> 6, l = tid & 63, lo = l & 15, hi = l >> 4;
    const int rw = w & 3, ch = w >> 2;
    const int h2 = w & 1, q4 = w >> 1;

    #pragma unroll
    for (int it = 0; it < 3; ++it) {
        int idx = tid + it * 512;
        int c = idx >> 3, g8 = idx & 7;
        *(f16x8*)&XT[c * 72 + g8 * 8] =
            *(const f16x8*)&XTg[(long)c * 131072 + b * 64 + g8 * 8];
    }
    __syncthreads();

    // ph1: y1[uv][c] = sum_hw L[uv][hw] x^T[c][hw]
    {
        f16x8 afr[2];
        int u = (rw * 16 + lo) >> 3, v = (rw * 16 + lo) & 7;
        #pragma unroll
        for (int kc = 0; kc < 2; ++kc) {
            int cg = kc * 4 + hi;
            #pragma unroll
            for (int e = 0; e < 8; ++e)
                afr[kc][e] = (f16)cos8((u * cg + v * e) & 7);
        }
        float4v acc[6];
        #pragma unroll
        for (int nt = 0; nt < 6; ++nt) acc[nt] = (float4v){0.f,0.f,0.f,0.f};
        #pragma unroll
        for (int kc = 0; kc < 2; ++kc)
            #pragma unroll
            for (int nt = 0; nt < 6; ++nt) {
                f16x8 bf = *(const f16x8*)&XT[(ch * 96 + nt * 16 + lo) * 72 + kc * 32 + hi * 8];
                acc[nt] = __builtin_amdgcn_mfma_f32_16x16x32_f16(afr[kc], bf, acc[nt], 0, 0, 0);
            }
        #pragma unroll
        for (int nt = 0; nt < 6; ++nt)
            #pragma unroll
            for (int r = 0; r < 4; ++r)
                Y[(rw * 16 + hi * 4 + r) * 200 + ch * 96 + nt * 16 + lo] = (f16)acc[nt][r];
    }
    __syncthreads();   // y1 visible; XT(x^T) reads done

    // ph2: y2[uv][o] = gelu(sum_c y1[uv][c] q1[o][c]) -> XT region, stride 216
    {
        float4v acc[2][3];
        #pragma unroll
        for (int mt = 0; mt < 2; ++mt)
            #pragma unroll
            for (int nj = 0; nj < 3; ++nj) acc[mt][nj] = (float4v){0.f,0.f,0.f,0.f};
        for (int kc = 0; kc < 6; ++kc) {
            f16x8 a[2];
            #pragma unroll
            for (int mt = 0; mt < 2; ++mt)
                a[mt] = *(const f16x8*)&Y[(h2 * 32 + mt * 16 + lo) * 200 + kc * 32 + hi * 8];
            #pragma unroll
            for (int nj = 0; nj < 3; ++nj) {
                f16x8 bf = *(const f16x8*)&q1f[((q4 * 3 + nj) * 6 + kc) * 512 + l * 8];
                #pragma unroll
                for (int mt = 0; mt < 2; ++mt)
                    acc[mt][nj] = __builtin_amdgcn_mfma_f32_16x16x32_f16(a[mt], bf, acc[mt][nj], 0, 0, 0);
            }
        }
        f16* y2 = XT;
        #pragma unroll
        for (int mt = 0; mt < 2; ++mt)
            #pragma unroll
            for (int nj = 0; nj < 3; ++nj)
                #pragma unroll
                for (int r = 0; r < 4; ++r)
                    y2[(h2 * 32 + mt * 16 + hi * 4 + r) * 216 + (q4 * 3 + nj) * 16 + lo] =
                        (f16)gelu_f(acc[mt][nj][r]);
    }
    __syncthreads();   // y2 visible; Y(y1) reads done

    // ph3: y3T[o][uv] = sum_c q2[o][c] y2[uv][c] -> Y region, swizzled cols
    {
        const f16* y2 = XT;
        float4v acc[3][2];
        #pragma unroll
        for (int jo = 0; jo < 3; ++jo)
            #pragma unroll
            for (int ju = 0; ju < 2; ++ju) acc[jo][ju] = (float4v){0.f,0.f,0.f,0.f};
        for (int kc = 0; kc < 6; ++kc) {
            f16x8 bf2[2];
            #pragma unroll
            for (int ju = 0; ju < 2; ++ju)
                bf2[ju] = *(const f16x8*)&y2[((h2 * 2 + ju) * 16 + lo) * 216 + kc * 32 + hi * 8];
            #pragma unroll
            for (int jo = 0; jo < 3; ++jo) {
                f16x8 a = *(const f16x8*)&q2f[((q4 * 3 + jo) * 6 + kc) * 512 + l * 8];
                #pragma unroll
                for (int ju = 0; ju < 2; ++ju)
                    acc[jo][ju] = __builtin_amdgcn_mfma_f32_16x16x32_f16(a, bf2[ju], acc[jo][ju], 0, 0, 0);
            }
        }
        __syncthreads();   // y2 reads done before overwriting Y
        #pragma unroll
        for (int jo = 0; jo < 3; ++jo)
            #pragma unroll
            for (int ju = 0; ju < 2; ++ju)
                #pragma unroll
                for (int r = 0; r < 4; ++r) {
                    int row = (q4 * 3 + jo) * 16 + hi * 4 + r;
                    int col = (h2 * 2 + ju) * 16 + lo;
                    Y[row * 64 + (col ^ ((row & 7) << 3))] = (f16)acc[jo][ju][r];
                }
    }
    __syncthreads();   // y3T visible

    // ph4: xifft[o][hw] = (1/64) sum_uv y3T[o][uv] L[hw][uv]
    {
        f16x8 bfr[2][2];
        #pragma unroll
        for (int t = 0; t < 2; ++t) {
            int hw = (ch * 2 + t) * 16 + lo;
            int hu = hw >> 3, hv = hw & 7;
            #pragma unroll
            for (int kc = 0; kc < 2; ++kc) {
                int cg = kc * 4 + hi;
                #pragma unroll
                for (int e = 0; e < 8; ++e)
                    bfr[t][kc][e] = (f16)cos8((hu * cg + hv * e) & 7);
            }
        }
        float4v acc[6];
        #pragma unroll
        for (int jt = 0; jt < 6; ++jt) acc[jt] = (float4v){0.f,0.f,0.f,0.f};
        #pragma unroll
        for (int kc = 0; kc < 2; ++kc)
            #pragma unroll
            for (int j = 0; j < 3; ++j) {
                int row = (rw * 3 + j) * 16 + lo;
                f16x8 a = *(const f16x8*)&Y[row * 64 + ((kc * 32 + hi * 8) ^ ((row & 7) << 3))];
                #pragma unroll
                for (int t = 0; t < 2; ++t)
                    acc[j * 2 + t] = __builtin_amdgcn_mfma_f32_16x16x32_f16(a, bfr[t][kc], acc[j * 2 + t], 0, 0, 0);
            }
        #pragma unroll
        for (int j = 0; j < 3; ++j)
            #pragma unroll
            for (int t = 0; t < 2; ++t)
                #pragma unroll
                for (int r = 0; r < 4; ++r)
                    xifft[gbase + ((rw * 3 + j) * 16 + hi * 4 + r) * 64 + (ch * 2 + t) * 16 + lo] =
                        (f16)(acc[j * 2 + t][r] * 0.015625f);
    }
}

// ---------------------------------------------------------------------------
// fp16 MFMA GEMM, K=192, weights in fragment order (no Ws staging, no loop
// barriers; epilogue bounce rows are wave-private -> barrier-free).
// GROUPED=true : A f32 (x), out grouped [(o/32)][row][o%32] f16 (qkv).
// GROUPED=false: A f16, out row-major [M][192] f32 (proj).
// ---------------------------------------------------------------------------
template<int NT, bool GROUPED>
__global__ __launch_bounds__(256) void gemm_frag(
    const void* __restrict__ Ain, const f16* __restrict__ Wf,
    const float* __restrict__ bias, void* __restrict__ out)
{
    __shared__ f16 As[64 * 200];
    __shared__ char bnc_raw[GROUPED ? 64 * 72 * 2 : 64 * 68 * 4];
    const int tid = threadIdx.x;
    const long row0 = (long)blockIdx.x * 64;
    const int w = tid >> 6, l = tid & 63, lo = l & 15, hi = l >> 4;

    if (GROUPED) {
        const float* A = (const float*)Ain;
        for (int idx = tid; idx < 3072; idx += 256) {
            int r = idx / 48, c4 = idx % 48;
            float4v v = *(const float4v*)&A[(row0 + r) * 192 + c4 * 4];
            f16x4 hv = {(f16)v.x, (f16)v.y, (f16)v.z, (f16)v.w};
            *(f16x4*)&As[r * 200 + c4 * 4] = hv;
        }
    } else {
        const f16* A = (const f16*)Ain;
        for (int idx = tid; idx < 1536; idx += 256) {
            int r = idx / 24, c8 = idx % 24;
            *(f16x8*)&As[r * 200 + c8 * 8] =
                *(const f16x8*)&A[(row0 + r) * 192 + c8 * 8];
        }
    }
    __syncthreads();

    for (int ot = 0; ot < NT; ++ot) {
        float4v acc[4];
        #pragma unroll
        for (int nt = 0; nt < 4; ++nt) acc[nt] = (float4v){0.f,0.f,0.f,0.f};
        #pragma unroll
        for (int kc = 0; kc < 6; ++kc) {
            f16x8 a = *(const f16x8*)&As[(w * 16 + lo) * 200 + kc * 32 + hi * 8];
            #pragma unroll
            for (int nt = 0; nt < 4; ++nt) {
                f16x8 bf = *(const f16x8*)&Wf[(long)(((ot * 4 + nt) * 6 + kc)) * 512 + l * 8];
                acc[nt] = __builtin_amdgcn_mfma_f32_16x16x32_f16(a, bf, acc[nt], 0, 0, 0);
            }
        }
        if (GROUPED) {
            f16* bw = (f16*)bnc_raw;  // [64][72], wave-private rows
            #pragma unroll
            for (int nt = 0; nt < 4; ++nt)
                #pragma unroll
                for (int r = 0; r < 4; ++r) {
                    float v = acc[nt][r] + bias[ot * 64 + nt * 16 + lo];
                    bw[(w * 16 + hi * 4 + r) * 72 + nt * 16 + lo] = (f16)v;
                }
            int row = w * 16 + (l >> 2);
            #pragma unroll
            for (int j = 0; j < 2; ++j) {
                int col = (l & 3) * 16 + j * 8;
                f16x8 v = *(const f16x8*)&bw[row * 72 + col];
                int o = ot * 64 + col;
                *(f16x8*)&((f16*)out)[((long)(o >> 5) * 131072 + row0 + row) * 32 + (o & 31)] = v;
            }
        } else {
            float* bwf = (float*)bnc_raw;  // [64][68], wave-private rows
            #pragma unroll
            for (int nt = 0; nt < 4; ++nt)
                #pragma unroll
                for (int r = 0; r < 4; ++r) {
                    float v = acc[nt][r] + bias[ot * 64 + nt * 16 + lo];
                    bwf[(w * 16 + hi * 4 + r) * 68 + nt * 16 + lo] = v;
                }
            int row = w * 16 + (l >> 2);
            #pragma unroll
            for (int j = 0; j < 4; ++j) {
                int c4 = ((l & 3) + j * 4) * 4;
                float4v v = *(const float4v*)&bwf[row * 68 + c4];
                *(float4v*)&((float*)out)[(row0 + row) * 192 + ot * 64 + c4] = v;
            }
        }
    }
}

// ---------------------------------------------------------------------------
// Fused depthwise-3x3 conv (packed f16) + xifft residual + MFMA attention.
// One block per (b,h); b XCD-swizzled so halo-sharing blocks share an L2.
// pls overlaid on dead tb -> LDS 28.8 KB -> 5 blocks/CU.
// ---------------------------------------------------------------------------
__global__ __launch_bounds__(256, 5) void k_attn(
    const f16* __restrict__ T, const f16* __restrict__ xifft,
    const float* __restrict__ dww, const float* __restrict__ dwb,
    f16* __restrict__ obnc)
{
    __shared__ f16 tb[3 * 66 * 32];   // [r][nn+1][ch]; later pls [64][72]
    __shared__ f16 qls[64 * 40];      // q rows; later output bounce
    __shared__ f16 kls[64 * 40];
    __shared__ f16 vtl[32 * 72];      // v transposed
    __shared__ f16 wd[864];           // [s][rj][32]
    __shared__ f16 bd[96];
    // XCD-aware swizzle: 2048 = 8 XCDs x 256 contiguous windows
    const int b = ((blockIdx.x & 7) << 8) | (blockIdx.x >> 3);
    const int h = blockIdx.y, tid = threadIdx.x;
    const int n = tid >> 2, cth = tid & 3;

    for (int idx = tid; idx < 864; idx += 256) {
        int s = idx / 288, rj = (idx % 288) >> 5, d = idx & 31;
        wd[idx] = (f16)dww[(s * 192 + h * 32 + d) * 9 + rj];
    }
    if (tid < 96) {
        int s = tid >> 5, d = tid & 31;
        bd[tid] = (f16)dwb[s * 192 + h * 32 + d];
    }
    f16x8 xf8 = *(const f16x8*)&xifft[(long)b * 12288 + h * 2048 + n * 32 + cth * 8];

    for (int s = 0; s < 3; ++s) {
        __syncthreads();
        if (tid < 24) {    // zero n-pads
            int r = tid / 8, pe = (tid >> 2) & 1, cc = tid & 3;
            f16x8 z = {};
            *(f16x8*)&tb[((r * 66) + pe * 65) * 32 + cc * 8] = z;
        }
        #pragma unroll
        for (int it = 0; it < 3; ++it) {
            int idx = tid + it * 256;
            int r = idx >> 8, rem = idx & 255;
            int nn = rem >> 2, cc = rem & 3;
            int bb = b + r - 1;
            f16x8 v = {};
            if (bb >= 0 && bb < 2048)
                v = *(const f16x8*)&T[((long)(s * 6 + h) * 131072
                                      + (long)bb * 64 + nn) * 32 + cc * 8];
            *(f16x8*)&tb[(r * 66 + nn + 1) * 32 + cc * 8] = v;
        }
        __syncthreads();
        f16x8 acc = *(const f16x8*)&bd[s * 32 + cth * 8];
        #pragma unroll
        for (int rj = 0; rj < 9; ++rj) {
            f16x8 tv = *(const f16x8*)&tb[((rj / 3) * 66 + n + rj % 3) * 32 + cth * 8];
            f16x8 wv = *(const f16x8*)&wd[(s * 9 + rj) * 32 + cth * 8];
            acc += wv * tv;
        }
        acc += xf8;
        if (s == 0) {
            acc *= (f16)SCALE_Q;
            *(f16x8*)&qls[n * 40 + cth * 8] = acc;
        } else if (s == 1) {
            *(f16x8*)&kls[n * 40 + cth * 8] = acc;
        } else {
            // stagger dd by cth -> conflict-free vtl scalar writes
            #pragma unroll
            for (int dd = 0; dd < 8; ++dd) {
                int dd2 = (dd + cth * 2) & 7;
                vtl[(cth * 8 + dd2) * 72 + n] = acc[dd2];
            }
        }
    }
    __syncthreads();   // q/k/v ready; tb dead -> reuse as pls

    f16* pls = tb;     // [64][72]

    // QK^T
    const int w = tid >> 6, l = tid & 63, lo = l & 15, hi = l >> 4;
    f16x8 qfrag = *(const f16x8*)&qls[(w * 16 + lo) * 40 + hi * 8];
    float4v accq[4];
    #pragma unroll
    for (int mt = 0; mt < 4; ++mt) {
        f16x8 kfrag = *(const f16x8*)&kls[(mt * 16 + lo) * 40 + hi * 8];
        accq[mt] = __builtin_amdgcn_mfma_f32_16x16x32_f16(
            qfrag, kfrag, (float4v){0.f, 0.f, 0.f, 0.f}, 0, 0, 0);
    }

    // bias + softmax in C-layout registers
    const f16* bg = g_biasg + h * 4096;
    float pv[4][4];
    #pragma unroll
    for (int mt = 0; mt < 4; ++mt)
        #pragma unroll
        for (int r = 0; r < 4; ++r)
            pv[mt][r] = accq[mt][r] + (float)bg[(w * 16 + hi * 4 + r) * 64 + mt * 16 + lo];
    float inv[4];
    #pragma unroll
    for (int r = 0; r < 4; ++r) {
        float mx = fmaxf(fmaxf(pv[0][r], pv[1][r]), fmaxf(pv[2][r], pv[3][r]));
        mx = fmaxf(mx, __shfl_xor(mx, 1));
        mx = fmaxf(mx, __shfl_xor(mx, 2));
        mx = fmaxf(mx, __shfl_xor(mx, 4));
        mx = fmaxf(mx, __shfl_xor(mx, 8));
        float sum = 0.f;
        #pragma unroll
        for (int mt = 0; mt < 4; ++mt) { pv[mt][r] = __expf(pv[mt][r] - mx); sum += pv[mt][r]; }
        sum += __shfl_xor(sum, 1);
        sum += __shfl_xor(sum, 2);
        sum += __shfl_xor(sum, 4);
        sum += __shfl_xor(sum, 8);
        inv[r] = 1.0f / sum;
    }
    #pragma unroll
    for (int mt = 0; mt < 4; ++mt)
        #pragma unroll
        for (int r = 0; r < 4; ++r)
            pls[(w * 16 + hi * 4 + r) * 72 + mt * 16 + lo] = (f16)(pv[mt][r] * inv[r]);
    // wave-private rows: in-order LDS per wave, no barrier

    // PV
    float4v acco[2] = {(float4v){0.f,0.f,0.f,0.f}, (float4v){0.f,0.f,0.f,0.f}};
    #pragma unroll
    for (int kc = 0; kc < 2; ++kc) {
        f16x8 pfrag = *(const f16x8*)&pls[(w * 16 + lo) * 72 + kc * 32 + hi * 8];
        #pragma unroll
        for (int dt = 0; dt < 2; ++dt) {
            f16x8 vfrag = *(const f16x8*)&vtl[(dt * 16 + lo) * 72 + kc * 32 + hi * 8];
            acco[dt] = __builtin_amdgcn_mfma_f32_16x16x32_f16(pfrag, vfrag, acco[dt], 0, 0, 0);
        }
    }
    // bounce output through qls (dead, wave-own rows) -> coalesced f16x8 stores
    #pragma unroll
    for (int dt = 0; dt < 2; ++dt)
        #pragma unroll
        for (int r = 0; r < 4; ++r)
            qls[(w * 16 + hi * 4 + r) * 40 + dt * 16 + lo] = (f16)acco[dt][r];
    {
        int row = w * 16 + (l >> 2);
        f16x8 ov = *(const f16x8*)&qls[row * 40 + (l & 3) * 8];
        *(f16x8*)&obnc[((long)b * 64 + row) * 192 + h * 32 + (l & 3) * 8] = ov;
    }
}

// ---------------------------------------------------------------------------
// Launcher. Workspace (f16 elems), 251,953,152 bytes total:
//   T    [0, 75497472)           : qkv conv output, grouped [18][131072][32]
//   XTg  = T[0, 25165824)        : x^T f16 (alias; dead before qkv writes T)
//   q1f  = T[25165824, +36864)   : q1 fragment-order (alias; dead before qkv)
//   q2f  = T[25202688, +36864)   : q2 fragment-order (alias; dead before qkv)
//   XI   [75497472, 100663296)   : xifft
//   O    [100663296, 125829120)  : obnc [bn][192]
//   WB   [125829120, +147456)    : qkvf | projf (fragment order, persistent)
// ---------------------------------------------------------------------------
extern "C" void kernel_launch(void* const* d_in, const int* in_sizes, int n_in,
                              void* d_out, int out_size, void* d_ws, size_t ws_size,
                              hipStream_t stream)
{
    const float* x      = (const float*)d_in[0];
    const float* qkvw   = (const float*)d_in[1];
    const float* qkvb   = (const float*)d_in[2];
    const float* dww    = (const float*)d_in[3];
    const float* dwb    = (const float*)d_in[4];
    const float* q1w    = (const float*)d_in[5];
    const float* q2w    = (const float*)d_in[6];
    const float* rpb    = (const float*)d_in[7];
    const float* projw  = (const float*)d_in[8];
    const float* projb  = (const float*)d_in[9];
    const int*   relidx = (const int*)d_in[10];

    f16* T    = (f16*)d_ws;
    f16* XTg  = T;                          // alias: dead before qkv-gemm writes T
    f16* q1f  = T + 25165824L;              // alias: dead before qkv-gemm writes T
    f16* q2f  = T + 25202688L;
    f16* XI   = T + 75497472L;
    f16* O    = XI + 25165824L;
    f16* WB   = O + 25165824L;
    f16* qkvf  = WB;
    f16* projf = WB + 110592;

    k_prep<<<960, 256, 0, stream>>>(qkvw, q1w, q2w, projw, rpb, relidx,
                                    qkvf, projf, q1f, q2f);

    // x -> x^T f16
    k_xt<<<dim3(2048, 3), 256, 0, stream>>>(x, XTg);

    // fused FFT branch -> xifft
    k_fft<<<2048, 512, 0, stream>>>(XTg, q1f, q2f, XI);

    // t = x @ qkv_w^T + qkv_b  (grouped [18][bn][32], f16)
    gemm_frag<9, true><<<2048, 256, 0, stream>>>(x, qkvf, qkvb, T);

    // fused depthwise conv + residual + MFMA attention -> obnc f16
    k_attn<<<dim3(2048, 6), 256, 0, stream>>>(T, XI, dww, dwb, O);

    // final projection -> d_out f32
    gemm_frag<3, false><<<2048, 256, 0, stream>>>(O, projf, projb, (float*)d_out);
}

// Round 11
// 329.467 us; speedup vs baseline: 9.9052x; 1.0633x over previous
//
#include <hip/hip_runtime.h>
#include <math.h>

// B=2048 windows, N=64 tokens, C=192 channels, 6 heads x 32 dim, 3C=576
#define SCALE_Q 0.17677669529663687f

typedef _Float16 f16;
typedef _Float16 f16x4 __attribute__((ext_vector_type(4)));
typedef _Float16 f16x8 __attribute__((ext_vector_type(8)));
typedef float float4v __attribute__((ext_vector_type(4)));

// Precomputed relative-position bias tile [6][64][64] (f16), L2-hot at use.
__device__ f16 g_biasg[6 * 64 * 64];

// cos(k*pi/4), k in [0,8) — branchless
__device__ __forceinline__ float cos8(int k) {
    float m = (k & 1) ? 0.70710678118654752f : ((k & 2) ? 0.f : 1.f);
    return (k >= 3 && k <= 5) ? -m : m;
}

// Fast GELU: A&S 7.1.26 erf approx, |err| <= 1.5e-7.
__device__ __forceinline__ float gelu_f(float v) {
    float az = fabsf(v) * 0.70710678118654752f;
    float t = 1.0f / fmaf(az, 0.3275911f, 1.0f);
    float p = t * fmaf(t, fmaf(t, fmaf(t, fmaf(t, 1.061405429f, -1.453152027f),
                                       1.421413741f), -0.284496736f), 0.254829592f);
    float erfv = 1.0f - p * __expf(-az * az);
    erfv = copysignf(erfv, v);
    return 0.5f * v * (1.0f + erfv);
}

// ---------------------------------------------------------------------------
// Prep: all weights to f16 MFMA-fragment order (512 elems/fragment):
//   Wf[(o16*6+kc)*512 + lane*8 + j] = W[o16*16+(lane&15)][kc*32+(lane>>4)*8+j]
// qkvf (576x192) | projf (192x192) | q1f | q2f (192x192) + bias tile.
// ---------------------------------------------------------------------------
__global__ __launch_bounds__(256) void k_prep(
    const float* __restrict__ qkvw, const float* __restrict__ q1w,
    const float* __restrict__ q2w, const float* __restrict__ projw,
    const float* __restrict__ rpb, const int* __restrict__ relidx,
    f16* __restrict__ qkvf, f16* __restrict__ projf,
    f16* __restrict__ q1f, f16* __restrict__ q2f)
{
    int idx = blockIdx.x * 256 + threadIdx.x;
    if (idx < 221184) {
        int i = idx;
        const float* src;
        f16* dst;
        if (i < 110592)      { src = qkvw;  dst = qkvf; }
        else if (i < 147456) { i -= 110592; src = projw; dst = projf; }
        else if (i < 184320) { i -= 147456; src = q1w;   dst = q1f; }
        else                 { i -= 184320; src = q2w;   dst = q2f; }
        int frag = i >> 9, rem = i & 511;
        int lane = rem >> 3, j = rem & 7;
        int o16 = frag / 6, kc = frag - o16 * 6;
        int row = o16 * 16 + (lane & 15);
        int col = kc * 32 + (lane >> 4) * 8 + j;
        dst[i] = (f16)src[row * 192 + col];
    } else if (idx < 245760) {
        int i = idx - 221184;
        int h = i >> 12, nm = i & 4095;
        g_biasg[h * 4096 + nm] = (f16)rpb[relidx[nm] * 6 + h];
    }
}

// ---------------------------------------------------------------------------
// x f32 [131072][192] -> XTg f16 [192][131072] (transposed), coalesced both sides.
// ---------------------------------------------------------------------------
__global__ __launch_bounds__(256) void k_xt(const float* __restrict__ x,
                                            f16* __restrict__ XTg)
{
    __shared__ float xs[64 * 65];
    const int bb = blockIdx.x, cg = blockIdx.y, tid = threadIdx.x;
    #pragma unroll
    for (int it = 0; it < 4; ++it) {
        int idx = tid + it * 256;
        int r = idx >> 4, c4 = idx & 15;
        float4v v = *(const float4v*)&x[((long)bb * 64 + r) * 192 + cg * 64 + c4 * 4];
        xs[r * 65 + c4 * 4 + 0] = v.x;
        xs[r * 65 + c4 * 4 + 1] = v.y;
        xs[r * 65 + c4 * 4 + 2] = v.z;
        xs[r * 65 + c4 * 4 + 3] = v.w;
    }
    __syncthreads();
    #pragma unroll
    for (int it = 0; it < 2; ++it) {
        int idx = tid + it * 256;
        int oc = idx >> 3, r8 = idx & 7;
        f16x8 o;
        #pragma unroll
        for (int j = 0; j < 8; ++j) o[j] = (f16)xs[(r8 * 8 + j) * 65 + oc];
        *(f16x8*)&XTg[((long)(cg * 64 + oc)) * 131072 + (long)bb * 64 + r8 * 8] = o;
    }
}

// ---------------------------------------------------------------------------
// Fully fused FFT branch, one block (512 thr, 8 waves) per window.
// ph1/ph4: rw=w&3 row-tiles, ch=w>>2 col-halves; DFT matrix per-lane (cos8).
// ph2/ph3: h2=w&1, q4=w>>1; weights from q1f/q2f fragment-order (L2-hot 1KB loads).
// LDS: XT[192][72] (x^T, later y2 [64][216]) + Y[64][200] (y1, later y3T swz).
// ---------------------------------------------------------------------------
__global__ __launch_bounds__(512, 4) void k_fft(
    const f16* __restrict__ XTg, const f16* __restrict__ q1f,
    const f16* __restrict__ q2f, f16* __restrict__ xifft)
{
    __shared__ f16 XT[192 * 72];
    __shared__ f16 Y[64 * 200];
    const int b = blockIdx.x, tid = threadIdx.x;
    const long gbase = (long)b * 12288;
    const int w = tid >> 6, l = tid & 63, lo = l & 15, hi = l >> 4;
    const int rw = w & 3, ch = w >> 2;
    const int h2 = w & 1, q4 = w >> 1;

    #pragma unroll
    for (int it = 0; it < 3; ++it) {
        int idx = tid + it * 512;
        int c = idx >> 3, g8 = idx & 7;
        *(f16x8*)&XT[c * 72 + g8 * 8] =
            *(const f16x8*)&XTg[(long)c * 131072 + b * 64 + g8 * 8];
    }
    __syncthreads();

    // ph1: y1[uv][c] = sum_hw L[uv][hw] x^T[c][hw]
    {
        f16x8 afr[2];
        int u = (rw * 16 + lo) >> 3, v = (rw * 16 + lo) & 7;
        #pragma unroll
        for (int kc = 0; kc < 2; ++kc) {
            int cg = kc * 4 + hi;
            #pragma unroll
            for (int e = 0; e < 8; ++e)
                afr[kc][e] = (f16)cos8((u * cg + v * e) & 7);
        }
        float4v acc[6];
        #pragma unroll
        for (int nt = 0; nt < 6; ++nt) acc[nt] = (float4v){0.f,0.f,0.f,0.f};
        #pragma unroll
        for (int kc = 0; kc < 2; ++kc)
            #pragma unroll
            for (int nt = 0; nt < 6; ++nt) {
                f16x8 bf = *(const f16x8*)&XT[(ch * 96 + nt * 16 + lo) * 72 + kc * 32 + hi * 8];
                acc[nt] = __builtin_amdgcn_mfma_f32_16x16x32_f16(afr[kc], bf, acc[nt], 0, 0, 0);
            }
        #pragma unroll
        for (int nt = 0; nt < 6; ++nt)
            #pragma unroll
            for (int r = 0; r < 4; ++r)
                Y[(rw * 16 + hi * 4 + r) * 200 + ch * 96 + nt * 16 + lo] = (f16)acc[nt][r];
    }
    __syncthreads();   // y1 visible; XT(x^T) reads done

    // ph2: y2[uv][o] = gelu(sum_c y1[uv][c] q1[o][c]) -> XT region, stride 216
    {
        float4v acc[2][3];
        #pragma unroll
        for (int mt = 0; mt < 2; ++mt)
            #pragma unroll
            for (int nj = 0; nj < 3; ++nj) acc[mt][nj] = (float4v){0.f,0.f,0.f,0.f};
        for (int kc = 0; kc < 6; ++kc) {
            f16x8 a[2];
            #pragma unroll
            for (int mt = 0; mt < 2; ++mt)
                a[mt] = *(const f16x8*)&Y[(h2 * 32 + mt * 16 + lo) * 200 + kc * 32 + hi * 8];
            #pragma unroll
            for (int nj = 0; nj < 3; ++nj) {
                f16x8 bf = *(const f16x8*)&q1f[((q4 * 3 + nj) * 6 + kc) * 512 + l * 8];
                #pragma unroll
                for (int mt = 0; mt < 2; ++mt)
                    acc[mt][nj] = __builtin_amdgcn_mfma_f32_16x16x32_f16(a[mt], bf, acc[mt][nj], 0, 0, 0);
            }
        }
        f16* y2 = XT;
        #pragma unroll
        for (int mt = 0; mt < 2; ++mt)
            #pragma unroll
            for (int nj = 0; nj < 3; ++nj)
                #pragma unroll
                for (int r = 0; r < 4; ++r)
                    y2[(h2 * 32 + mt * 16 + hi * 4 + r) * 216 + (q4 * 3 + nj) * 16 + lo] =
                        (f16)gelu_f(acc[mt][nj][r]);
    }
    __syncthreads();   // y2 visible; Y(y1) reads done

    // ph3: y3T[o][uv] = sum_c q2[o][c] y2[uv][c] -> Y region, swizzled cols
    {
        const f16* y2 = XT;
        float4v acc[3][2];
        #pragma unroll
        for (int jo = 0; jo < 3; ++jo)
            #pragma unroll
            for (int ju = 0; ju < 2; ++ju) acc[jo][ju] = (float4v){0.f,0.f,0.f,0.f};
        for (int kc = 0; kc < 6; ++kc) {
            f16x8 bf2[2];
            #pragma unroll
            for (int ju = 0; ju < 2; ++ju)
                bf2[ju] = *(const f16x8*)&y2[((h2 * 2 + ju) * 16 + lo) * 216 + kc * 32 + hi * 8];
            #pragma unroll
            for (int jo = 0; jo < 3; ++jo) {
                f16x8 a = *(const f16x8*)&q2f[((q4 * 3 + jo) * 6 + kc) * 512 + l * 8];
                #pragma unroll
                for (int ju = 0; ju < 2; ++ju)
                    acc[jo][ju] = __builtin_amdgcn_mfma_f32_16x16x32_f16(a, bf2[ju], acc[jo][ju], 0, 0, 0);
            }
        }
        __syncthreads();   // y2 reads done before overwriting Y
        #pragma unroll
        for (int jo = 0; jo < 3; ++jo)
            #pragma unroll
            for (int ju = 0; ju < 2; ++ju)
                #pragma unroll
                for (int r = 0; r < 4; ++r) {
                    int row = (q4 * 3 + jo) * 16 + hi * 4 + r;
                    int col = (h2 * 2 + ju) * 16 + lo;
                    Y[row * 64 + (col ^ ((row & 7) << 3))] = (f16)acc[jo][ju][r];
                }
    }
    __syncthreads();   // y3T visible

    // ph4: xifft[o][hw] = (1/64) sum_uv y3T[o][uv] L[hw][uv]
    {
        f16x8 bfr[2][2];
        #pragma unroll
        for (int t = 0; t < 2; ++t) {
            int hw = (ch * 2 + t) * 16 + lo;
            int hu = hw >> 3, hv = hw & 7;
            #pragma unroll
            for (int kc = 0; kc < 2; ++kc) {
                int cg = kc * 4 + hi;
                #pragma unroll
                for (int e = 0; e < 8; ++e)
                    bfr[t][kc][e] = (f16)cos8((hu * cg + hv * e) & 7);
            }
        }
        float4v acc[6];
        #pragma unroll
        for (int jt = 0; jt < 6; ++jt) acc[jt] = (float4v){0.f,0.f,0.f,0.f};
        #pragma unroll
        for (int kc = 0; kc < 2; ++kc)
            #pragma unroll
            for (int j = 0; j < 3; ++j) {
                int row = (rw * 3 + j) * 16 + lo;
                f16x8 a = *(const f16x8*)&Y[row * 64 + ((kc * 32 + hi * 8) ^ ((row & 7) << 3))];
                #pragma unroll
                for (int t = 0; t < 2; ++t)
                    acc[j * 2 + t] = __builtin_amdgcn_mfma_f32_16x16x32_f16(a, bfr[t][kc], acc[j * 2 + t], 0, 0, 0);
            }
        #pragma unroll
        for (int j = 0; j < 3; ++j)
            #pragma unroll
            for (int t = 0; t < 2; ++t)
                #pragma unroll
                for (int r = 0; r < 4; ++r)
                    xifft[gbase + ((rw * 3 + j) * 16 + hi * 4 + r) * 64 + (ch * 2 + t) * 16 + lo] =
                        (f16)(acc[j * 2 + t][r] * 0.015625f);
    }
}

// ---------------------------------------------------------------------------
// fp16 MFMA GEMM, K=192, weights in fragment order (no Ws staging, no loop
// barriers; epilogue bounce rows are wave-private -> barrier-free).
// GROUPED=true : A f32 (x), out grouped [(o/32)][row][o%32] f16 (qkv).
// GROUPED=false: A f16, out row-major [M][192] f32 (proj).
// ---------------------------------------------------------------------------
template<int NT, bool GROUPED>
__global__ __launch_bounds__(256) void gemm_frag(
    const void* __restrict__ Ain, const f16* __restrict__ Wf,
    const float* __restrict__ bias, void* __restrict__ out)
{
    __shared__ f16 As[64 * 200];
    __shared__ char bnc_raw[GROUPED ? 64 * 72 * 2 : 64 * 68 * 4];
    const int tid = threadIdx.x;
    const long row0 = (long)blockIdx.x * 64;
    const int w = tid >> 6, l = tid & 63, lo = l & 15, hi = l >> 4;

    if (GROUPED) {
        const float* A = (const float*)Ain;
        for (int idx = tid; idx < 3072; idx += 256) {
            int r = idx / 48, c4 = idx % 48;
            float4v v = *(const float4v*)&A[(row0 + r) * 192 + c4 * 4];
            f16x4 hv = {(f16)v.x, (f16)v.y, (f16)v.z, (f16)v.w};
            *(f16x4*)&As[r * 200 + c4 * 4] = hv;
        }
    } else {
        const f16* A = (const f16*)Ain;
        for (int idx = tid; idx < 1536; idx += 256) {
            int r = idx / 24, c8 = idx % 24;
            *(f16x8*)&As[r * 200 + c8 * 8] =
                *(const f16x8*)&A[(row0 + r) * 192 + c8 * 8];
        }
    }
    __syncthreads();

    for (int ot = 0; ot < NT; ++ot) {
        float4v acc[4];
        #pragma unroll
        for (int nt = 0; nt < 4; ++nt) acc[nt] = (float4v){0.f,0.f,0.f,0.f};
        #pragma unroll
        for (int kc = 0; kc < 6; ++kc) {
            f16x8 a = *(const f16x8*)&As[(w * 16 + lo) * 200 + kc * 32 + hi * 8];
            #pragma unroll
            for (int nt = 0; nt < 4; ++nt) {
                f16x8 bf = *(const f16x8*)&Wf[(long)(((ot * 4 + nt) * 6 + kc)) * 512 + l * 8];
                acc[nt] = __builtin_amdgcn_mfma_f32_16x16x32_f16(a, bf, acc[nt], 0, 0, 0);
            }
        }
        if (GROUPED) {
            f16* bw = (f16*)bnc_raw;  // [64][72], wave-private rows
            #pragma unroll
            for (int nt = 0; nt < 4; ++nt)
                #pragma unroll
                for (int r = 0; r < 4; ++r) {
                    float v = acc[nt][r] + bias[ot * 64 + nt * 16 + lo];
                    bw[(w * 16 + hi * 4 + r) * 72 + nt * 16 + lo] = (f16)v;
                }
            int row = w * 16 + (l >> 2);
            #pragma unroll
            for (int j = 0; j < 2; ++j) {
                int col = (l & 3) * 16 + j * 8;
                f16x8 v = *(const f16x8*)&bw[row * 72 + col];
                int o = ot * 64 + col;
                *(f16x8*)&((f16*)out)[((long)(o >> 5) * 131072 + row0 + row) * 32 + (o & 31)] = v;
            }
        } else {
            float* bwf = (float*)bnc_raw;  // [64][68], wave-private rows
            #pragma unroll
            for (int nt = 0; nt < 4; ++nt)
                #pragma unroll
                for (int r = 0; r < 4; ++r) {
                    float v = acc[nt][r] + bias[ot * 64 + nt * 16 + lo];
                    bwf[(w * 16 + hi * 4 + r) * 68 + nt * 16 + lo] = v;
                }
            int row = w * 16 + (l >> 2);
            #pragma unroll
            for (int j = 0; j < 4; ++j) {
                int c4 = ((l & 3) + j * 4) * 4;
                float4v v = *(const float4v*)&bwf[row * 68 + c4];
                *(float4v*)&((float*)out)[(row0 + row) * 192 + ot * 64 + c4] = v;
            }
        }
    }
}

// ---------------------------------------------------------------------------
// Fused depthwise-3x3 conv (packed f16) + xifft residual + MFMA attention.
// One block per (b,h) — natural b (producer-affine L2). Register prefetch of
// the next s-phase's halo (T14 async-stage split) hides global latency under
// the conv math. pls overlaid on dead tb -> LDS 29 KB -> 5 blocks/CU.
// ---------------------------------------------------------------------------
__global__ __launch_bounds__(256, 5) void k_attn(
    const f16* __restrict__ T, const f16* __restrict__ xifft,
    const float* __restrict__ dww, const float* __restrict__ dwb,
    f16* __restrict__ obnc)
{
    __shared__ f16 tb[3 * 66 * 32];   // [r][nn+1][ch]; later pls [64][72]
    __shared__ f16 qls[64 * 40];      // q rows; later output bounce
    __shared__ f16 kls[64 * 40];
    __shared__ f16 vtl[32 * 72];      // v transposed
    __shared__ f16 wd[864];           // [s][rj][32]
    __shared__ f16 bd[96];
    const int b = blockIdx.x;
    const int h = blockIdx.y, tid = threadIdx.x;
    const int n = tid >> 2, cth = tid & 3;

    for (int idx = tid; idx < 864; idx += 256) {
        int s = idx / 288, rj = (idx % 288) >> 5, d = idx & 31;
        wd[idx] = (f16)dww[(s * 192 + h * 32 + d) * 9 + rj];
    }
    if (tid < 96) {
        int s = tid >> 5, d = tid & 31;
        bd[tid] = (f16)dwb[s * 192 + h * 32 + d];
    }
    if (tid < 24) {    // zero n-pads once (interior writes never touch them)
        int r = tid / 8, pe = (tid >> 2) & 1, cc = tid & 3;
        f16x8 z = {};
        *(f16x8*)&tb[((r * 66) + pe * 65) * 32 + cc * 8] = z;
    }
    f16x8 xf8 = *(const f16x8*)&xifft[(long)b * 12288 + h * 2048 + n * 32 + cth * 8];

    // per-thread staging slots (s-invariant addresses; only group offset moves)
    long  g_off[3];
    int   l_off[3];
    bool  g_val[3];
    #pragma unroll
    for (int it = 0; it < 3; ++it) {
        int idx = tid + it * 256;
        int r = idx >> 8, rem = idx & 255;
        int nn = rem >> 2, cc = rem & 3;
        int bb = b + r - 1;
        g_val[it] = (bb >= 0 && bb < 2048);
        g_off[it] = ((long)bb * 64 + nn) * 32 + cc * 8;
        l_off[it] = (r * 66 + nn + 1) * 32 + cc * 8;
    }
    f16x8 pre[3];
    #pragma unroll
    for (int it = 0; it < 3; ++it) {
        f16x8 v = {};
        if (g_val[it]) v = *(const f16x8*)&T[(long)h * 4194304 + g_off[it]];  // s=0
        pre[it] = v;
    }
    __syncthreads();   // wd/bd/pads staged

    for (int s = 0; s < 3; ++s) {
        #pragma unroll
        for (int it = 0; it < 3; ++it)
            *(f16x8*)&tb[l_off[it]] = pre[it];
        if (s < 2) {   // issue next phase's loads; latency hides under conv
            #pragma unroll
            for (int it = 0; it < 3; ++it) {
                f16x8 v = {};
                if (g_val[it])
                    v = *(const f16x8*)&T[(long)((s + 1) * 6 + h) * 4194304 + g_off[it]];
                pre[it] = v;
            }
        }
        __syncthreads();   // tb visible
        f16x8 acc = *(const f16x8*)&bd[s * 32 + cth * 8];
        #pragma unroll
        for (int rj = 0; rj < 9; ++rj) {
            f16x8 tv = *(const f16x8*)&tb[((rj / 3) * 66 + n + rj % 3) * 32 + cth * 8];
            f16x8 wv = *(const f16x8*)&wd[(s * 9 + rj) * 32 + cth * 8];
            acc += wv * tv;
        }
        acc += xf8;
        if (s == 0) {
            acc *= (f16)SCALE_Q;
            *(f16x8*)&qls[n * 40 + cth * 8] = acc;
        } else if (s == 1) {
            *(f16x8*)&kls[n * 40 + cth * 8] = acc;
        } else {
            // stagger dd by cth -> conflict-free vtl scalar writes
            #pragma unroll
            for (int dd = 0; dd < 8; ++dd) {
                int dd2 = (dd + cth * 2) & 7;
                vtl[(cth * 8 + dd2) * 72 + n] = acc[dd2];
            }
        }
        __syncthreads();   // conv reads of tb done (also final q/k/v fence at s=2)
    }

    f16* pls = tb;     // tb dead -> reuse as pls [64][72]

    // QK^T
    const int w = tid >> 6, l = tid & 63, lo = l & 15, hi = l >> 4;
    f16x8 qfrag = *(const f16x8*)&qls[(w * 16 + lo) * 40 + hi * 8];
    float4v accq[4];
    #pragma unroll
    for (int mt = 0; mt < 4; ++mt) {
        f16x8 kfrag = *(const f16x8*)&kls[(mt * 16 + lo) * 40 + hi * 8];
        accq[mt] = __builtin_amdgcn_mfma_f32_16x16x32_f16(
            qfrag, kfrag, (float4v){0.f, 0.f, 0.f, 0.f}, 0, 0, 0);
    }

    // bias + softmax in C-layout registers
    const f16* bg = g_biasg + h * 4096;
    float pv[4][4];
    #pragma unroll
    for (int mt = 0; mt < 4; ++mt)
        #pragma unroll
        for (int r = 0; r < 4; ++r)
            pv[mt][r] = accq[mt][r] + (float)bg[(w * 16 + hi * 4 + r) * 64 + mt * 16 + lo];
    float inv[4];
    #pragma unroll
    for (int r = 0; r < 4; ++r) {
        float mx = fmaxf(fmaxf(pv[0][r], pv[1][r]), fmaxf(pv[2][r], pv[3][r]));
        mx = fmaxf(mx, __shfl_xor(mx, 1));
        mx = fmaxf(mx, __shfl_xor(mx, 2));
        mx = fmaxf(mx, __shfl_xor(mx, 4));
        mx = fmaxf(mx, __shfl_xor(mx, 8));
        float sum = 0.f;
        #pragma unroll
        for (int mt = 0; mt < 4; ++mt) { pv[mt][r] = __expf(pv[mt][r] - mx); sum += pv[mt][r]; }
        sum += __shfl_xor(sum, 1);
        sum += __shfl_xor(sum, 2);
        sum += __shfl_xor(sum, 4);
        sum += __shfl_xor(sum, 8);
        inv[r] = 1.0f / sum;
    }
    #pragma unroll
    for (int mt = 0; mt < 4; ++mt)
        #pragma unroll
        for (int r = 0; r < 4; ++r)
            pls[(w * 16 + hi * 4 + r) * 72 + mt * 16 + lo] = (f16)(pv[mt][r] * inv[r]);
    // wave-private rows: in-order LDS per wave, no barrier

    // PV
    float4v acco[2] = {(float4v){0.f,0.f,0.f,0.f}, (float4v){0.f,0.f,0.f,0.f}};
    #pragma unroll
    for (int kc = 0; kc < 2; ++kc) {
        f16x8 pfrag = *(const f16x8*)&pls[(w * 16 + lo) * 72 + kc * 32 + hi * 8];
        #pragma unroll
        for (int dt = 0; dt < 2; ++dt) {
            f16x8 vfrag = *(const f16x8*)&vtl[(dt * 16 + lo) * 72 + kc * 32 + hi * 8];
            acco[dt] = __builtin_amdgcn_mfma_f32_16x16x32_f16(pfrag, vfrag, acco[dt], 0, 0, 0);
        }
    }
    // bounce output through qls (dead, wave-own rows) -> coalesced f16x8 stores
    #pragma unroll
    for (int dt = 0; dt < 2; ++dt)
        #pragma unroll
        for (int r = 0; r < 4; ++r)
            qls[(w * 16 + hi * 4 + r) * 40 + dt * 16 + lo] = (f16)acco[dt][r];
    {
        int row = w * 16 + (l >> 2);
        f16x8 ov = *(const f16x8*)&qls[row * 40 + (l & 3) * 8];
        *(f16x8*)&obnc[((long)b * 64 + row) * 192 + h * 32 + (l & 3) * 8] = ov;
    }
}

// ---------------------------------------------------------------------------
// Launcher. Workspace (f16 elems), 251,953,152 bytes total:
//   T    [0, 75497472)           : qkv conv output, grouped [18][131072][32]
//   XTg  = T[0, 25165824)        : x^T f16 (alias; dead before qkv writes T)
//   q1f  = T[25165824, +36864)   : q1 fragment-order (alias; dead before qkv)
//   q2f  = T[25202688, +36864)   : q2 fragment-order (alias; dead before qkv)
//   XI   [75497472, 100663296)   : xifft
//   O    [100663296, 125829120)  : obnc [bn][192]
//   WB   [125829120, +147456)    : qkvf | projf (fragment order, persistent)
// ---------------------------------------------------------------------------
extern "C" void kernel_launch(void* const* d_in, const int* in_sizes, int n_in,
                              void* d_out, int out_size, void* d_ws, size_t ws_size,
                              hipStream_t stream)
{
    const float* x      = (const float*)d_in[0];
    const float* qkvw   = (const float*)d_in[1];
    const float* qkvb   = (const float*)d_in[2];
    const float* dww    = (const float*)d_in[3];
    const float* dwb    = (const float*)d_in[4];
    const float* q1w    = (const float*)d_in[5];
    const float* q2w    = (const float*)d_in[6];
    const float* rpb    = (const float*)d_in[7];
    const float* projw  = (const float*)d_in[8];
    const float* projb  = (const float*)d_in[9];
    const int*   relidx = (const int*)d_in[10];

    f16* T    = (f16*)d_ws;
    f16* XTg  = T;                          // alias: dead before qkv-gemm writes T
    f16* q1f  = T + 25165824L;              // alias: dead before qkv-gemm writes T
    f16* q2f  = T + 25202688L;
    f16* XI   = T + 75497472L;
    f16* O    = XI + 25165824L;
    f16* WB   = O + 25165824L;
    f16* qkvf  = WB;
    f16* projf = WB + 110592;

    k_prep<<<960, 256, 0, stream>>>(qkvw, q1w, q2w, projw, rpb, relidx,
                                    qkvf, projf, q1f, q2f);

    // x -> x^T f16
    k_xt<<<dim3(2048, 3), 256, 0, stream>>>(x, XTg);

    // fused FFT branch -> xifft
    k_fft<<<2048, 512, 0, stream>>>(XTg, q1f, q2f, XI);

    // t = x @ qkv_w^T + qkv_b  (grouped [18][bn][32], f16)
    gemm_frag<9, true><<<2048, 256, 0, stream>>>(x, qkvf, qkvb, T);

    // fused depthwise conv + residual + MFMA attention -> obnc f16
    k_attn<<<dim3(2048, 6), 256, 0, stream>>>(T, XI, dww, dwb, O);

    // final projection -> d_out f32
    gemm_frag<3, false><<<2048, 256, 0, stream>>>(O, projf, projb, (float*)d_out);
}